// Round 9
// baseline (1628.988 us; speedup 1.0000x reference)
//
#include <hip/hip_runtime.h>
#include <cstddef>

#define N_NODES_  100000
#define N_HEDGES_ 200000
#define E_        1200000
#define G_        512
#define H_        64
#define HE_       35
#define D_        99      // H_+HE_
#define HOUT_     128
#define L_        3
#define NB_N_     1563    // ceil(N_NODES/64)
#define NB_H_     3125    // N_HEDGES/64

typedef unsigned int u32;
typedef _Float16 f2_t __attribute__((ext_vector_type(2)));

__device__ __forceinline__ float sigm_(float x){
  return __builtin_amdgcn_rcpf(1.f + __expf(-x));
}
__device__ __forceinline__ float sp_(float x){
  return fmaxf(x, 0.f) + __logf(1.f + __expf(-fabsf(x)));
}
__device__ __forceinline__ float gate_(float F, float C){ return sigm_(F)*sp_(C); }

__device__ __forceinline__ u32 pk_(float a, float b){
  return __builtin_bit_cast(u32, __builtin_amdgcn_cvt_pkrtz(a, b));
}
__device__ __forceinline__ float dot2_(u32 a, u32 b, float c){
#if __has_builtin(__builtin_amdgcn_fdot2)
  return __builtin_amdgcn_fdot2(__builtin_bit_cast(f2_t, a),
                                __builtin_bit_cast(f2_t, b), c, false);
#else
  f2_t x = __builtin_bit_cast(f2_t, a), y = __builtin_bit_cast(f2_t, b);
  return c + (float)x[0]*(float)y[0] + (float)x[1]*(float)y[1];
#endif
}
__device__ __forceinline__ float lo_(u32 a){ return (float)__builtin_bit_cast(f2_t, a)[0]; }
__device__ __forceinline__ float hi_(u32 a){ return (float)__builtin_bit_cast(f2_t, a)[1]; }

// ---------------- per-call counts (XCD-partitioned scatter) ----------------
__global__ void k_counts(const int* __restrict__ ni, const int* __restrict__ hi,
                         int* __restrict__ hcnt, int* __restrict__ ndeg){
  int part = blockIdx.x & 7;
  int tid = (blockIdx.x >> 3)*256 + threadIdx.x;
  int stride = (gridDim.x >> 3)*256;
  for (int e = tid; e < E_; e += stride){
    int n = ni[e], he = hi[e];
    if (((n >> 6) & 7) == part)  atomicAdd(&ndeg[n], 1);
    if (((he >> 6) & 7) == part) atomicAdd(&hcnt[he], 1);
  }
}
__global__ void k_gcnt(const int* __restrict__ batch, int* __restrict__ gcnt){
  int n = blockIdx.x*256 + threadIdx.x;
  if (n < N_NODES_) atomicAdd(&gcnt[batch[n]], 1);
}
__global__ void k_inv(const int* __restrict__ hcnt, const int* __restrict__ ndeg,
                      float* __restrict__ hinv, float* __restrict__ ninv){
  int i = blockIdx.x*256 + threadIdx.x;
  if (i < N_HEDGES_) hinv[i] = 1.f/fmaxf((float)hcnt[i], 1.f);
  if (i < N_NODES_)  ninv[i] = 1.f/fmaxf((float)ndeg[i], 1.f);
}

// ---------------- CSR build: scan ----------------
__global__ void k_scan1(const int* __restrict__ cnt, int n, int* __restrict__ off,
                        int* __restrict__ bsum){
  __shared__ int tmp[256];
  int i = blockIdx.x*256 + threadIdx.x;
  int v = (i < n) ? cnt[i] : 0;
  tmp[threadIdx.x] = v;
  __syncthreads();
  for (int d = 1; d < 256; d <<= 1){
    int t = (threadIdx.x >= d) ? tmp[threadIdx.x - d] : 0;
    __syncthreads();
    tmp[threadIdx.x] += t;
    __syncthreads();
  }
  if (i < n) off[i] = tmp[threadIdx.x] - v;
  if (threadIdx.x == 255) bsum[blockIdx.x] = tmp[255];
}
__global__ void k_scan2(int* __restrict__ bsum, int nb){
  __shared__ int tmp[1024];
  int t = threadIdx.x;
  int v = (t < nb) ? bsum[t] : 0;
  tmp[t] = v;
  __syncthreads();
  for (int d = 1; d < 1024; d <<= 1){
    int x = (t >= d) ? tmp[t - d] : 0;
    __syncthreads();
    tmp[t] += x;
    __syncthreads();
  }
  if (t < nb) bsum[t] = tmp[t] - v;
}
__global__ void k_scan3(int* __restrict__ off, const int* __restrict__ bsum, int n){
  int i = blockIdx.x*256 + threadIdx.x;
  if (i < n) off[i] += bsum[blockIdx.x];
}

// ---------------- bucketed CSR fill, XCD-partitioned ----------------
__global__ void k_bucket_init(const int* __restrict__ node_off, const int* __restrict__ hedge_off,
                              int* __restrict__ bcurN, int* __restrict__ bcurH){
  int b = blockIdx.x*256 + threadIdx.x;
  if (b < NB_N_) bcurN[b] = node_off[b*64];
  if (b < NB_H_) bcurH[b] = hedge_off[b*64];
}
// pair encoding: (local_row_6b << 24) | id (< 2^24)
__global__ void k_binfill(const int* __restrict__ ni, const int* __restrict__ hi,
                          int* __restrict__ bcurN, int* __restrict__ bcurH,
                          u32* __restrict__ pairN, u32* __restrict__ pairH){
  int part = blockIdx.x & 7;
  int tid = (blockIdx.x >> 3)*256 + threadIdx.x;
  int stride = (gridDim.x >> 3)*256;
  for (int e = tid; e < E_; e += stride){
    int n = ni[e], he = hi[e];
    int bn = n >> 6, bh = he >> 6;
    if ((bn & 7) == part){
      int pn = atomicAdd(&bcurN[bn], 1);
      pairN[pn] = ((u32)(n & 63) << 24) | (u32)he;
    }
    if ((bh & 7) == part){
      int ph = atomicAdd(&bcurH[bh], 1);
      pairH[ph] = ((u32)(he & 63) << 24) | (u32)n;
    }
  }
}
// one block per bucket of 64 rows; LDS cursors; hot dest region
__global__ void k_csrfill(const int* __restrict__ off_arr, const int* __restrict__ bcur,
                          const u32* __restrict__ pair, int nitems, int* __restrict__ out){
  __shared__ int cur[64];
  int b = blockIdx.x, t = threadIdx.x;
  int nb = b*64;
  if (t < 64){
    int idx = nb + t;
    cur[t] = (idx < nitems) ? off_arr[idx] : 0;
  }
  __syncthreads();
  int base = off_arr[nb];
  int end  = bcur[b];
  for (int pos = base + t; pos < end; pos += 256){
    u32 p = pair[pos];
    int loc = p >> 24;
    int val = (int)(p & 0xFFFFFFu);
    int idx = atomicAdd(&cur[loc], 1);
    out[idx] = val;
  }
}

// ---------------- pack hattr to fp16 pairs [NH][18] ----------------
__global__ void k_hattr_pack(const float* __restrict__ hattr, u32* __restrict__ hattr16){
  int i = blockIdx.x*256 + threadIdx.x;
  if (i >= N_HEDGES_*18) return;
  int he = i/18, p = i - he*18;
  int k0 = 2*p, k1 = 2*p + 1;
  float w0 = (k0 < 35) ? hattr[(size_t)he*35 + k0] : 0.f;
  float w1 = (k1 < 35) ? hattr[(size_t)he*35 + k1] : 0.f;
  hattr16[i] = pk_(w0, w1);
}

// ---------------- embed: h = x @ We + be ; also packed fp16 mirror ----------------
__global__ void k_embed(const float* __restrict__ x, const float* __restrict__ We,
                        const float* __restrict__ be, float* __restrict__ h,
                        u32* __restrict__ h16){
  __shared__ __align__(16) float As[64*100];
  __shared__ __align__(16) float Ws[64*100];
  int tid = threadIdx.x;
  for (int idx = tid; idx < 64*100; idx += 256){
    int c = idx/100, k = idx - c*100;
    Ws[idx] = (k < 92) ? We[k*64 + c] : 0.f;
  }
  int rt = tid & 15, ct = tid >> 4;
  float bias[4];
  #pragma unroll
  for (int j = 0; j < 4; ++j) bias[j] = be[ct*4 + j];
  const int ntiles = (N_NODES_ + 63)/64;
  for (int tile = blockIdx.x; tile < ntiles; tile += gridDim.x){
    int rbase = tile*64;
    __syncthreads();
    for (int idx = tid; idx < 64*100; idx += 256){
      int r = idx/100, k = idx - r*100;
      int rg = rbase + r;
      As[idx] = (rg < N_NODES_ && k < 92) ? x[(size_t)rg*92 + k] : 0.f;
    }
    __syncthreads();
    float acc[4][4] = {};
    for (int kc = 0; kc < 25; ++kc){
      float4 av[4], wv[4];
      #pragma unroll
      for (int i = 0; i < 4; ++i) av[i] = *(const float4*)&As[(rt + 16*i)*100 + kc*4];
      #pragma unroll
      for (int j = 0; j < 4; ++j) wv[j] = *(const float4*)&Ws[(ct*4 + j)*100 + kc*4];
      #pragma unroll
      for (int i = 0; i < 4; ++i)
        #pragma unroll
        for (int j = 0; j < 4; ++j)
          acc[i][j] += av[i].x*wv[j].x + av[i].y*wv[j].y + av[i].z*wv[j].z + av[i].w*wv[j].w;
    }
    #pragma unroll
    for (int i = 0; i < 4; ++i){
      int r = rbase + rt + 16*i;
      if (r < N_NODES_){
        float4 st;
        st.x = acc[i][0] + bias[0]; st.y = acc[i][1] + bias[1];
        st.z = acc[i][2] + bias[2]; st.w = acc[i][3] + bias[3];
        *(float4*)&h[(size_t)r*64 + ct*4] = st;
        h16[(size_t)r*32 + ct*2]     = pk_(st.x, st.y);
        h16[(size_t)r*32 + ct*2 + 1] = pk_(st.z, st.w);
      }
    }
  }
}

// ---------------- hedge gather (fp16, uint2): hmean16[he] = mean of h16 rows ----------------
__global__ void __launch_bounds__(256) k_gather_hedge(
    const u32* __restrict__ h16, const int* __restrict__ hedge_off,
    const int* __restrict__ hcnt, const int* __restrict__ edge_h,
    const float* __restrict__ hinv, u32* __restrict__ hmean16){
  int w = (blockIdx.x*256 + threadIdx.x) >> 4;
  int p = threadIdx.x & 15;
  if (w >= N_HEDGES_) return;
  int off = hedge_off[w], deg = hcnt[w];
  float a0 = 0.f, a1 = 0.f, a2 = 0.f, a3 = 0.f;
  int i = 0;
  for (; i + 1 < deg; i += 2){
    int n0 = edge_h[off+i], n1 = edge_h[off+i+1];
    uint2 u0 = *(const uint2*)&h16[(size_t)n0*32 + 2*p];
    uint2 u1 = *(const uint2*)&h16[(size_t)n1*32 + 2*p];
    a0 += lo_(u0.x) + lo_(u1.x); a1 += hi_(u0.x) + hi_(u1.x);
    a2 += lo_(u0.y) + lo_(u1.y); a3 += hi_(u0.y) + hi_(u1.y);
  }
  if (i < deg){
    uint2 u = *(const uint2*)&h16[(size_t)edge_h[off+i]*32 + 2*p];
    a0 += lo_(u.x); a1 += hi_(u.x); a2 += lo_(u.y); a3 += hi_(u.y);
  }
  float inv = hinv[w];
  uint2 st; st.x = pk_(a0*inv, a1*inv); st.y = pk_(a2*inv, a3*inv);
  *(uint2*)&hmean16[(size_t)w*32 + 2*p] = st;
}

// ---------------- hedge MLP pre-BN (dot2): tfc = [msg@Wf1|msg@Wc1]+b, col stats ----------
__global__ void k_hedge_mlp1(const u32* __restrict__ hmean16, const u32* __restrict__ hattr16,
                             const float* __restrict__ Wf1, const float* __restrict__ bf1,
                             const float* __restrict__ Wc1, const float* __restrict__ bc1,
                             float* __restrict__ tfc, float* __restrict__ hstats){
  __shared__ __align__(16) u32 As16[64*52];
  __shared__ __align__(16) u32 Ws16[80*52];
  __shared__ float sstat[160];
  int tid = threadIdx.x;
  for (int idx = tid; idx < 80*52; idx += 256){
    int c = idx/52, kk = idx - c*52;
    int k0 = 2*kk, k1 = 2*kk + 1;
    float w0 = 0.f, w1 = 0.f;
    if (c < 70){
      if (k0 < 99) w0 = (c < 35) ? Wf1[k0*35 + c] : Wc1[k0*35 + (c-35)];
      if (k1 < 99) w1 = (c < 35) ? Wf1[k1*35 + c] : Wc1[k1*35 + (c-35)];
    }
    Ws16[idx] = pk_(w0, w1);
  }
  for (int idx = tid; idx < 160; idx += 256) sstat[idx] = 0.f;
  int rt = tid & 15, ct = tid >> 4;
  float bias[5];
  #pragma unroll
  for (int j = 0; j < 5; ++j){
    int c = ct*5 + j;
    bias[j] = (c < 35) ? bf1[c] : (c < 70 ? bc1[c - 35] : 0.f);
  }
  for (int tile = blockIdx.x; tile < N_HEDGES_/64; tile += gridDim.x){
    int rbase = tile*64;
    __syncthreads();
    for (int idx = tid; idx < 64*52; idx += 256){
      int r = idx/52, kk = idx - r*52;
      int rg = rbase + r;
      u32 v = 0;
      if (kk < 32)      v = hmean16[(size_t)rg*32 + kk];
      else if (kk < 50) v = hattr16[(size_t)rg*18 + (kk - 32)];
      As16[idx] = v;
    }
    __syncthreads();
    float acc[4][5] = {};
    for (int kc = 0; kc < 13; ++kc){
      uint4 av[4], wv[5];
      #pragma unroll
      for (int i = 0; i < 4; ++i) av[i] = *(const uint4*)&As16[(rt + 16*i)*52 + kc*4];
      #pragma unroll
      for (int j = 0; j < 5; ++j) wv[j] = *(const uint4*)&Ws16[(ct*5 + j)*52 + kc*4];
      #pragma unroll
      for (int i = 0; i < 4; ++i)
        #pragma unroll
        for (int j = 0; j < 5; ++j){
          float a = acc[i][j];
          a = dot2_(av[i].x, wv[j].x, a);
          a = dot2_(av[i].y, wv[j].y, a);
          a = dot2_(av[i].z, wv[j].z, a);
          a = dot2_(av[i].w, wv[j].w, a);
          acc[i][j] = a;
        }
    }
    #pragma unroll
    for (int j = 0; j < 5; ++j){
      int c = ct*5 + j;
      if (c < 70){
        float s = 0.f, q = 0.f;
        #pragma unroll
        for (int i = 0; i < 4; ++i){
          float v = acc[i][j] + bias[j];
          int r = rbase + rt + 16*i;
          tfc[(size_t)r*70 + c] = v;
          s += v; q += v*v;
        }
        atomicAdd(&sstat[c], s);
        atomicAdd(&sstat[80 + c], q);
      }
    }
  }
  __syncthreads();
  for (int idx = tid; idx < 160; idx += 256) atomicAdd(&hstats[idx], sstat[idx]);
}

// ---------------- BN finalize (hedge) ----------------
__global__ void k_bn_fin_hedge(const float* __restrict__ stats,
                               const float* __restrict__ gf, const float* __restrict__ btf,
                               const float* __restrict__ gc, const float* __restrict__ btc,
                               float* __restrict__ ab, float invN){
  int j = threadIdx.x;
  if (j >= 70) return;
  float m = stats[j]*invN;
  float var = stats[80+j]*invN - m*m;
  float gg = (j < 35) ? gf[j] : gc[j-35];
  float bb = (j < 35) ? btf[j] : btc[j-35];
  float a = gg*rsqrtf(var + 1e-5f);
  ab[j] = a; ab[70+j] = bb - m*a;
}

// ---------------- hedge feats + project (dot2): heFC2 packed fp16 ------------
__global__ void k_hedge_feats(const float* __restrict__ tfc, const float* __restrict__ ab,
                              const float* __restrict__ Wf2, const float* __restrict__ bf2,
                              const float* __restrict__ Wc2, const float* __restrict__ bc2,
                              u32* __restrict__ heFC2){
  __shared__ __align__(16) u32 As16[64*20];
  __shared__ __align__(16) u32 Ws16[128*20];
  int tid = threadIdx.x;
  for (int idx = tid; idx < 128*20; idx += 256){
    int c = idx/20, kk = idx - c*20;
    int k0 = 2*kk, k1 = 2*kk + 1;
    float w0 = 0.f, w1 = 0.f;
    if (k0 < 35) w0 = (c < 64) ? Wf2[(64+k0)*64 + c] : Wc2[(64+k0)*64 + (c-64)];
    if (k1 < 35) w1 = (c < 64) ? Wf2[(64+k1)*64 + c] : Wc2[(64+k1)*64 + (c-64)];
    Ws16[idx] = pk_(w0, w1);
  }
  int rt = tid & 15, ct = tid >> 4;
  float biasF[4], biasC[4];
  #pragma unroll
  for (int j = 0; j < 4; ++j){ biasF[j] = bf2[ct*4 + j]; biasC[j] = bc2[ct*4 + j]; }
  for (int tile = blockIdx.x; tile < N_HEDGES_/64; tile += gridDim.x){
    int rbase = tile*64;
    __syncthreads();
    for (int idx = tid; idx < 64*20; idx += 256){
      int r = idx/20, kk = idx - r*20;
      int rg = rbase + r;
      int k0 = 2*kk, k1 = 2*kk + 1;
      float a0 = 0.f, a1 = 0.f;
      if (k0 < 35){
        float zf = ab[k0]    * tfc[(size_t)rg*70 + k0]      + ab[70 + k0];
        float zc = ab[35+k0] * tfc[(size_t)rg*70 + 35 + k0] + ab[105 + k0];
        a0 = gate_(zf, zc);
      }
      if (k1 < 35){
        float zf = ab[k1]    * tfc[(size_t)rg*70 + k1]      + ab[70 + k1];
        float zc = ab[35+k1] * tfc[(size_t)rg*70 + 35 + k1] + ab[105 + k1];
        a1 = gate_(zf, zc);
      }
      As16[idx] = pk_(a0, a1);
    }
    __syncthreads();
    float accF[4][4] = {}, accC[4][4] = {};
    for (int kc = 0; kc < 5; ++kc){
      uint4 av[4], wF[4], wC[4];
      #pragma unroll
      for (int i = 0; i < 4; ++i) av[i] = *(const uint4*)&As16[(rt + 16*i)*20 + kc*4];
      #pragma unroll
      for (int j = 0; j < 4; ++j){
        wF[j] = *(const uint4*)&Ws16[(ct*4 + j)*20 + kc*4];
        wC[j] = *(const uint4*)&Ws16[(64 + ct*4 + j)*20 + kc*4];
      }
      #pragma unroll
      for (int i = 0; i < 4; ++i)
        #pragma unroll
        for (int j = 0; j < 4; ++j){
          float f = accF[i][j], c = accC[i][j];
          f = dot2_(av[i].x, wF[j].x, f); c = dot2_(av[i].x, wC[j].x, c);
          f = dot2_(av[i].y, wF[j].y, f); c = dot2_(av[i].y, wC[j].y, c);
          f = dot2_(av[i].z, wF[j].z, f); c = dot2_(av[i].z, wC[j].z, c);
          f = dot2_(av[i].w, wF[j].w, f); c = dot2_(av[i].w, wC[j].w, c);
          accF[i][j] = f; accC[i][j] = c;
        }
    }
    #pragma unroll
    for (int i = 0; i < 4; ++i){
      int r = rbase + rt + 16*i;
      #pragma unroll
      for (int j = 0; j < 4; ++j){
        heFC2[(size_t)r*64 + ct*4 + j] = pk_(accF[i][j] + biasF[j], accC[i][j] + biasC[j]);
      }
    }
  }
}

// ---------------- node projections (dot2): nFC2 packed fp16 ----------------
__global__ void k_node_lin(const u32* __restrict__ h16,
                           const float* __restrict__ Wf2, const float* __restrict__ Wc2,
                           u32* __restrict__ nFC2){
  __shared__ __align__(16) u32 As16[64*36];
  __shared__ __align__(16) u32 Ws16[128*36];
  int tid = threadIdx.x;
  for (int idx = tid; idx < 128*36; idx += 256){
    int c = idx/36, kk = idx - c*36;
    int k0 = 2*kk, k1 = 2*kk + 1;
    float w0 = 0.f, w1 = 0.f;
    if (k0 < 64) w0 = (c < 64) ? Wf2[k0*64 + c] : Wc2[k0*64 + (c-64)];
    if (k1 < 64) w1 = (c < 64) ? Wf2[k1*64 + c] : Wc2[k1*64 + (c-64)];
    Ws16[idx] = pk_(w0, w1);
  }
  int rt = tid & 15, ct = tid >> 4;
  const int ntiles = (N_NODES_ + 63)/64;
  for (int tile = blockIdx.x; tile < ntiles; tile += gridDim.x){
    int rbase = tile*64;
    __syncthreads();
    for (int idx = tid; idx < 64*36; idx += 256){
      int r = idx/36, kk = idx - r*36;
      int rg = rbase + r;
      As16[idx] = (rg < N_NODES_ && kk < 32) ? h16[(size_t)rg*32 + kk] : 0u;
    }
    __syncthreads();
    float accF[4][4] = {}, accC[4][4] = {};
    for (int kc = 0; kc < 8; ++kc){
      uint4 av[4], wF[4], wC[4];
      #pragma unroll
      for (int i = 0; i < 4; ++i) av[i] = *(const uint4*)&As16[(rt + 16*i)*36 + kc*4];
      #pragma unroll
      for (int j = 0; j < 4; ++j){
        wF[j] = *(const uint4*)&Ws16[(ct*4 + j)*36 + kc*4];
        wC[j] = *(const uint4*)&Ws16[(64 + ct*4 + j)*36 + kc*4];
      }
      #pragma unroll
      for (int i = 0; i < 4; ++i)
        #pragma unroll
        for (int j = 0; j < 4; ++j){
          float f = accF[i][j], c = accC[i][j];
          f = dot2_(av[i].x, wF[j].x, f); c = dot2_(av[i].x, wC[j].x, c);
          f = dot2_(av[i].y, wF[j].y, f); c = dot2_(av[i].y, wC[j].y, c);
          f = dot2_(av[i].z, wF[j].z, f); c = dot2_(av[i].z, wC[j].z, c);
          f = dot2_(av[i].w, wF[j].w, f); c = dot2_(av[i].w, wC[j].w, c);
          accF[i][j] = f; accC[i][j] = c;
        }
    }
    #pragma unroll
    for (int i = 0; i < 4; ++i){
      int r = rbase + rt + 16*i;
      if (r < N_NODES_){
        #pragma unroll
        for (int j = 0; j < 4; ++j){
          nFC2[(size_t)r*64 + ct*4 + j] = pk_(accF[i][j], accC[i][j]);
        }
      }
    }
  }
}

// ---------------- fused edge: node-CSR gather + gated act + mean + stats ------
__global__ void k_edge(const u32* __restrict__ nFC2, const u32* __restrict__ heFC2,
                       const int* __restrict__ node_off, const int* __restrict__ ndeg,
                       const int* __restrict__ edge_n, const float* __restrict__ ninv,
                       float* __restrict__ nmean, float* __restrict__ nstats){
  int lane = threadIdx.x & 63, wave = threadIdx.x >> 6;
  float s = 0.f, q = 0.f;
  for (int base = blockIdx.x*4; base < N_NODES_; base += gridDim.x*4){
    int n = base + wave;
    if (n < N_NODES_){
      int off = __builtin_amdgcn_readfirstlane(node_off[n]);
      int deg = __builtin_amdgcn_readfirstlane(ndeg[n]);
      u32 p0 = nFC2[(size_t)n*64 + lane];
      float f0 = lo_(p0), c0 = hi_(p0);
      float acc = 0.f;
      int i = 0;
      for (; i + 3 < deg; i += 4){
        int e0 = edge_n[off+i], e1 = edge_n[off+i+1], e2 = edge_n[off+i+2], e3 = edge_n[off+i+3];
        u32 a0 = heFC2[(size_t)e0*64 + lane];
        u32 a1 = heFC2[(size_t)e1*64 + lane];
        u32 a2 = heFC2[(size_t)e2*64 + lane];
        u32 a3 = heFC2[(size_t)e3*64 + lane];
        acc += gate_(f0 + lo_(a0), c0 + hi_(a0))
             + gate_(f0 + lo_(a1), c0 + hi_(a1))
             + gate_(f0 + lo_(a2), c0 + hi_(a2))
             + gate_(f0 + lo_(a3), c0 + hi_(a3));
      }
      for (; i < deg; ++i){
        u32 a = heFC2[(size_t)edge_n[off+i]*64 + lane];
        acc += gate_(f0 + lo_(a), c0 + hi_(a));
      }
      float m = acc * ninv[n];
      nmean[(size_t)n*64 + lane] = m;
      s += m; q += m*m;
    }
  }
  __shared__ float p1[256], p2[256];
  p1[threadIdx.x] = s; p2[threadIdx.x] = q;
  __syncthreads();
  if (wave == 0){
    float a = p1[lane] + p1[64+lane] + p1[128+lane] + p1[192+lane];
    float b = p2[lane] + p2[64+lane] + p2[128+lane] + p2[192+lane];
    atomicAdd(&nstats[lane], a);
    atomicAdd(&nstats[64+lane], b);
  }
}

__global__ void k_bn_fin_node(const float* __restrict__ stats, const float* __restrict__ g,
                              const float* __restrict__ bt, float* __restrict__ ab, float invN){
  int j = threadIdx.x;
  if (j >= 64) return;
  float m = stats[j]*invN;
  float var = stats[64+j]*invN - m*m;
  float a = g[j]*rsqrtf(var + 1e-5f);
  ab[j] = a; ab[64+j] = bt[j] - m*a;
}

// ---------------- node update: h' = softplus(BN(mean) + h), + fp16 mirror ----------------
__global__ void k_node_update(const float* __restrict__ nmean, const float* __restrict__ ab,
                              const float* __restrict__ h, float* __restrict__ hout,
                              u32* __restrict__ h16out){
  int t = blockIdx.x*256 + threadIdx.x;
  if (t >= N_NODES_*32) return;
  int p = t & 31;
  int f0 = 2*p, f1 = 2*p + 1;
  float2 nm = ((const float2*)nmean)[t];
  float2 hh = ((const float2*)h)[t];
  float r0 = sp_(ab[f0]*nm.x + ab[64+f0] + hh.x);
  float r1 = sp_(ab[f1]*nm.y + ab[64+f1] + hh.y);
  float2 st; st.x = r0; st.y = r1;
  ((float2*)hout)[t] = st;
  h16out[t] = pk_(r0, r1);
}

// ---------------- graph mean + head ----------------
__global__ void k_graph_agg(const float* __restrict__ h, const int* __restrict__ batch,
                            float* __restrict__ gsum){
  int t = blockIdx.x*256 + threadIdx.x;
  int n = t >> 6; if (n >= N_NODES_) return;
  int f = t & 63;
  atomicAdd(&gsum[(size_t)batch[n]*64+f], h[t]);
}

__global__ void k_head(const float* __restrict__ gsum, const int* __restrict__ gcnt,
                       const float* __restrict__ Wl2, const float* __restrict__ bl2,
                       const float* __restrict__ Wo, const float* __restrict__ bo,
                       float* __restrict__ out){
  __shared__ float gm[64];
  __shared__ float red[128];
  int g = blockIdx.x, j = threadIdx.x;
  if (j < 64) gm[j] = gsum[(size_t)g*64+j] / fmaxf((float)gcnt[g], 1.f);
  __syncthreads();
  float u = bl2[j];
  for (int f = 0; f < 64; ++f) u += gm[f]*Wl2[f*128+j];
  red[j] = sp_(u)*Wo[j];
  __syncthreads();
  for (int s = 64; s > 0; s >>= 1){
    if (j < s) red[j] += red[j+s];
    __syncthreads();
  }
  if (j == 0) out[g] = red[0] + bo[0];
}

extern "C" void kernel_launch(void* const* d_in, const int* in_sizes, int n_in,
                              void* d_out, int out_size, void* d_ws, size_t ws_size,
                              hipStream_t stream){
  (void)in_sizes; (void)n_in; (void)out_size; (void)ws_size;
  const float* x      = (const float*)d_in[0];
  const int*   ni     = (const int*)d_in[1];
  const int*   hi     = ni + E_;
  const float* hattr  = (const float*)d_in[2];
  const int*   batch  = (const int*)d_in[3];
  const float* We     = (const float*)d_in[4];
  const float* be     = (const float*)d_in[5];
  const float* Wf1    = (const float*)d_in[6];
  const float* bf1    = (const float*)d_in[7];
  const float* Wc1    = (const float*)d_in[8];
  const float* bc1    = (const float*)d_in[9];
  const float* Wf2    = (const float*)d_in[10];
  const float* bf2    = (const float*)d_in[11];
  const float* Wc2    = (const float*)d_in[12];
  const float* bc2    = (const float*)d_in[13];
  const float* bn_f_g = (const float*)d_in[14];
  const float* bn_f_b = (const float*)d_in[15];
  const float* bn_c_g = (const float*)d_in[16];
  const float* bn_c_b = (const float*)d_in[17];
  const float* bn_o_g = (const float*)d_in[18];
  const float* bn_o_b = (const float*)d_in[19];
  const float* Wl2    = (const float*)d_in[20];
  const float* bl2    = (const float*)d_in[21];
  const float* Wo     = (const float*)d_in[22];
  const float* bo     = (const float*)d_in[23];

  float* ws = (float*)d_ws;
  size_t o = 0;
  float* h0    = ws + o; o += (size_t)N_NODES_*H_;
  float* h1    = ws + o; o += (size_t)N_NODES_*H_;
  float* tfc   = ws + o; o += (size_t)N_HEDGES_*70;    // 14.0M floats
  u32*   nFC2  = (u32*)tfc;                            // alias: layer-time
  u32*   pairN = (u32*)tfc;                            // alias: CSR-build-time only
  u32*   pairH = ((u32*)tfc) + E_;
  float* hmR   = ws + o; o += (size_t)N_HEDGES_*H_;    // 12.8M floats region
  u32*   hmean16 = (u32*)hmR;
  u32*   heFC2   = (u32*)hmR;                          // hmean16 dead before heFC2 written
  float* nmean = ws + o; o += (size_t)N_NODES_*H_;
  u32*  h16a   = (u32*)(ws + o); o += (size_t)N_NODES_*32;
  u32*  h16b   = (u32*)(ws + o); o += (size_t)N_NODES_*32;
  u32*  hattr16= (u32*)(ws + o); o += (size_t)N_HEDGES_*18;
  float* hstats = ws + o; o += 256;
  float* habs   = ws + o; o += 256;
  float* nstats = ws + o; o += 128;
  float* nabs   = ws + o; o += 128;
  float* gsum   = ws + o; o += (size_t)G_*H_;
  float* hinv   = ws + o; o += N_HEDGES_;
  float* ninv   = ws + o; o += N_NODES_;
  int* hcnt     = (int*)(ws + o); o += N_HEDGES_;
  int* ndeg     = (int*)(ws + o); o += N_NODES_;
  int* gcnt     = (int*)(ws + o); o += G_;
  int* node_off = (int*)(ws + o); o += N_NODES_;
  int* hedge_off= (int*)(ws + o); o += N_HEDGES_;
  int* bcurN    = (int*)(ws + o); o += NB_N_;
  int* bcurH    = (int*)(ws + o); o += NB_H_;
  int* bsumA    = (int*)(ws + o); o += 1024;
  int* bsumB    = (int*)(ws + o); o += 1024;
  int* edge_n   = (int*)(ws + o); o += E_;
  int* edge_h   = (int*)(ws + o); o += E_;

  hipMemsetAsync(hcnt, 0, sizeof(int)*N_HEDGES_, stream);
  hipMemsetAsync(ndeg, 0, sizeof(int)*N_NODES_, stream);
  hipMemsetAsync(gcnt, 0, sizeof(int)*G_, stream);
  hipMemsetAsync(gsum, 0, sizeof(float)*G_*H_, stream);

  k_counts<<<2048, 256, 0, stream>>>(ni, hi, hcnt, ndeg);
  k_gcnt<<<(N_NODES_+255)/256, 256, 0, stream>>>(batch, gcnt);
  k_inv<<<(N_HEDGES_+255)/256, 256, 0, stream>>>(hcnt, ndeg, hinv, ninv);
  k_hattr_pack<<<(N_HEDGES_*18+255)/256, 256, 0, stream>>>(hattr, hattr16);

  // CSR offsets
  k_scan1<<<(N_NODES_+255)/256, 256, 0, stream>>>(ndeg, N_NODES_, node_off, bsumA);
  k_scan2<<<1, 1024, 0, stream>>>(bsumA, (N_NODES_+255)/256);
  k_scan3<<<(N_NODES_+255)/256, 256, 0, stream>>>(node_off, bsumA, N_NODES_);
  k_scan1<<<(N_HEDGES_+255)/256, 256, 0, stream>>>(hcnt, N_HEDGES_, hedge_off, bsumB);
  k_scan2<<<1, 1024, 0, stream>>>(bsumB, (N_HEDGES_+255)/256);
  k_scan3<<<(N_HEDGES_+255)/256, 256, 0, stream>>>(hedge_off, bsumB, N_HEDGES_);

  // bucketed, XCD-partitioned CSR fill (write-coalesced per XCD)
  k_bucket_init<<<(NB_H_+255)/256, 256, 0, stream>>>(node_off, hedge_off, bcurN, bcurH);
  k_binfill<<<2048, 256, 0, stream>>>(ni, hi, bcurN, bcurH, pairN, pairH);
  k_csrfill<<<NB_N_, 256, 0, stream>>>(node_off, bcurN, pairN, N_NODES_, edge_n);
  k_csrfill<<<NB_H_, 256, 0, stream>>>(hedge_off, bcurH, pairH, N_HEDGES_, edge_h);

  k_embed<<<768, 256, 0, stream>>>(x, We, be, h0, h16a);

  float* hcur2 = h0;  u32* hc16 = h16a;
  float* hnxt  = h1;  u32* hn16 = h16b;
  for (int l = 0; l < L_; ++l){
    const float* Wf1l = Wf1 + (size_t)l*D_*HE_;
    const float* Wc1l = Wc1 + (size_t)l*D_*HE_;
    const float* Wf2l = Wf2 + (size_t)l*D_*H_;
    const float* Wc2l = Wc2 + (size_t)l*D_*H_;

    hipMemsetAsync(hstats, 0, sizeof(float)*160, stream);
    hipMemsetAsync(nstats, 0, sizeof(float)*128, stream);

    k_gather_hedge<<<(N_HEDGES_*16)/256, 256, 0, stream>>>(hc16, hedge_off, hcnt, edge_h,
                                                           hinv, hmean16);
    k_hedge_mlp1<<<1280, 256, 0, stream>>>(hmean16, hattr16, Wf1l, bf1 + l*HE_,
                                           Wc1l, bc1 + l*HE_, tfc, hstats);
    k_bn_fin_hedge<<<1, 128, 0, stream>>>(hstats, bn_f_g + l*HE_, bn_f_b + l*HE_,
                                          bn_c_g + l*HE_, bn_c_b + l*HE_, habs,
                                          1.f/(float)N_HEDGES_);
    k_hedge_feats<<<1536, 256, 0, stream>>>(tfc, habs, Wf2l, bf2 + l*H_,
                                            Wc2l, bc2 + l*H_, heFC2);
    k_node_lin<<<1024, 256, 0, stream>>>(hc16, Wf2l, Wc2l, nFC2);
    k_edge<<<2048, 256, 0, stream>>>(nFC2, heFC2, node_off, ndeg, edge_n, ninv, nmean, nstats);
    k_bn_fin_node<<<1, 64, 0, stream>>>(nstats, bn_o_g + l*H_, bn_o_b + l*H_, nabs,
                                        1.f/(float)N_NODES_);
    k_node_update<<<(N_NODES_*32+255)/256, 256, 0, stream>>>(nmean, nabs, hcur2, hnxt, hn16);
    float* t2 = hcur2; hcur2 = hnxt; hnxt = t2;
    u32* t3 = hc16; hc16 = hn16; hn16 = t3;
  }

  k_graph_agg<<<(N_NODES_*H_+255)/256, 256, 0, stream>>>(hcur2, batch, gsum);
  k_head<<<G_, 128, 0, stream>>>(gsum, gcnt, Wl2, bl2, Wo, bo, (float*)d_out);
}

// Round 10
// 1434.166 us; speedup vs baseline: 1.1358x; 1.1358x over previous
//
#include <hip/hip_runtime.h>
#include <cstddef>

#define N_NODES_  100000
#define N_HEDGES_ 200000
#define E_        1200000
#define G_        512
#define H_        64
#define HE_       35
#define D_        99      // H_+HE_
#define HOUT_     128
#define L_        3
#define NBN5_     196     // ceil(N_NODES/512)
#define NBH5_     391     // ceil(N_HEDGES/512)
#define CHUNK_    4096

typedef unsigned int u32;
typedef _Float16 f2_t __attribute__((ext_vector_type(2)));

__device__ __forceinline__ float sigm_(float x){
  return __builtin_amdgcn_rcpf(1.f + __expf(-x));
}
__device__ __forceinline__ float sp_(float x){
  return fmaxf(x, 0.f) + __logf(1.f + __expf(-fabsf(x)));
}
__device__ __forceinline__ float gate_(float F, float C){ return sigm_(F)*sp_(C); }

__device__ __forceinline__ u32 pk_(float a, float b){
  return __builtin_bit_cast(u32, __builtin_amdgcn_cvt_pkrtz(a, b));
}
__device__ __forceinline__ float dot2_(u32 a, u32 b, float c){
#if __has_builtin(__builtin_amdgcn_fdot2)
  return __builtin_amdgcn_fdot2(__builtin_bit_cast(f2_t, a),
                                __builtin_bit_cast(f2_t, b), c, false);
#else
  f2_t x = __builtin_bit_cast(f2_t, a), y = __builtin_bit_cast(f2_t, b);
  return c + (float)x[0]*(float)y[0] + (float)x[1]*(float)y[1];
#endif
}
__device__ __forceinline__ float lo_(u32 a){ return (float)__builtin_bit_cast(f2_t, a)[0]; }
__device__ __forceinline__ float hi_(u32 a){ return (float)__builtin_bit_cast(f2_t, a)[1]; }

// ---------------- per-call counts (simple; binfill dominates, not this) ----------------
__global__ void k_counts(const int* __restrict__ ni, const int* __restrict__ hi,
                         int* __restrict__ hcnt, int* __restrict__ ndeg){
  int e = blockIdx.x*256 + threadIdx.x;
  if (e >= E_) return;
  atomicAdd(&hcnt[hi[e]], 1);
  atomicAdd(&ndeg[ni[e]], 1);
}
__global__ void k_gcnt(const int* __restrict__ batch, int* __restrict__ gcnt){
  int n = blockIdx.x*256 + threadIdx.x;
  if (n < N_NODES_) atomicAdd(&gcnt[batch[n]], 1);
}
__global__ void k_inv(const int* __restrict__ hcnt, const int* __restrict__ ndeg,
                      float* __restrict__ hinv, float* __restrict__ ninv){
  int i = blockIdx.x*256 + threadIdx.x;
  if (i < N_HEDGES_) hinv[i] = 1.f/fmaxf((float)hcnt[i], 1.f);
  if (i < N_NODES_)  ninv[i] = 1.f/fmaxf((float)ndeg[i], 1.f);
}

// ---------------- CSR build: scan ----------------
__global__ void k_scan1(const int* __restrict__ cnt, int n, int* __restrict__ off,
                        int* __restrict__ bsum){
  __shared__ int tmp[256];
  int i = blockIdx.x*256 + threadIdx.x;
  int v = (i < n) ? cnt[i] : 0;
  tmp[threadIdx.x] = v;
  __syncthreads();
  for (int d = 1; d < 256; d <<= 1){
    int t = (threadIdx.x >= d) ? tmp[threadIdx.x - d] : 0;
    __syncthreads();
    tmp[threadIdx.x] += t;
    __syncthreads();
  }
  if (i < n) off[i] = tmp[threadIdx.x] - v;
  if (threadIdx.x == 255) bsum[blockIdx.x] = tmp[255];
}
__global__ void k_scan2(int* __restrict__ bsum, int nb){
  __shared__ int tmp[1024];
  int t = threadIdx.x;
  int v = (t < nb) ? bsum[t] : 0;
  tmp[t] = v;
  __syncthreads();
  for (int d = 1; d < 1024; d <<= 1){
    int x = (t >= d) ? tmp[t - d] : 0;
    __syncthreads();
    tmp[t] += x;
    __syncthreads();
  }
  if (t < nb) bsum[t] = tmp[t] - v;
}
__global__ void k_scan3(int* __restrict__ off, const int* __restrict__ bsum, int n){
  int i = blockIdx.x*256 + threadIdx.x;
  if (i < n) off[i] += bsum[blockIdx.x];
}

// ---------------- bucketed CSR fill: per-block reserved contiguous runs ----------------
__global__ void k_bucket_init(const int* __restrict__ node_off, const int* __restrict__ hedge_off,
                              int* __restrict__ gcurN, int* __restrict__ gcurH){
  int b = blockIdx.x*256 + threadIdx.x;
  if (b < NBN5_) gcurN[b] = node_off[b*512];
  if (b < NBH5_) gcurH[b] = hedge_off[b*512];
}
// pair encoding: (local_row_9b << 18) | id (< 2^18)
__global__ void k_binfill(const int* __restrict__ ni, const int* __restrict__ hi,
                          int* __restrict__ gcurN, int* __restrict__ gcurH,
                          u32* __restrict__ pairN, u32* __restrict__ pairH){
  __shared__ int histN[NBN5_], histH[NBH5_];
  __shared__ int baseN[NBN5_], baseH[NBH5_];
  const int nchunks = (E_ + CHUNK_ - 1)/CHUNK_;
  for (int c = blockIdx.x; c < nchunks; c += gridDim.x){
    int e0 = c*CHUNK_;
    int e1 = e0 + CHUNK_; if (e1 > E_) e1 = E_;
    for (int i = threadIdx.x; i < NBN5_; i += 256) histN[i] = 0;
    for (int i = threadIdx.x; i < NBH5_; i += 256) histH[i] = 0;
    __syncthreads();
    for (int e = e0 + threadIdx.x; e < e1; e += 256){
      atomicAdd(&histN[ni[e] >> 9], 1);
      atomicAdd(&histH[hi[e] >> 9], 1);
    }
    __syncthreads();
    for (int i = threadIdx.x; i < NBN5_; i += 256){
      int hv = histN[i];
      baseN[i] = hv ? atomicAdd(&gcurN[i], hv) : 0;
      histN[i] = 0;
    }
    for (int i = threadIdx.x; i < NBH5_; i += 256){
      int hv = histH[i];
      baseH[i] = hv ? atomicAdd(&gcurH[i], hv) : 0;
      histH[i] = 0;
    }
    __syncthreads();
    for (int e = e0 + threadIdx.x; e < e1; e += 256){
      int n = ni[e], he = hi[e];
      int bn = n >> 9, bh = he >> 9;
      int pn = baseN[bn] + atomicAdd(&histN[bn], 1);
      pairN[pn] = ((u32)(n & 511) << 18) | (u32)he;
      int ph = baseH[bh] + atomicAdd(&histH[bh], 1);
      pairH[ph] = ((u32)(he & 511) << 18) | (u32)n;
    }
    __syncthreads();
  }
}
// one block per 512-row bucket; LDS cursors; 24KB hot dest window
__global__ void k_csrfill(const int* __restrict__ off_arr, const int* __restrict__ gcur,
                          const u32* __restrict__ pair, int nrows, int* __restrict__ out){
  __shared__ int cur[512];
  int b = blockIdx.x, t = threadIdx.x;
  int nb = b*512;
  for (int i = t; i < 512; i += 256){
    int idx = nb + i;
    cur[i] = (idx < nrows) ? off_arr[idx] : 0;
  }
  __syncthreads();
  int base = off_arr[nb];
  int end  = gcur[b];
  for (int pos = base + t; pos < end; pos += 256){
    u32 p = pair[pos];
    int idx = atomicAdd(&cur[p >> 18], 1);
    out[idx] = (int)(p & 0x3FFFFu);
  }
}

// ---------------- pack hattr to fp16 pairs [NH][18] ----------------
__global__ void k_hattr_pack(const float* __restrict__ hattr, u32* __restrict__ hattr16){
  int i = blockIdx.x*256 + threadIdx.x;
  if (i >= N_HEDGES_*18) return;
  int he = i/18, p = i - he*18;
  int k0 = 2*p, k1 = 2*p + 1;
  float w0 = (k0 < 35) ? hattr[(size_t)he*35 + k0] : 0.f;
  float w1 = (k1 < 35) ? hattr[(size_t)he*35 + k1] : 0.f;
  hattr16[i] = pk_(w0, w1);
}

// ---------------- embed: h = x @ We + be ; also packed fp16 mirror ----------------
__global__ void k_embed(const float* __restrict__ x, const float* __restrict__ We,
                        const float* __restrict__ be, float* __restrict__ h,
                        u32* __restrict__ h16){
  __shared__ __align__(16) float As[64*100];
  __shared__ __align__(16) float Ws[64*100];
  int tid = threadIdx.x;
  for (int idx = tid; idx < 64*100; idx += 256){
    int c = idx/100, k = idx - c*100;
    Ws[idx] = (k < 92) ? We[k*64 + c] : 0.f;
  }
  int rt = tid & 15, ct = tid >> 4;
  float bias[4];
  #pragma unroll
  for (int j = 0; j < 4; ++j) bias[j] = be[ct*4 + j];
  const int ntiles = (N_NODES_ + 63)/64;
  for (int tile = blockIdx.x; tile < ntiles; tile += gridDim.x){
    int rbase = tile*64;
    __syncthreads();
    for (int idx = tid; idx < 64*100; idx += 256){
      int r = idx/100, k = idx - r*100;
      int rg = rbase + r;
      As[idx] = (rg < N_NODES_ && k < 92) ? x[(size_t)rg*92 + k] : 0.f;
    }
    __syncthreads();
    float acc[4][4] = {};
    for (int kc = 0; kc < 25; ++kc){
      float4 av[4], wv[4];
      #pragma unroll
      for (int i = 0; i < 4; ++i) av[i] = *(const float4*)&As[(rt + 16*i)*100 + kc*4];
      #pragma unroll
      for (int j = 0; j < 4; ++j) wv[j] = *(const float4*)&Ws[(ct*4 + j)*100 + kc*4];
      #pragma unroll
      for (int i = 0; i < 4; ++i)
        #pragma unroll
        for (int j = 0; j < 4; ++j)
          acc[i][j] += av[i].x*wv[j].x + av[i].y*wv[j].y + av[i].z*wv[j].z + av[i].w*wv[j].w;
    }
    #pragma unroll
    for (int i = 0; i < 4; ++i){
      int r = rbase + rt + 16*i;
      if (r < N_NODES_){
        float4 st;
        st.x = acc[i][0] + bias[0]; st.y = acc[i][1] + bias[1];
        st.z = acc[i][2] + bias[2]; st.w = acc[i][3] + bias[3];
        *(float4*)&h[(size_t)r*64 + ct*4] = st;
        h16[(size_t)r*32 + ct*2]     = pk_(st.x, st.y);
        h16[(size_t)r*32 + ct*2 + 1] = pk_(st.z, st.w);
      }
    }
  }
}

// ---------------- hedge gather (fp16, uint2): hmean16[he] = mean of h16 rows ----------------
__global__ void __launch_bounds__(256) k_gather_hedge(
    const u32* __restrict__ h16, const int* __restrict__ hedge_off,
    const int* __restrict__ hcnt, const int* __restrict__ edge_h,
    const float* __restrict__ hinv, u32* __restrict__ hmean16){
  int w = (blockIdx.x*256 + threadIdx.x) >> 4;
  int p = threadIdx.x & 15;
  if (w >= N_HEDGES_) return;
  int off = hedge_off[w], deg = hcnt[w];
  float a0 = 0.f, a1 = 0.f, a2 = 0.f, a3 = 0.f;
  int i = 0;
  for (; i + 1 < deg; i += 2){
    int n0 = edge_h[off+i], n1 = edge_h[off+i+1];
    uint2 u0 = *(const uint2*)&h16[(size_t)n0*32 + 2*p];
    uint2 u1 = *(const uint2*)&h16[(size_t)n1*32 + 2*p];
    a0 += lo_(u0.x) + lo_(u1.x); a1 += hi_(u0.x) + hi_(u1.x);
    a2 += lo_(u0.y) + lo_(u1.y); a3 += hi_(u0.y) + hi_(u1.y);
  }
  if (i < deg){
    uint2 u = *(const uint2*)&h16[(size_t)edge_h[off+i]*32 + 2*p];
    a0 += lo_(u.x); a1 += hi_(u.x); a2 += lo_(u.y); a3 += hi_(u.y);
  }
  float inv = hinv[w];
  uint2 st; st.x = pk_(a0*inv, a1*inv); st.y = pk_(a2*inv, a3*inv);
  *(uint2*)&hmean16[(size_t)w*32 + 2*p] = st;
}

// ---------------- hedge MLP pre-BN (dot2): tfc = [msg@Wf1|msg@Wc1]+b, col stats ----------
__global__ void k_hedge_mlp1(const u32* __restrict__ hmean16, const u32* __restrict__ hattr16,
                             const float* __restrict__ Wf1, const float* __restrict__ bf1,
                             const float* __restrict__ Wc1, const float* __restrict__ bc1,
                             float* __restrict__ tfc, float* __restrict__ hstats){
  __shared__ __align__(16) u32 As16[64*52];
  __shared__ __align__(16) u32 Ws16[80*52];
  __shared__ float sstat[160];
  int tid = threadIdx.x;
  for (int idx = tid; idx < 80*52; idx += 256){
    int c = idx/52, kk = idx - c*52;
    int k0 = 2*kk, k1 = 2*kk + 1;
    float w0 = 0.f, w1 = 0.f;
    if (c < 70){
      if (k0 < 99) w0 = (c < 35) ? Wf1[k0*35 + c] : Wc1[k0*35 + (c-35)];
      if (k1 < 99) w1 = (c < 35) ? Wf1[k1*35 + c] : Wc1[k1*35 + (c-35)];
    }
    Ws16[idx] = pk_(w0, w1);
  }
  for (int idx = tid; idx < 160; idx += 256) sstat[idx] = 0.f;
  int rt = tid & 15, ct = tid >> 4;
  float bias[5];
  #pragma unroll
  for (int j = 0; j < 5; ++j){
    int c = ct*5 + j;
    bias[j] = (c < 35) ? bf1[c] : (c < 70 ? bc1[c - 35] : 0.f);
  }
  for (int tile = blockIdx.x; tile < N_HEDGES_/64; tile += gridDim.x){
    int rbase = tile*64;
    __syncthreads();
    for (int idx = tid; idx < 64*52; idx += 256){
      int r = idx/52, kk = idx - r*52;
      int rg = rbase + r;
      u32 v = 0;
      if (kk < 32)      v = hmean16[(size_t)rg*32 + kk];
      else if (kk < 50) v = hattr16[(size_t)rg*18 + (kk - 32)];
      As16[idx] = v;
    }
    __syncthreads();
    float acc[4][5] = {};
    for (int kc = 0; kc < 13; ++kc){
      uint4 av[4], wv[5];
      #pragma unroll
      for (int i = 0; i < 4; ++i) av[i] = *(const uint4*)&As16[(rt + 16*i)*52 + kc*4];
      #pragma unroll
      for (int j = 0; j < 5; ++j) wv[j] = *(const uint4*)&Ws16[(ct*5 + j)*52 + kc*4];
      #pragma unroll
      for (int i = 0; i < 4; ++i)
        #pragma unroll
        for (int j = 0; j < 5; ++j){
          float a = acc[i][j];
          a = dot2_(av[i].x, wv[j].x, a);
          a = dot2_(av[i].y, wv[j].y, a);
          a = dot2_(av[i].z, wv[j].z, a);
          a = dot2_(av[i].w, wv[j].w, a);
          acc[i][j] = a;
        }
    }
    #pragma unroll
    for (int j = 0; j < 5; ++j){
      int c = ct*5 + j;
      if (c < 70){
        float s = 0.f, q = 0.f;
        #pragma unroll
        for (int i = 0; i < 4; ++i){
          float v = acc[i][j] + bias[j];
          int r = rbase + rt + 16*i;
          tfc[(size_t)r*70 + c] = v;
          s += v; q += v*v;
        }
        atomicAdd(&sstat[c], s);
        atomicAdd(&sstat[80 + c], q);
      }
    }
  }
  __syncthreads();
  for (int idx = tid; idx < 160; idx += 256) atomicAdd(&hstats[idx], sstat[idx]);
}

// ---------------- BN finalize (hedge) ----------------
__global__ void k_bn_fin_hedge(const float* __restrict__ stats,
                               const float* __restrict__ gf, const float* __restrict__ btf,
                               const float* __restrict__ gc, const float* __restrict__ btc,
                               float* __restrict__ ab, float invN){
  int j = threadIdx.x;
  if (j >= 70) return;
  float m = stats[j]*invN;
  float var = stats[80+j]*invN - m*m;
  float gg = (j < 35) ? gf[j] : gc[j-35];
  float bb = (j < 35) ? btf[j] : btc[j-35];
  float a = gg*rsqrtf(var + 1e-5f);
  ab[j] = a; ab[70+j] = bb - m*a;
}

// ---------------- hedge feats + project (dot2): heFC2 packed fp16 ------------
__global__ void k_hedge_feats(const float* __restrict__ tfc, const float* __restrict__ ab,
                              const float* __restrict__ Wf2, const float* __restrict__ bf2,
                              const float* __restrict__ Wc2, const float* __restrict__ bc2,
                              u32* __restrict__ heFC2){
  __shared__ __align__(16) u32 As16[64*20];
  __shared__ __align__(16) u32 Ws16[128*20];
  int tid = threadIdx.x;
  for (int idx = tid; idx < 128*20; idx += 256){
    int c = idx/20, kk = idx - c*20;
    int k0 = 2*kk, k1 = 2*kk + 1;
    float w0 = 0.f, w1 = 0.f;
    if (k0 < 35) w0 = (c < 64) ? Wf2[(64+k0)*64 + c] : Wc2[(64+k0)*64 + (c-64)];
    if (k1 < 35) w1 = (c < 64) ? Wf2[(64+k1)*64 + c] : Wc2[(64+k1)*64 + (c-64)];
    Ws16[idx] = pk_(w0, w1);
  }
  int rt = tid & 15, ct = tid >> 4;
  float biasF[4], biasC[4];
  #pragma unroll
  for (int j = 0; j < 4; ++j){ biasF[j] = bf2[ct*4 + j]; biasC[j] = bc2[ct*4 + j]; }
  for (int tile = blockIdx.x; tile < N_HEDGES_/64; tile += gridDim.x){
    int rbase = tile*64;
    __syncthreads();
    for (int idx = tid; idx < 64*20; idx += 256){
      int r = idx/20, kk = idx - r*20;
      int rg = rbase + r;
      int k0 = 2*kk, k1 = 2*kk + 1;
      float a0 = 0.f, a1 = 0.f;
      if (k0 < 35){
        float zf = ab[k0]    * tfc[(size_t)rg*70 + k0]      + ab[70 + k0];
        float zc = ab[35+k0] * tfc[(size_t)rg*70 + 35 + k0] + ab[105 + k0];
        a0 = gate_(zf, zc);
      }
      if (k1 < 35){
        float zf = ab[k1]    * tfc[(size_t)rg*70 + k1]      + ab[70 + k1];
        float zc = ab[35+k1] * tfc[(size_t)rg*70 + 35 + k1] + ab[105 + k1];
        a1 = gate_(zf, zc);
      }
      As16[idx] = pk_(a0, a1);
    }
    __syncthreads();
    float accF[4][4] = {}, accC[4][4] = {};
    for (int kc = 0; kc < 5; ++kc){
      uint4 av[4], wF[4], wC[4];
      #pragma unroll
      for (int i = 0; i < 4; ++i) av[i] = *(const uint4*)&As16[(rt + 16*i)*20 + kc*4];
      #pragma unroll
      for (int j = 0; j < 4; ++j){
        wF[j] = *(const uint4*)&Ws16[(ct*4 + j)*20 + kc*4];
        wC[j] = *(const uint4*)&Ws16[(64 + ct*4 + j)*20 + kc*4];
      }
      #pragma unroll
      for (int i = 0; i < 4; ++i)
        #pragma unroll
        for (int j = 0; j < 4; ++j){
          float f = accF[i][j], c = accC[i][j];
          f = dot2_(av[i].x, wF[j].x, f); c = dot2_(av[i].x, wC[j].x, c);
          f = dot2_(av[i].y, wF[j].y, f); c = dot2_(av[i].y, wC[j].y, c);
          f = dot2_(av[i].z, wF[j].z, f); c = dot2_(av[i].z, wC[j].z, c);
          f = dot2_(av[i].w, wF[j].w, f); c = dot2_(av[i].w, wC[j].w, c);
          accF[i][j] = f; accC[i][j] = c;
        }
    }
    #pragma unroll
    for (int i = 0; i < 4; ++i){
      int r = rbase + rt + 16*i;
      #pragma unroll
      for (int j = 0; j < 4; ++j){
        heFC2[(size_t)r*64 + ct*4 + j] = pk_(accF[i][j] + biasF[j], accC[i][j] + biasC[j]);
      }
    }
  }
}

// ---------------- node projections (dot2): nFC2 packed fp16 ----------------
__global__ void k_node_lin(const u32* __restrict__ h16,
                           const float* __restrict__ Wf2, const float* __restrict__ Wc2,
                           u32* __restrict__ nFC2){
  __shared__ __align__(16) u32 As16[64*36];
  __shared__ __align__(16) u32 Ws16[128*36];
  int tid = threadIdx.x;
  for (int idx = tid; idx < 128*36; idx += 256){
    int c = idx/36, kk = idx - c*36;
    int k0 = 2*kk, k1 = 2*kk + 1;
    float w0 = 0.f, w1 = 0.f;
    if (k0 < 64) w0 = (c < 64) ? Wf2[k0*64 + c] : Wc2[k0*64 + (c-64)];
    if (k1 < 64) w1 = (c < 64) ? Wf2[k1*64 + c] : Wc2[k1*64 + (c-64)];
    Ws16[idx] = pk_(w0, w1);
  }
  int rt = tid & 15, ct = tid >> 4;
  const int ntiles = (N_NODES_ + 63)/64;
  for (int tile = blockIdx.x; tile < ntiles; tile += gridDim.x){
    int rbase = tile*64;
    __syncthreads();
    for (int idx = tid; idx < 64*36; idx += 256){
      int r = idx/36, kk = idx - r*36;
      int rg = rbase + r;
      As16[idx] = (rg < N_NODES_ && kk < 32) ? h16[(size_t)rg*32 + kk] : 0u;
    }
    __syncthreads();
    float accF[4][4] = {}, accC[4][4] = {};
    for (int kc = 0; kc < 8; ++kc){
      uint4 av[4], wF[4], wC[4];
      #pragma unroll
      for (int i = 0; i < 4; ++i) av[i] = *(const uint4*)&As16[(rt + 16*i)*36 + kc*4];
      #pragma unroll
      for (int j = 0; j < 4; ++j){
        wF[j] = *(const uint4*)&Ws16[(ct*4 + j)*36 + kc*4];
        wC[j] = *(const uint4*)&Ws16[(64 + ct*4 + j)*36 + kc*4];
      }
      #pragma unroll
      for (int i = 0; i < 4; ++i)
        #pragma unroll
        for (int j = 0; j < 4; ++j){
          float f = accF[i][j], c = accC[i][j];
          f = dot2_(av[i].x, wF[j].x, f); c = dot2_(av[i].x, wC[j].x, c);
          f = dot2_(av[i].y, wF[j].y, f); c = dot2_(av[i].y, wC[j].y, c);
          f = dot2_(av[i].z, wF[j].z, f); c = dot2_(av[i].z, wC[j].z, c);
          f = dot2_(av[i].w, wF[j].w, f); c = dot2_(av[i].w, wC[j].w, c);
          accF[i][j] = f; accC[i][j] = c;
        }
    }
    #pragma unroll
    for (int i = 0; i < 4; ++i){
      int r = rbase + rt + 16*i;
      if (r < N_NODES_){
        #pragma unroll
        for (int j = 0; j < 4; ++j){
          nFC2[(size_t)r*64 + ct*4 + j] = pk_(accF[i][j], accC[i][j]);
        }
      }
    }
  }
}

// ---------------- fused edge: node-CSR gather + gated act + mean + stats ------
__global__ void k_edge(const u32* __restrict__ nFC2, const u32* __restrict__ heFC2,
                       const int* __restrict__ node_off, const int* __restrict__ ndeg,
                       const int* __restrict__ edge_n, const float* __restrict__ ninv,
                       float* __restrict__ nmean, float* __restrict__ nstats){
  int lane = threadIdx.x & 63, wave = threadIdx.x >> 6;
  float s = 0.f, q = 0.f;
  for (int base = blockIdx.x*4; base < N_NODES_; base += gridDim.x*4){
    int n = base + wave;
    if (n < N_NODES_){
      int off = __builtin_amdgcn_readfirstlane(node_off[n]);
      int deg = __builtin_amdgcn_readfirstlane(ndeg[n]);
      u32 p0 = nFC2[(size_t)n*64 + lane];
      float f0 = lo_(p0), c0 = hi_(p0);
      float acc = 0.f;
      int i = 0;
      for (; i + 3 < deg; i += 4){
        int e0 = edge_n[off+i], e1 = edge_n[off+i+1], e2 = edge_n[off+i+2], e3 = edge_n[off+i+3];
        u32 a0 = heFC2[(size_t)e0*64 + lane];
        u32 a1 = heFC2[(size_t)e1*64 + lane];
        u32 a2 = heFC2[(size_t)e2*64 + lane];
        u32 a3 = heFC2[(size_t)e3*64 + lane];
        acc += gate_(f0 + lo_(a0), c0 + hi_(a0))
             + gate_(f0 + lo_(a1), c0 + hi_(a1))
             + gate_(f0 + lo_(a2), c0 + hi_(a2))
             + gate_(f0 + lo_(a3), c0 + hi_(a3));
      }
      for (; i < deg; ++i){
        u32 a = heFC2[(size_t)edge_n[off+i]*64 + lane];
        acc += gate_(f0 + lo_(a), c0 + hi_(a));
      }
      float m = acc * ninv[n];
      nmean[(size_t)n*64 + lane] = m;
      s += m; q += m*m;
    }
  }
  __shared__ float p1[256], p2[256];
  p1[threadIdx.x] = s; p2[threadIdx.x] = q;
  __syncthreads();
  if (wave == 0){
    float a = p1[lane] + p1[64+lane] + p1[128+lane] + p1[192+lane];
    float b = p2[lane] + p2[64+lane] + p2[128+lane] + p2[192+lane];
    atomicAdd(&nstats[lane], a);
    atomicAdd(&nstats[64+lane], b);
  }
}

__global__ void k_bn_fin_node(const float* __restrict__ stats, const float* __restrict__ g,
                              const float* __restrict__ bt, float* __restrict__ ab, float invN){
  int j = threadIdx.x;
  if (j >= 64) return;
  float m = stats[j]*invN;
  float var = stats[64+j]*invN - m*m;
  float a = g[j]*rsqrtf(var + 1e-5f);
  ab[j] = a; ab[64+j] = bt[j] - m*a;
}

// ---------------- node update: h' = softplus(BN(mean) + h), + fp16 mirror ----------------
__global__ void k_node_update(const float* __restrict__ nmean, const float* __restrict__ ab,
                              const float* __restrict__ h, float* __restrict__ hout,
                              u32* __restrict__ h16out){
  int t = blockIdx.x*256 + threadIdx.x;
  if (t >= N_NODES_*32) return;
  int p = t & 31;
  int f0 = 2*p, f1 = 2*p + 1;
  float2 nm = ((const float2*)nmean)[t];
  float2 hh = ((const float2*)h)[t];
  float r0 = sp_(ab[f0]*nm.x + ab[64+f0] + hh.x);
  float r1 = sp_(ab[f1]*nm.y + ab[64+f1] + hh.y);
  float2 st; st.x = r0; st.y = r1;
  ((float2*)hout)[t] = st;
  h16out[t] = pk_(r0, r1);
}

// ---------------- graph mean + head ----------------
__global__ void k_graph_agg(const float* __restrict__ h, const int* __restrict__ batch,
                            float* __restrict__ gsum){
  int t = blockIdx.x*256 + threadIdx.x;
  int n = t >> 6; if (n >= N_NODES_) return;
  int f = t & 63;
  atomicAdd(&gsum[(size_t)batch[n]*64+f], h[t]);
}

__global__ void k_head(const float* __restrict__ gsum, const int* __restrict__ gcnt,
                       const float* __restrict__ Wl2, const float* __restrict__ bl2,
                       const float* __restrict__ Wo, const float* __restrict__ bo,
                       float* __restrict__ out){
  __shared__ float gm[64];
  __shared__ float red[128];
  int g = blockIdx.x, j = threadIdx.x;
  if (j < 64) gm[j] = gsum[(size_t)g*64+j] / fmaxf((float)gcnt[g], 1.f);
  __syncthreads();
  float u = bl2[j];
  for (int f = 0; f < 64; ++f) u += gm[f]*Wl2[f*128+j];
  red[j] = sp_(u)*Wo[j];
  __syncthreads();
  for (int s = 64; s > 0; s >>= 1){
    if (j < s) red[j] += red[j+s];
    __syncthreads();
  }
  if (j == 0) out[g] = red[0] + bo[0];
}

extern "C" void kernel_launch(void* const* d_in, const int* in_sizes, int n_in,
                              void* d_out, int out_size, void* d_ws, size_t ws_size,
                              hipStream_t stream){
  (void)in_sizes; (void)n_in; (void)out_size; (void)ws_size;
  const float* x      = (const float*)d_in[0];
  const int*   ni     = (const int*)d_in[1];
  const int*   hi     = ni + E_;
  const float* hattr  = (const float*)d_in[2];
  const int*   batch  = (const int*)d_in[3];
  const float* We     = (const float*)d_in[4];
  const float* be     = (const float*)d_in[5];
  const float* Wf1    = (const float*)d_in[6];
  const float* bf1    = (const float*)d_in[7];
  const float* Wc1    = (const float*)d_in[8];
  const float* bc1    = (const float*)d_in[9];
  const float* Wf2    = (const float*)d_in[10];
  const float* bf2    = (const float*)d_in[11];
  const float* Wc2    = (const float*)d_in[12];
  const float* bc2    = (const float*)d_in[13];
  const float* bn_f_g = (const float*)d_in[14];
  const float* bn_f_b = (const float*)d_in[15];
  const float* bn_c_g = (const float*)d_in[16];
  const float* bn_c_b = (const float*)d_in[17];
  const float* bn_o_g = (const float*)d_in[18];
  const float* bn_o_b = (const float*)d_in[19];
  const float* Wl2    = (const float*)d_in[20];
  const float* bl2    = (const float*)d_in[21];
  const float* Wo     = (const float*)d_in[22];
  const float* bo     = (const float*)d_in[23];

  float* ws = (float*)d_ws;
  size_t o = 0;
  float* h0    = ws + o; o += (size_t)N_NODES_*H_;
  float* h1    = ws + o; o += (size_t)N_NODES_*H_;
  float* tfc   = ws + o; o += (size_t)N_HEDGES_*70;    // 14.0M floats
  u32*   nFC2  = (u32*)tfc;                            // alias: layer-time
  u32*   pairN = (u32*)tfc;                            // alias: CSR-build-time only
  u32*   pairH = ((u32*)tfc) + E_;
  float* hmR   = ws + o; o += (size_t)N_HEDGES_*H_;    // 12.8M floats region
  u32*   hmean16 = (u32*)hmR;
  u32*   heFC2   = (u32*)hmR;                          // hmean16 dead before heFC2 written
  float* nmean = ws + o; o += (size_t)N_NODES_*H_;
  u32*  h16a   = (u32*)(ws + o); o += (size_t)N_NODES_*32;
  u32*  h16b   = (u32*)(ws + o); o += (size_t)N_NODES_*32;
  u32*  hattr16= (u32*)(ws + o); o += (size_t)N_HEDGES_*18;
  float* hstats = ws + o; o += 256;
  float* habs   = ws + o; o += 256;
  float* nstats = ws + o; o += 128;
  float* nabs   = ws + o; o += 128;
  float* gsum   = ws + o; o += (size_t)G_*H_;
  float* hinv   = ws + o; o += N_HEDGES_;
  float* ninv   = ws + o; o += N_NODES_;
  int* hcnt     = (int*)(ws + o); o += N_HEDGES_;
  int* ndeg     = (int*)(ws + o); o += N_NODES_;
  int* gcnt     = (int*)(ws + o); o += G_;
  int* node_off = (int*)(ws + o); o += N_NODES_;
  int* hedge_off= (int*)(ws + o); o += N_HEDGES_;
  int* gcurN    = (int*)(ws + o); o += NBN5_;
  int* gcurH    = (int*)(ws + o); o += NBH5_;
  int* bsumA    = (int*)(ws + o); o += 1024;
  int* bsumB    = (int*)(ws + o); o += 1024;
  int* edge_n   = (int*)(ws + o); o += E_;
  int* edge_h   = (int*)(ws + o); o += E_;

  hipMemsetAsync(hcnt, 0, sizeof(int)*N_HEDGES_, stream);
  hipMemsetAsync(ndeg, 0, sizeof(int)*N_NODES_, stream);
  hipMemsetAsync(gcnt, 0, sizeof(int)*G_, stream);
  hipMemsetAsync(gsum, 0, sizeof(float)*G_*H_, stream);

  k_counts<<<(E_+255)/256, 256, 0, stream>>>(ni, hi, hcnt, ndeg);
  k_gcnt<<<(N_NODES_+255)/256, 256, 0, stream>>>(batch, gcnt);
  k_inv<<<(N_HEDGES_+255)/256, 256, 0, stream>>>(hcnt, ndeg, hinv, ninv);
  k_hattr_pack<<<(N_HEDGES_*18+255)/256, 256, 0, stream>>>(hattr, hattr16);

  // CSR offsets
  k_scan1<<<(N_NODES_+255)/256, 256, 0, stream>>>(ndeg, N_NODES_, node_off, bsumA);
  k_scan2<<<1, 1024, 0, stream>>>(bsumA, (N_NODES_+255)/256);
  k_scan3<<<(N_NODES_+255)/256, 256, 0, stream>>>(node_off, bsumA, N_NODES_);
  k_scan1<<<(N_HEDGES_+255)/256, 256, 0, stream>>>(hcnt, N_HEDGES_, hedge_off, bsumB);
  k_scan2<<<1, 1024, 0, stream>>>(bsumB, (N_HEDGES_+255)/256);
  k_scan3<<<(N_HEDGES_+255)/256, 256, 0, stream>>>(hedge_off, bsumB, N_HEDGES_);

  // bucketed CSR fill: per-block reserved contiguous runs (write-coalesced)
  k_bucket_init<<<(NBH5_+255)/256, 256, 0, stream>>>(node_off, hedge_off, gcurN, gcurH);
  k_binfill<<<(E_+CHUNK_-1)/CHUNK_, 256, 0, stream>>>(ni, hi, gcurN, gcurH, pairN, pairH);
  k_csrfill<<<NBN5_, 256, 0, stream>>>(node_off, gcurN, pairN, N_NODES_, edge_n);
  k_csrfill<<<NBH5_, 256, 0, stream>>>(hedge_off, gcurH, pairH, N_HEDGES_, edge_h);

  k_embed<<<768, 256, 0, stream>>>(x, We, be, h0, h16a);

  float* hcur2 = h0;  u32* hc16 = h16a;
  float* hnxt  = h1;  u32* hn16 = h16b;
  for (int l = 0; l < L_; ++l){
    const float* Wf1l = Wf1 + (size_t)l*D_*HE_;
    const float* Wc1l = Wc1 + (size_t)l*D_*HE_;
    const float* Wf2l = Wf2 + (size_t)l*D_*H_;
    const float* Wc2l = Wc2 + (size_t)l*D_*H_;

    hipMemsetAsync(hstats, 0, sizeof(float)*160, stream);
    hipMemsetAsync(nstats, 0, sizeof(float)*128, stream);

    k_gather_hedge<<<(N_HEDGES_*16)/256, 256, 0, stream>>>(hc16, hedge_off, hcnt, edge_h,
                                                           hinv, hmean16);
    k_hedge_mlp1<<<1280, 256, 0, stream>>>(hmean16, hattr16, Wf1l, bf1 + l*HE_,
                                           Wc1l, bc1 + l*HE_, tfc, hstats);
    k_bn_fin_hedge<<<1, 128, 0, stream>>>(hstats, bn_f_g + l*HE_, bn_f_b + l*HE_,
                                          bn_c_g + l*HE_, bn_c_b + l*HE_, habs,
                                          1.f/(float)N_HEDGES_);
    k_hedge_feats<<<1536, 256, 0, stream>>>(tfc, habs, Wf2l, bf2 + l*H_,
                                            Wc2l, bc2 + l*H_, heFC2);
    k_node_lin<<<1024, 256, 0, stream>>>(hc16, Wf2l, Wc2l, nFC2);
    k_edge<<<2048, 256, 0, stream>>>(nFC2, heFC2, node_off, ndeg, edge_n, ninv, nmean, nstats);
    k_bn_fin_node<<<1, 64, 0, stream>>>(nstats, bn_o_g + l*H_, bn_o_b + l*H_, nabs,
                                        1.f/(float)N_NODES_);
    k_node_update<<<(N_NODES_*32+255)/256, 256, 0, stream>>>(nmean, nabs, hcur2, hnxt, hn16);
    float* t2 = hcur2; hcur2 = hnxt; hnxt = t2;
    u32* t3 = hc16; hc16 = hn16; hn16 = t3;
  }

  k_graph_agg<<<(N_NODES_*H_+255)/256, 256, 0, stream>>>(hcur2, batch, gsum);
  k_head<<<G_, 128, 0, stream>>>(gsum, gcnt, Wl2, bl2, Wo, bo, (float*)d_out);
}

// Round 11
// 1394.032 us; speedup vs baseline: 1.1685x; 1.0288x over previous
//
#include <hip/hip_runtime.h>
#include <cstddef>

#define N_NODES_  100000
#define N_HEDGES_ 200000
#define E_        1200000
#define G_        512
#define H_        64
#define HE_       35
#define D_        99      // H_+HE_
#define HOUT_     128
#define L_        3
#define NBN5_     196     // ceil(N_NODES/512)
#define NBH5_     391     // ceil(N_HEDGES/512)
#define CHUNK_    4096

typedef unsigned int u32;
typedef _Float16 f2_t __attribute__((ext_vector_type(2)));

__device__ __forceinline__ float sigm_(float x){
  return __builtin_amdgcn_rcpf(1.f + __expf(-x));
}
__device__ __forceinline__ float sp_(float x){
  return fmaxf(x, 0.f) + __logf(1.f + __expf(-fabsf(x)));
}
__device__ __forceinline__ float gate_(float F, float C){ return sigm_(F)*sp_(C); }

__device__ __forceinline__ u32 pk_(float a, float b){
  return __builtin_bit_cast(u32, __builtin_amdgcn_cvt_pkrtz(a, b));
}
__device__ __forceinline__ float dot2_(u32 a, u32 b, float c){
#if __has_builtin(__builtin_amdgcn_fdot2)
  return __builtin_amdgcn_fdot2(__builtin_bit_cast(f2_t, a),
                                __builtin_bit_cast(f2_t, b), c, false);
#else
  f2_t x = __builtin_bit_cast(f2_t, a), y = __builtin_bit_cast(f2_t, b);
  return c + (float)x[0]*(float)y[0] + (float)x[1]*(float)y[1];
#endif
}
__device__ __forceinline__ float lo_(u32 a){ return (float)__builtin_bit_cast(f2_t, a)[0]; }
__device__ __forceinline__ float hi_(u32 a){ return (float)__builtin_bit_cast(f2_t, a)[1]; }

// ---------------- per-call counts ----------------
__global__ void k_counts(const int* __restrict__ ni, const int* __restrict__ hi,
                         int* __restrict__ hcnt, int* __restrict__ ndeg){
  int e = blockIdx.x*256 + threadIdx.x;
  if (e >= E_) return;
  atomicAdd(&hcnt[hi[e]], 1);
  atomicAdd(&ndeg[ni[e]], 1);
}
__global__ void k_gcnt(const int* __restrict__ batch, int* __restrict__ gcnt){
  int n = blockIdx.x*256 + threadIdx.x;
  if (n < N_NODES_) atomicAdd(&gcnt[batch[n]], 1);
}
__global__ void k_inv(const int* __restrict__ hcnt, const int* __restrict__ ndeg,
                      float* __restrict__ hinv, float* __restrict__ ninv){
  int i = blockIdx.x*256 + threadIdx.x;
  if (i < N_HEDGES_) hinv[i] = 1.f/fmaxf((float)hcnt[i], 1.f);
  if (i < N_NODES_)  ninv[i] = 1.f/fmaxf((float)ndeg[i], 1.f);
}

// ---------------- CSR build: scan ----------------
__global__ void k_scan1(const int* __restrict__ cnt, int n, int* __restrict__ off,
                        int* __restrict__ bsum){
  __shared__ int tmp[256];
  int i = blockIdx.x*256 + threadIdx.x;
  int v = (i < n) ? cnt[i] : 0;
  tmp[threadIdx.x] = v;
  __syncthreads();
  for (int d = 1; d < 256; d <<= 1){
    int t = (threadIdx.x >= d) ? tmp[threadIdx.x - d] : 0;
    __syncthreads();
    tmp[threadIdx.x] += t;
    __syncthreads();
  }
  if (i < n) off[i] = tmp[threadIdx.x] - v;
  if (threadIdx.x == 255) bsum[blockIdx.x] = tmp[255];
}
__global__ void k_scan2(int* __restrict__ bsum, int nb){
  __shared__ int tmp[1024];
  int t = threadIdx.x;
  int v = (t < nb) ? bsum[t] : 0;
  tmp[t] = v;
  __syncthreads();
  for (int d = 1; d < 1024; d <<= 1){
    int x = (t >= d) ? tmp[t - d] : 0;
    __syncthreads();
    tmp[t] += x;
    __syncthreads();
  }
  if (t < nb) bsum[t] = tmp[t] - v;
}
__global__ void k_scan3(int* __restrict__ off, const int* __restrict__ bsum, int n){
  int i = blockIdx.x*256 + threadIdx.x;
  if (i < n) off[i] += bsum[blockIdx.x];
}

// ---------------- bucketed CSR fill: per-block reserved contiguous runs ----------------
__global__ void k_bucket_init(const int* __restrict__ node_off, const int* __restrict__ hedge_off,
                              int* __restrict__ gcurN, int* __restrict__ gcurH){
  int b = blockIdx.x*256 + threadIdx.x;
  if (b < NBN5_) gcurN[b] = node_off[b*512];
  if (b < NBH5_) gcurH[b] = hedge_off[b*512];
}
// pair encoding: (local_row_9b << 18) | id (< 2^18)
__global__ void k_binfill(const int* __restrict__ ni, const int* __restrict__ hi,
                          int* __restrict__ gcurN, int* __restrict__ gcurH,
                          u32* __restrict__ pairN, u32* __restrict__ pairH){
  __shared__ int histN[NBN5_], histH[NBH5_];
  __shared__ int baseN[NBN5_], baseH[NBH5_];
  const int nchunks = (E_ + CHUNK_ - 1)/CHUNK_;
  for (int c = blockIdx.x; c < nchunks; c += gridDim.x){
    int e0 = c*CHUNK_;
    int e1 = e0 + CHUNK_; if (e1 > E_) e1 = E_;
    for (int i = threadIdx.x; i < NBN5_; i += 256) histN[i] = 0;
    for (int i = threadIdx.x; i < NBH5_; i += 256) histH[i] = 0;
    __syncthreads();
    for (int e = e0 + threadIdx.x; e < e1; e += 256){
      atomicAdd(&histN[ni[e] >> 9], 1);
      atomicAdd(&histH[hi[e] >> 9], 1);
    }
    __syncthreads();
    for (int i = threadIdx.x; i < NBN5_; i += 256){
      int hv = histN[i];
      baseN[i] = hv ? atomicAdd(&gcurN[i], hv) : 0;
      histN[i] = 0;
    }
    for (int i = threadIdx.x; i < NBH5_; i += 256){
      int hv = histH[i];
      baseH[i] = hv ? atomicAdd(&gcurH[i], hv) : 0;
      histH[i] = 0;
    }
    __syncthreads();
    for (int e = e0 + threadIdx.x; e < e1; e += 256){
      int n = ni[e], he = hi[e];
      int bn = n >> 9, bh = he >> 9;
      int pn = baseN[bn] + atomicAdd(&histN[bn], 1);
      pairN[pn] = ((u32)(n & 511) << 18) | (u32)he;
      int ph = baseH[bh] + atomicAdd(&histH[bh], 1);
      pairH[ph] = ((u32)(he & 511) << 18) | (u32)n;
    }
    __syncthreads();
  }
}
// one block per 512-row bucket; LDS cursors; 24KB hot dest window
__global__ void k_csrfill(const int* __restrict__ off_arr, const int* __restrict__ gcur,
                          const u32* __restrict__ pair, int nrows, int* __restrict__ out){
  __shared__ int cur[512];
  int b = blockIdx.x, t = threadIdx.x;
  int nb = b*512;
  for (int i = t; i < 512; i += 256){
    int idx = nb + i;
    cur[i] = (idx < nrows) ? off_arr[idx] : 0;
  }
  __syncthreads();
  int base = off_arr[nb];
  int end  = gcur[b];
  for (int pos = base + t; pos < end; pos += 256){
    u32 p = pair[pos];
    int idx = atomicAdd(&cur[p >> 18], 1);
    out[idx] = (int)(p & 0x3FFFFu);
  }
}

// ---------------- pack hattr to fp16 pairs [NH][18] ----------------
__global__ void k_hattr_pack(const float* __restrict__ hattr, u32* __restrict__ hattr16){
  int i = blockIdx.x*256 + threadIdx.x;
  if (i >= N_HEDGES_*18) return;
  int he = i/18, p = i - he*18;
  int k0 = 2*p, k1 = 2*p + 1;
  float w0 = (k0 < 35) ? hattr[(size_t)he*35 + k0] : 0.f;
  float w1 = (k1 < 35) ? hattr[(size_t)he*35 + k1] : 0.f;
  hattr16[i] = pk_(w0, w1);
}

// ---------------- embed: h = x @ We + be ; also packed fp16 mirror ----------------
__global__ void k_embed(const float* __restrict__ x, const float* __restrict__ We,
                        const float* __restrict__ be, float* __restrict__ h,
                        u32* __restrict__ h16){
  __shared__ __align__(16) float As[64*100];
  __shared__ __align__(16) float Ws[64*100];
  int tid = threadIdx.x;
  for (int idx = tid; idx < 64*100; idx += 256){
    int c = idx/100, k = idx - c*100;
    Ws[idx] = (k < 92) ? We[k*64 + c] : 0.f;
  }
  int rt = tid & 15, ct = tid >> 4;
  float bias[4];
  #pragma unroll
  for (int j = 0; j < 4; ++j) bias[j] = be[ct*4 + j];
  const int ntiles = (N_NODES_ + 63)/64;
  for (int tile = blockIdx.x; tile < ntiles; tile += gridDim.x){
    int rbase = tile*64;
    __syncthreads();
    for (int idx = tid; idx < 64*100; idx += 256){
      int r = idx/100, k = idx - r*100;
      int rg = rbase + r;
      As[idx] = (rg < N_NODES_ && k < 92) ? x[(size_t)rg*92 + k] : 0.f;
    }
    __syncthreads();
    float acc[4][4] = {};
    for (int kc = 0; kc < 25; ++kc){
      float4 av[4], wv[4];
      #pragma unroll
      for (int i = 0; i < 4; ++i) av[i] = *(const float4*)&As[(rt + 16*i)*100 + kc*4];
      #pragma unroll
      for (int j = 0; j < 4; ++j) wv[j] = *(const float4*)&Ws[(ct*4 + j)*100 + kc*4];
      #pragma unroll
      for (int i = 0; i < 4; ++i)
        #pragma unroll
        for (int j = 0; j < 4; ++j)
          acc[i][j] += av[i].x*wv[j].x + av[i].y*wv[j].y + av[i].z*wv[j].z + av[i].w*wv[j].w;
    }
    #pragma unroll
    for (int i = 0; i < 4; ++i){
      int r = rbase + rt + 16*i;
      if (r < N_NODES_){
        float4 st;
        st.x = acc[i][0] + bias[0]; st.y = acc[i][1] + bias[1];
        st.z = acc[i][2] + bias[2]; st.w = acc[i][3] + bias[3];
        *(float4*)&h[(size_t)r*64 + ct*4] = st;
        h16[(size_t)r*32 + ct*2]     = pk_(st.x, st.y);
        h16[(size_t)r*32 + ct*2 + 1] = pk_(st.z, st.w);
      }
    }
  }
}

// ---------------- hedge gather (fp16, uint2): hmean16[he] = mean of h16 rows ----------------
__global__ void __launch_bounds__(256) k_gather_hedge(
    const u32* __restrict__ h16, const int* __restrict__ hedge_off,
    const int* __restrict__ hcnt, const int* __restrict__ edge_h,
    const float* __restrict__ hinv, u32* __restrict__ hmean16){
  int w = (blockIdx.x*256 + threadIdx.x) >> 4;
  int p = threadIdx.x & 15;
  if (w >= N_HEDGES_) return;
  int off = hedge_off[w], deg = hcnt[w];
  float a0 = 0.f, a1 = 0.f, a2 = 0.f, a3 = 0.f;
  int i = 0;
  for (; i + 1 < deg; i += 2){
    int n0 = edge_h[off+i], n1 = edge_h[off+i+1];
    uint2 u0 = *(const uint2*)&h16[(size_t)n0*32 + 2*p];
    uint2 u1 = *(const uint2*)&h16[(size_t)n1*32 + 2*p];
    a0 += lo_(u0.x) + lo_(u1.x); a1 += hi_(u0.x) + hi_(u1.x);
    a2 += lo_(u0.y) + lo_(u1.y); a3 += hi_(u0.y) + hi_(u1.y);
  }
  if (i < deg){
    uint2 u = *(const uint2*)&h16[(size_t)edge_h[off+i]*32 + 2*p];
    a0 += lo_(u.x); a1 += hi_(u.x); a2 += lo_(u.y); a3 += hi_(u.y);
  }
  float inv = hinv[w];
  uint2 st; st.x = pk_(a0*inv, a1*inv); st.y = pk_(a2*inv, a3*inv);
  *(uint2*)&hmean16[(size_t)w*32 + 2*p] = st;
}

// ---------------- hedge MLP pre-BN (dot2): tfcT[c][r] (transposed), reg-accum stats ------
__global__ void k_hedge_mlp1(const u32* __restrict__ hmean16, const u32* __restrict__ hattr16,
                             const float* __restrict__ Wf1, const float* __restrict__ bf1,
                             const float* __restrict__ Wc1, const float* __restrict__ bc1,
                             float* __restrict__ tfcT, float* __restrict__ hstats){
  __shared__ __align__(16) u32 As16[64*52];
  __shared__ __align__(16) u32 Ws16[80*52];
  __shared__ float sstat[160];
  int tid = threadIdx.x;
  for (int idx = tid; idx < 80*52; idx += 256){
    int c = idx/52, kk = idx - c*52;
    int k0 = 2*kk, k1 = 2*kk + 1;
    float w0 = 0.f, w1 = 0.f;
    if (c < 70){
      if (k0 < 99) w0 = (c < 35) ? Wf1[k0*35 + c] : Wc1[k0*35 + (c-35)];
      if (k1 < 99) w1 = (c < 35) ? Wf1[k1*35 + c] : Wc1[k1*35 + (c-35)];
    }
    Ws16[idx] = pk_(w0, w1);
  }
  for (int idx = tid; idx < 160; idx += 256) sstat[idx] = 0.f;
  int rt = tid & 15, ct = tid >> 4;
  float bias[5];
  #pragma unroll
  for (int j = 0; j < 5; ++j){
    int c = ct*5 + j;
    bias[j] = (c < 35) ? bf1[c] : (c < 70 ? bc1[c - 35] : 0.f);
  }
  float sreg[5] = {}, qreg[5] = {};
  for (int tile = blockIdx.x; tile < N_HEDGES_/64; tile += gridDim.x){
    int rbase = tile*64;
    __syncthreads();
    for (int idx = tid; idx < 64*52; idx += 256){
      int r = idx/52, kk = idx - r*52;
      int rg = rbase + r;
      u32 v = 0;
      if (kk < 32)      v = hmean16[(size_t)rg*32 + kk];
      else if (kk < 50) v = hattr16[(size_t)rg*18 + (kk - 32)];
      As16[idx] = v;
    }
    __syncthreads();
    float acc[4][5] = {};
    for (int kc = 0; kc < 13; ++kc){
      uint4 av[4], wv[5];
      #pragma unroll
      for (int i = 0; i < 4; ++i) av[i] = *(const uint4*)&As16[(rt + 16*i)*52 + kc*4];
      #pragma unroll
      for (int j = 0; j < 5; ++j) wv[j] = *(const uint4*)&Ws16[(ct*5 + j)*52 + kc*4];
      #pragma unroll
      for (int i = 0; i < 4; ++i)
        #pragma unroll
        for (int j = 0; j < 5; ++j){
          float a = acc[i][j];
          a = dot2_(av[i].x, wv[j].x, a);
          a = dot2_(av[i].y, wv[j].y, a);
          a = dot2_(av[i].z, wv[j].z, a);
          a = dot2_(av[i].w, wv[j].w, a);
          acc[i][j] = a;
        }
    }
    #pragma unroll
    for (int j = 0; j < 5; ++j){
      int c = ct*5 + j;
      if (c < 70){
        #pragma unroll
        for (int i = 0; i < 4; ++i){
          float v = acc[i][j] + bias[j];
          tfcT[(size_t)c*N_HEDGES_ + rbase + rt + 16*i] = v;   // coalesced: rt consecutive
          sreg[j] += v; qreg[j] += v*v;
        }
      }
    }
  }
  // wave-level reduce over rt (lane bits 0-3), then one LDS atomic per wave per column
  int lane = tid & 63;
  #pragma unroll
  for (int j = 0; j < 5; ++j){
    float s = sreg[j], q = qreg[j];
    #pragma unroll
    for (int m = 1; m < 16; m <<= 1){
      s += __shfl_xor(s, m);
      q += __shfl_xor(q, m);
    }
    if ((lane & 15) == 0){
      int c = ct*5 + j;
      if (c < 70){
        atomicAdd(&sstat[c], s);
        atomicAdd(&sstat[80 + c], q);
      }
    }
  }
  __syncthreads();
  for (int idx = tid; idx < 160; idx += 256) atomicAdd(&hstats[idx], sstat[idx]);
}

// ---------------- BN finalize (hedge) ----------------
__global__ void k_bn_fin_hedge(const float* __restrict__ stats,
                               const float* __restrict__ gf, const float* __restrict__ btf,
                               const float* __restrict__ gc, const float* __restrict__ btc,
                               float* __restrict__ ab, float invN){
  int j = threadIdx.x;
  if (j >= 70) return;
  float m = stats[j]*invN;
  float var = stats[80+j]*invN - m*m;
  float gg = (j < 35) ? gf[j] : gc[j-35];
  float bb = (j < 35) ? btf[j] : btc[j-35];
  float a = gg*rsqrtf(var + 1e-5f);
  ab[j] = a; ab[70+j] = bb - m*a;
}

// ---------------- hedge feats + project (dot2, transposed tfcT reads): heFC2 fp16 ---------
__global__ void k_hedge_feats(const float* __restrict__ tfcT, const float* __restrict__ ab,
                              const float* __restrict__ Wf2, const float* __restrict__ bf2,
                              const float* __restrict__ Wc2, const float* __restrict__ bc2,
                              u32* __restrict__ heFC2){
  __shared__ __align__(16) u32 As16[64*20];
  __shared__ __align__(16) u32 Ws16[128*20];
  int tid = threadIdx.x;
  for (int idx = tid; idx < 128*20; idx += 256){
    int c = idx/20, kk = idx - c*20;
    int k0 = 2*kk, k1 = 2*kk + 1;
    float w0 = 0.f, w1 = 0.f;
    if (k0 < 35) w0 = (c < 64) ? Wf2[(64+k0)*64 + c] : Wc2[(64+k0)*64 + (c-64)];
    if (k1 < 35) w1 = (c < 64) ? Wf2[(64+k1)*64 + c] : Wc2[(64+k1)*64 + (c-64)];
    Ws16[idx] = pk_(w0, w1);
  }
  int rt = tid & 15, ct = tid >> 4;
  float biasF[4], biasC[4];
  #pragma unroll
  for (int j = 0; j < 4; ++j){ biasF[j] = bf2[ct*4 + j]; biasC[j] = bc2[ct*4 + j]; }
  for (int tile = blockIdx.x; tile < N_HEDGES_/64; tile += gridDim.x){
    int rbase = tile*64;
    __syncthreads();
    // staging: per (kk, r); column-stream reads from transposed tfcT (coalesced over r)
    for (int idx = tid; idx < 64*20; idx += 256){
      int kk = idx >> 6;        // 0..19
      int r  = idx & 63;
      float a0 = 0.f, a1 = 0.f;
      if (kk < 18){
        int rg = rbase + r;
        int k0 = 2*kk, k1 = 2*kk + 1;
        {
          float tf = tfcT[(size_t)k0*N_HEDGES_ + rg];
          float tc = tfcT[(size_t)(35+k0)*N_HEDGES_ + rg];
          float zf = ab[k0]*tf + ab[70 + k0];
          float zc = ab[35+k0]*tc + ab[105 + k0];
          a0 = gate_(zf, zc);
        }
        if (k1 < 35){
          float tf = tfcT[(size_t)k1*N_HEDGES_ + rg];
          float tc = tfcT[(size_t)(35+k1)*N_HEDGES_ + rg];
          float zf = ab[k1]*tf + ab[70 + k1];
          float zc = ab[35+k1]*tc + ab[105 + k1];
          a1 = gate_(zf, zc);
        }
      }
      As16[r*20 + kk] = pk_(a0, a1);
    }
    __syncthreads();
    float accF[4][4] = {}, accC[4][4] = {};
    for (int kc = 0; kc < 5; ++kc){
      uint4 av[4], wF[4], wC[4];
      #pragma unroll
      for (int i = 0; i < 4; ++i) av[i] = *(const uint4*)&As16[(rt + 16*i)*20 + kc*4];
      #pragma unroll
      for (int j = 0; j < 4; ++j){
        wF[j] = *(const uint4*)&Ws16[(ct*4 + j)*20 + kc*4];
        wC[j] = *(const uint4*)&Ws16[(64 + ct*4 + j)*20 + kc*4];
      }
      #pragma unroll
      for (int i = 0; i < 4; ++i)
        #pragma unroll
        for (int j = 0; j < 4; ++j){
          float f = accF[i][j], c = accC[i][j];
          f = dot2_(av[i].x, wF[j].x, f); c = dot2_(av[i].x, wC[j].x, c);
          f = dot2_(av[i].y, wF[j].y, f); c = dot2_(av[i].y, wC[j].y, c);
          f = dot2_(av[i].z, wF[j].z, f); c = dot2_(av[i].z, wC[j].z, c);
          f = dot2_(av[i].w, wF[j].w, f); c = dot2_(av[i].w, wC[j].w, c);
          accF[i][j] = f; accC[i][j] = c;
        }
    }
    #pragma unroll
    for (int i = 0; i < 4; ++i){
      int r = rbase + rt + 16*i;
      #pragma unroll
      for (int j = 0; j < 4; ++j){
        heFC2[(size_t)r*64 + ct*4 + j] = pk_(accF[i][j] + biasF[j], accC[i][j] + biasC[j]);
      }
    }
  }
}

// ---------------- node projections (dot2): nFC2 packed fp16 ----------------
__global__ void k_node_lin(const u32* __restrict__ h16,
                           const float* __restrict__ Wf2, const float* __restrict__ Wc2,
                           u32* __restrict__ nFC2){
  __shared__ __align__(16) u32 As16[64*36];
  __shared__ __align__(16) u32 Ws16[128*36];
  int tid = threadIdx.x;
  for (int idx = tid; idx < 128*36; idx += 256){
    int c = idx/36, kk = idx - c*36;
    int k0 = 2*kk, k1 = 2*kk + 1;
    float w0 = 0.f, w1 = 0.f;
    if (k0 < 64) w0 = (c < 64) ? Wf2[k0*64 + c] : Wc2[k0*64 + (c-64)];
    if (k1 < 64) w1 = (c < 64) ? Wf2[k1*64 + c] : Wc2[k1*64 + (c-64)];
    Ws16[idx] = pk_(w0, w1);
  }
  int rt = tid & 15, ct = tid >> 4;
  const int ntiles = (N_NODES_ + 63)/64;
  for (int tile = blockIdx.x; tile < ntiles; tile += gridDim.x){
    int rbase = tile*64;
    __syncthreads();
    for (int idx = tid; idx < 64*36; idx += 256){
      int r = idx/36, kk = idx - r*36;
      int rg = rbase + r;
      As16[idx] = (rg < N_NODES_ && kk < 32) ? h16[(size_t)rg*32 + kk] : 0u;
    }
    __syncthreads();
    float accF[4][4] = {}, accC[4][4] = {};
    for (int kc = 0; kc < 8; ++kc){
      uint4 av[4], wF[4], wC[4];
      #pragma unroll
      for (int i = 0; i < 4; ++i) av[i] = *(const uint4*)&As16[(rt + 16*i)*36 + kc*4];
      #pragma unroll
      for (int j = 0; j < 4; ++j){
        wF[j] = *(const uint4*)&Ws16[(ct*4 + j)*36 + kc*4];
        wC[j] = *(const uint4*)&Ws16[(64 + ct*4 + j)*36 + kc*4];
      }
      #pragma unroll
      for (int i = 0; i < 4; ++i)
        #pragma unroll
        for (int j = 0; j < 4; ++j){
          float f = accF[i][j], c = accC[i][j];
          f = dot2_(av[i].x, wF[j].x, f); c = dot2_(av[i].x, wC[j].x, c);
          f = dot2_(av[i].y, wF[j].y, f); c = dot2_(av[i].y, wC[j].y, c);
          f = dot2_(av[i].z, wF[j].z, f); c = dot2_(av[i].z, wC[j].z, c);
          f = dot2_(av[i].w, wF[j].w, f); c = dot2_(av[i].w, wC[j].w, c);
          accF[i][j] = f; accC[i][j] = c;
        }
    }
    #pragma unroll
    for (int i = 0; i < 4; ++i){
      int r = rbase + rt + 16*i;
      if (r < N_NODES_){
        #pragma unroll
        for (int j = 0; j < 4; ++j){
          nFC2[(size_t)r*64 + ct*4 + j] = pk_(accF[i][j], accC[i][j]);
        }
      }
    }
  }
}

// ---------------- fused edge: node-CSR gather + gated act + mean + stats ------
__global__ void k_edge(const u32* __restrict__ nFC2, const u32* __restrict__ heFC2,
                       const int* __restrict__ node_off, const int* __restrict__ ndeg,
                       const int* __restrict__ edge_n, const float* __restrict__ ninv,
                       float* __restrict__ nmean, float* __restrict__ nstats){
  int lane = threadIdx.x & 63, wave = threadIdx.x >> 6;
  float s = 0.f, q = 0.f;
  for (int base = blockIdx.x*4; base < N_NODES_; base += gridDim.x*4){
    int n = base + wave;
    if (n < N_NODES_){
      int off = __builtin_amdgcn_readfirstlane(node_off[n]);
      int deg = __builtin_amdgcn_readfirstlane(ndeg[n]);
      u32 p0 = nFC2[(size_t)n*64 + lane];
      float f0 = lo_(p0), c0 = hi_(p0);
      float acc = 0.f;
      int i = 0;
      for (; i + 3 < deg; i += 4){
        int e0 = edge_n[off+i], e1 = edge_n[off+i+1], e2 = edge_n[off+i+2], e3 = edge_n[off+i+3];
        u32 a0 = heFC2[(size_t)e0*64 + lane];
        u32 a1 = heFC2[(size_t)e1*64 + lane];
        u32 a2 = heFC2[(size_t)e2*64 + lane];
        u32 a3 = heFC2[(size_t)e3*64 + lane];
        acc += gate_(f0 + lo_(a0), c0 + hi_(a0))
             + gate_(f0 + lo_(a1), c0 + hi_(a1))
             + gate_(f0 + lo_(a2), c0 + hi_(a2))
             + gate_(f0 + lo_(a3), c0 + hi_(a3));
      }
      for (; i < deg; ++i){
        u32 a = heFC2[(size_t)edge_n[off+i]*64 + lane];
        acc += gate_(f0 + lo_(a), c0 + hi_(a));
      }
      float m = acc * ninv[n];
      nmean[(size_t)n*64 + lane] = m;
      s += m; q += m*m;
    }
  }
  __shared__ float p1[256], p2[256];
  p1[threadIdx.x] = s; p2[threadIdx.x] = q;
  __syncthreads();
  if (wave == 0){
    float a = p1[lane] + p1[64+lane] + p1[128+lane] + p1[192+lane];
    float b = p2[lane] + p2[64+lane] + p2[128+lane] + p2[192+lane];
    atomicAdd(&nstats[lane], a);
    atomicAdd(&nstats[64+lane], b);
  }
}

__global__ void k_bn_fin_node(const float* __restrict__ stats, const float* __restrict__ g,
                              const float* __restrict__ bt, float* __restrict__ ab, float invN){
  int j = threadIdx.x;
  if (j >= 64) return;
  float m = stats[j]*invN;
  float var = stats[64+j]*invN - m*m;
  float a = g[j]*rsqrtf(var + 1e-5f);
  ab[j] = a; ab[64+j] = bt[j] - m*a;
}

// ---------------- node update: h' = softplus(BN(mean) + h), + fp16 mirror ----------------
__global__ void k_node_update(const float* __restrict__ nmean, const float* __restrict__ ab,
                              const float* __restrict__ h, float* __restrict__ hout,
                              u32* __restrict__ h16out){
  int t = blockIdx.x*256 + threadIdx.x;
  if (t >= N_NODES_*32) return;
  int p = t & 31;
  int f0 = 2*p, f1 = 2*p + 1;
  float2 nm = ((const float2*)nmean)[t];
  float2 hh = ((const float2*)h)[t];
  float r0 = sp_(ab[f0]*nm.x + ab[64+f0] + hh.x);
  float r1 = sp_(ab[f1]*nm.y + ab[64+f1] + hh.y);
  float2 st; st.x = r0; st.y = r1;
  ((float2*)hout)[t] = st;
  h16out[t] = pk_(r0, r1);
}

// ---------------- graph mean + head ----------------
__global__ void k_graph_agg(const float* __restrict__ h, const int* __restrict__ batch,
                            float* __restrict__ gsum){
  int t = blockIdx.x*256 + threadIdx.x;
  int n = t >> 6; if (n >= N_NODES_) return;
  int f = t & 63;
  atomicAdd(&gsum[(size_t)batch[n]*64+f], h[t]);
}

__global__ void k_head(const float* __restrict__ gsum, const int* __restrict__ gcnt,
                       const float* __restrict__ Wl2, const float* __restrict__ bl2,
                       const float* __restrict__ Wo, const float* __restrict__ bo,
                       float* __restrict__ out){
  __shared__ float gm[64];
  __shared__ float red[128];
  int g = blockIdx.x, j = threadIdx.x;
  if (j < 64) gm[j] = gsum[(size_t)g*64+j] / fmaxf((float)gcnt[g], 1.f);
  __syncthreads();
  float u = bl2[j];
  for (int f = 0; f < 64; ++f) u += gm[f]*Wl2[f*128+j];
  red[j] = sp_(u)*Wo[j];
  __syncthreads();
  for (int s = 64; s > 0; s >>= 1){
    if (j < s) red[j] += red[j+s];
    __syncthreads();
  }
  if (j == 0) out[g] = red[0] + bo[0];
}

extern "C" void kernel_launch(void* const* d_in, const int* in_sizes, int n_in,
                              void* d_out, int out_size, void* d_ws, size_t ws_size,
                              hipStream_t stream){
  (void)in_sizes; (void)n_in; (void)out_size; (void)ws_size;
  const float* x      = (const float*)d_in[0];
  const int*   ni     = (const int*)d_in[1];
  const int*   hi     = ni + E_;
  const float* hattr  = (const float*)d_in[2];
  const int*   batch  = (const int*)d_in[3];
  const float* We     = (const float*)d_in[4];
  const float* be     = (const float*)d_in[5];
  const float* Wf1    = (const float*)d_in[6];
  const float* bf1    = (const float*)d_in[7];
  const float* Wc1    = (const float*)d_in[8];
  const float* bc1    = (const float*)d_in[9];
  const float* Wf2    = (const float*)d_in[10];
  const float* bf2    = (const float*)d_in[11];
  const float* Wc2    = (const float*)d_in[12];
  const float* bc2    = (const float*)d_in[13];
  const float* bn_f_g = (const float*)d_in[14];
  const float* bn_f_b = (const float*)d_in[15];
  const float* bn_c_g = (const float*)d_in[16];
  const float* bn_c_b = (const float*)d_in[17];
  const float* bn_o_g = (const float*)d_in[18];
  const float* bn_o_b = (const float*)d_in[19];
  const float* Wl2    = (const float*)d_in[20];
  const float* bl2    = (const float*)d_in[21];
  const float* Wo     = (const float*)d_in[22];
  const float* bo     = (const float*)d_in[23];

  float* ws = (float*)d_ws;
  size_t o = 0;
  float* h0    = ws + o; o += (size_t)N_NODES_*H_;
  float* h1    = ws + o; o += (size_t)N_NODES_*H_;
  float* tfcT  = ws + o; o += (size_t)N_HEDGES_*70;    // 14.0M floats, [70][NH] transposed
  u32*   nFC2  = (u32*)tfcT;                           // alias: layer-time
  u32*   pairN = (u32*)tfcT;                           // alias: CSR-build-time only
  u32*   pairH = ((u32*)tfcT) + E_;
  float* hmR   = ws + o; o += (size_t)N_HEDGES_*H_;    // 12.8M floats region
  u32*   hmean16 = (u32*)hmR;
  u32*   heFC2   = (u32*)hmR;                          // hmean16 dead before heFC2 written
  float* nmean = ws + o; o += (size_t)N_NODES_*H_;
  u32*  h16a   = (u32*)(ws + o); o += (size_t)N_NODES_*32;
  u32*  h16b   = (u32*)(ws + o); o += (size_t)N_NODES_*32;
  u32*  hattr16= (u32*)(ws + o); o += (size_t)N_HEDGES_*18;
  float* hstats = ws + o; o += 256;
  float* habs   = ws + o; o += 256;
  float* nstats = ws + o; o += 128;
  float* nabs   = ws + o; o += 128;
  float* gsum   = ws + o; o += (size_t)G_*H_;
  float* hinv   = ws + o; o += N_HEDGES_;
  float* ninv   = ws + o; o += N_NODES_;
  int* hcnt     = (int*)(ws + o); o += N_HEDGES_;
  int* ndeg     = (int*)(ws + o); o += N_NODES_;
  int* gcnt     = (int*)(ws + o); o += G_;
  int* node_off = (int*)(ws + o); o += N_NODES_;
  int* hedge_off= (int*)(ws + o); o += N_HEDGES_;
  int* gcurN    = (int*)(ws + o); o += NBN5_;
  int* gcurH    = (int*)(ws + o); o += NBH5_;
  int* bsumA    = (int*)(ws + o); o += 1024;
  int* bsumB    = (int*)(ws + o); o += 1024;
  int* edge_n   = (int*)(ws + o); o += E_;
  int* edge_h   = (int*)(ws + o); o += E_;

  hipMemsetAsync(hcnt, 0, sizeof(int)*N_HEDGES_, stream);
  hipMemsetAsync(ndeg, 0, sizeof(int)*N_NODES_, stream);
  hipMemsetAsync(gcnt, 0, sizeof(int)*G_, stream);
  hipMemsetAsync(gsum, 0, sizeof(float)*G_*H_, stream);

  k_counts<<<(E_+255)/256, 256, 0, stream>>>(ni, hi, hcnt, ndeg);
  k_gcnt<<<(N_NODES_+255)/256, 256, 0, stream>>>(batch, gcnt);
  k_inv<<<(N_HEDGES_+255)/256, 256, 0, stream>>>(hcnt, ndeg, hinv, ninv);
  k_hattr_pack<<<(N_HEDGES_*18+255)/256, 256, 0, stream>>>(hattr, hattr16);

  // CSR offsets
  k_scan1<<<(N_NODES_+255)/256, 256, 0, stream>>>(ndeg, N_NODES_, node_off, bsumA);
  k_scan2<<<1, 1024, 0, stream>>>(bsumA, (N_NODES_+255)/256);
  k_scan3<<<(N_NODES_+255)/256, 256, 0, stream>>>(node_off, bsumA, N_NODES_);
  k_scan1<<<(N_HEDGES_+255)/256, 256, 0, stream>>>(hcnt, N_HEDGES_, hedge_off, bsumB);
  k_scan2<<<1, 1024, 0, stream>>>(bsumB, (N_HEDGES_+255)/256);
  k_scan3<<<(N_HEDGES_+255)/256, 256, 0, stream>>>(hedge_off, bsumB, N_HEDGES_);

  // bucketed CSR fill: per-block reserved contiguous runs (write-coalesced)
  k_bucket_init<<<(NBH5_+255)/256, 256, 0, stream>>>(node_off, hedge_off, gcurN, gcurH);
  k_binfill<<<(E_+CHUNK_-1)/CHUNK_, 256, 0, stream>>>(ni, hi, gcurN, gcurH, pairN, pairH);
  k_csrfill<<<NBN5_, 256, 0, stream>>>(node_off, gcurN, pairN, N_NODES_, edge_n);
  k_csrfill<<<NBH5_, 256, 0, stream>>>(hedge_off, gcurH, pairH, N_HEDGES_, edge_h);

  k_embed<<<768, 256, 0, stream>>>(x, We, be, h0, h16a);

  float* hcur2 = h0;  u32* hc16 = h16a;
  float* hnxt  = h1;  u32* hn16 = h16b;
  for (int l = 0; l < L_; ++l){
    const float* Wf1l = Wf1 + (size_t)l*D_*HE_;
    const float* Wc1l = Wc1 + (size_t)l*D_*HE_;
    const float* Wf2l = Wf2 + (size_t)l*D_*H_;
    const float* Wc2l = Wc2 + (size_t)l*D_*H_;

    hipMemsetAsync(hstats, 0, sizeof(float)*160, stream);
    hipMemsetAsync(nstats, 0, sizeof(float)*128, stream);

    k_gather_hedge<<<(N_HEDGES_*16)/256, 256, 0, stream>>>(hc16, hedge_off, hcnt, edge_h,
                                                           hinv, hmean16);
    k_hedge_mlp1<<<1280, 256, 0, stream>>>(hmean16, hattr16, Wf1l, bf1 + l*HE_,
                                           Wc1l, bc1 + l*HE_, tfcT, hstats);
    k_bn_fin_hedge<<<1, 128, 0, stream>>>(hstats, bn_f_g + l*HE_, bn_f_b + l*HE_,
                                          bn_c_g + l*HE_, bn_c_b + l*HE_, habs,
                                          1.f/(float)N_HEDGES_);
    k_hedge_feats<<<1536, 256, 0, stream>>>(tfcT, habs, Wf2l, bf2 + l*H_,
                                            Wc2l, bc2 + l*H_, heFC2);
    k_node_lin<<<1024, 256, 0, stream>>>(hc16, Wf2l, Wc2l, nFC2);
    k_edge<<<2048, 256, 0, stream>>>(nFC2, heFC2, node_off, ndeg, edge_n, ninv, nmean, nstats);
    k_bn_fin_node<<<1, 64, 0, stream>>>(nstats, bn_o_g + l*H_, bn_o_b + l*H_, nabs,
                                        1.f/(float)N_NODES_);
    k_node_update<<<(N_NODES_*32+255)/256, 256, 0, stream>>>(nmean, nabs, hcur2, hnxt, hn16);
    float* t2 = hcur2; hcur2 = hnxt; hnxt = t2;
    u32* t3 = hc16; hc16 = hn16; hn16 = t3;
  }

  k_graph_agg<<<(N_NODES_*H_+255)/256, 256, 0, stream>>>(hcur2, batch, gsum);
  k_head<<<G_, 128, 0, stream>>>(gsum, gcnt, Wl2, bl2, Wo, bo, (float*)d_out);
}

// Round 12
// 1312.004 us; speedup vs baseline: 1.2416x; 1.0625x over previous
//
#include <hip/hip_runtime.h>
#include <cstddef>

#define N_NODES_  100000
#define N_HEDGES_ 200000
#define E_        1200000
#define G_        512
#define H_        64
#define HE_       35
#define D_        99      // H_+HE_
#define HOUT_     128
#define L_        3
#define NBN5_     196     // ceil(N_NODES/512)
#define NBH5_     391     // ceil(N_HEDGES/512)
#define CHUNK_    4096

typedef unsigned int u32;
typedef _Float16 f2_t __attribute__((ext_vector_type(2)));

__device__ __forceinline__ float sigm_(float x){
  return __builtin_amdgcn_rcpf(1.f + __expf(-x));
}
__device__ __forceinline__ float sp_(float x){
  return fmaxf(x, 0.f) + __logf(1.f + __expf(-fabsf(x)));
}
__device__ __forceinline__ float gate_(float F, float C){ return sigm_(F)*sp_(C); }

__device__ __forceinline__ u32 pk_(float a, float b){
  return __builtin_bit_cast(u32, __builtin_amdgcn_cvt_pkrtz(a, b));
}
__device__ __forceinline__ u32 pkadd_(u32 a, u32 b){
  f2_t s = __builtin_bit_cast(f2_t, a) + __builtin_bit_cast(f2_t, b);
  return __builtin_bit_cast(u32, s);
}
__device__ __forceinline__ float dot2_(u32 a, u32 b, float c){
#if __has_builtin(__builtin_amdgcn_fdot2)
  return __builtin_amdgcn_fdot2(__builtin_bit_cast(f2_t, a),
                                __builtin_bit_cast(f2_t, b), c, false);
#else
  f2_t x = __builtin_bit_cast(f2_t, a), y = __builtin_bit_cast(f2_t, b);
  return c + (float)x[0]*(float)y[0] + (float)x[1]*(float)y[1];
#endif
}
__device__ __forceinline__ float lo_(u32 a){ return (float)__builtin_bit_cast(f2_t, a)[0]; }
__device__ __forceinline__ float hi_(u32 a){ return (float)__builtin_bit_cast(f2_t, a)[1]; }

// ---------------- graph-batch counts ----------------
__global__ void k_gcnt(const int* __restrict__ batch, int* __restrict__ gcnt){
  int n = blockIdx.x*256 + threadIdx.x;
  if (n < N_NODES_) atomicAdd(&gcnt[batch[n]], 1);
}

// ---------------- bucket histogram (replaces per-row k_counts) ----------------
__global__ void k_bhist(const int* __restrict__ ni, const int* __restrict__ hi,
                        int* __restrict__ totN, int* __restrict__ totH){
  __shared__ int hN[NBN5_], hH[NBH5_];
  for (int i = threadIdx.x; i < NBN5_; i += 256) hN[i] = 0;
  for (int i = threadIdx.x; i < NBH5_; i += 256) hH[i] = 0;
  __syncthreads();
  int stride = gridDim.x*256;
  for (int e = blockIdx.x*256 + threadIdx.x; e < E_; e += stride){
    atomicAdd(&hN[ni[e] >> 9], 1);
    atomicAdd(&hH[hi[e] >> 9], 1);
  }
  __syncthreads();
  for (int i = threadIdx.x; i < NBN5_; i += 256) if (hN[i]) atomicAdd(&totN[i], hN[i]);
  for (int i = threadIdx.x; i < NBH5_; i += 256) if (hH[i]) atomicAdd(&totH[i], hH[i]);
}

// ---------------- bucket-base scan (587 values, 1 block) ----------------
__global__ void k_bscan(const int* __restrict__ totN, const int* __restrict__ totH,
                        int* __restrict__ bbaseN, int* __restrict__ bbaseH,
                        int* __restrict__ gcurN, int* __restrict__ gcurH){
  __shared__ int tmp[512];
  int t = threadIdx.x;
  int v = (t < NBN5_) ? totN[t] : 0;
  tmp[t] = v; __syncthreads();
  for (int d = 1; d < 512; d <<= 1){
    int x = (t >= d) ? tmp[t-d] : 0; __syncthreads();
    tmp[t] += x; __syncthreads();
  }
  if (t < NBN5_){ int b = tmp[t] - v; bbaseN[t] = b; gcurN[t] = b; }
  __syncthreads();
  int w = (t < NBH5_) ? totH[t] : 0;
  tmp[t] = w; __syncthreads();
  for (int d = 1; d < 512; d <<= 1){
    int x = (t >= d) ? tmp[t-d] : 0; __syncthreads();
    tmp[t] += x; __syncthreads();
  }
  if (t < NBH5_){ int b = tmp[t] - w; bbaseH[t] = b; gcurH[t] = b; }
}

// ---------------- bucketed pair fill: per-block reserved contiguous runs ----------------
// pair encoding: (local_row_9b << 18) | id (< 2^18)
__global__ void k_binfill(const int* __restrict__ ni, const int* __restrict__ hi,
                          int* __restrict__ gcurN, int* __restrict__ gcurH,
                          u32* __restrict__ pairN, u32* __restrict__ pairH){
  __shared__ int histN[NBN5_], histH[NBH5_];
  __shared__ int baseN[NBN5_], baseH[NBH5_];
  const int nchunks = (E_ + CHUNK_ - 1)/CHUNK_;
  for (int c = blockIdx.x; c < nchunks; c += gridDim.x){
    int e0 = c*CHUNK_;
    int e1 = e0 + CHUNK_; if (e1 > E_) e1 = E_;
    for (int i = threadIdx.x; i < NBN5_; i += 256) histN[i] = 0;
    for (int i = threadIdx.x; i < NBH5_; i += 256) histH[i] = 0;
    __syncthreads();
    for (int e = e0 + threadIdx.x; e < e1; e += 256){
      atomicAdd(&histN[ni[e] >> 9], 1);
      atomicAdd(&histH[hi[e] >> 9], 1);
    }
    __syncthreads();
    for (int i = threadIdx.x; i < NBN5_; i += 256){
      int hv = histN[i];
      baseN[i] = hv ? atomicAdd(&gcurN[i], hv) : 0;
      histN[i] = 0;
    }
    for (int i = threadIdx.x; i < NBH5_; i += 256){
      int hv = histH[i];
      baseH[i] = hv ? atomicAdd(&gcurH[i], hv) : 0;
      histH[i] = 0;
    }
    __syncthreads();
    for (int e = e0 + threadIdx.x; e < e1; e += 256){
      int n = ni[e], he = hi[e];
      int bn = n >> 9, bh = he >> 9;
      int pn = baseN[bn] + atomicAdd(&histN[bn], 1);
      pairN[pn] = ((u32)(n & 511) << 18) | (u32)he;
      int ph = baseH[bh] + atomicAdd(&histH[bh], 1);
      pairH[ph] = ((u32)(he & 511) << 18) | (u32)n;
    }
    __syncthreads();
  }
}

// ---------------- csrfill2: per-bucket count + scan + place; writes CSR, counts, inv ------
__global__ void __launch_bounds__(512) k_csrfill2(
    const int* __restrict__ bbase, const int* __restrict__ gcur,
    const u32* __restrict__ pair, int nrows, int* __restrict__ out,
    int* __restrict__ off_arr, int* __restrict__ cnt_arr, float* __restrict__ inv_arr){
  __shared__ int cnt[512], cur[512], tmp[512];
  int b = blockIdx.x, t = threadIdx.x;   // 512 threads
  int nb = b*512;
  cnt[t] = 0;
  __syncthreads();
  int base = bbase[b], end = gcur[b];
  for (int pos = base + t; pos < end; pos += 512)
    atomicAdd(&cnt[pair[pos] >> 18], 1);
  __syncthreads();
  int v = cnt[t];
  tmp[t] = v; __syncthreads();
  for (int d = 1; d < 512; d <<= 1){
    int x = (t >= d) ? tmp[t-d] : 0; __syncthreads();
    tmp[t] += x; __syncthreads();
  }
  int ro = base + tmp[t] - v;            // exclusive row offset
  cur[t] = ro;
  int row = nb + t;
  if (row < nrows){
    off_arr[row] = ro;
    cnt_arr[row] = v;
    inv_arr[row] = 1.f/fmaxf((float)v, 1.f);
  }
  __syncthreads();
  for (int pos = base + t; pos < end; pos += 512){
    u32 p = pair[pos];
    int idx = atomicAdd(&cur[p >> 18], 1);
    out[idx] = (int)(p & 0x3FFFFu);
  }
}

// ---------------- pack hattr to fp16 pairs [NH][18] ----------------
__global__ void k_hattr_pack(const float* __restrict__ hattr, u32* __restrict__ hattr16){
  int i = blockIdx.x*256 + threadIdx.x;
  if (i >= N_HEDGES_*18) return;
  int he = i/18, p = i - he*18;
  int k0 = 2*p, k1 = 2*p + 1;
  float w0 = (k0 < 35) ? hattr[(size_t)he*35 + k0] : 0.f;
  float w1 = (k1 < 35) ? hattr[(size_t)he*35 + k1] : 0.f;
  hattr16[i] = pk_(w0, w1);
}

// ---------------- embed: h = x @ We + be ; also packed fp16 mirror ----------------
__global__ void k_embed(const float* __restrict__ x, const float* __restrict__ We,
                        const float* __restrict__ be, float* __restrict__ h,
                        u32* __restrict__ h16){
  __shared__ __align__(16) float As[64*100];
  __shared__ __align__(16) float Ws[64*100];
  int tid = threadIdx.x;
  for (int idx = tid; idx < 64*100; idx += 256){
    int c = idx/100, k = idx - c*100;
    Ws[idx] = (k < 92) ? We[k*64 + c] : 0.f;
  }
  int rt = tid & 15, ct = tid >> 4;
  float bias[4];
  #pragma unroll
  for (int j = 0; j < 4; ++j) bias[j] = be[ct*4 + j];
  const int ntiles = (N_NODES_ + 63)/64;
  for (int tile = blockIdx.x; tile < ntiles; tile += gridDim.x){
    int rbase = tile*64;
    __syncthreads();
    for (int idx = tid; idx < 64*100; idx += 256){
      int r = idx/100, k = idx - r*100;
      int rg = rbase + r;
      As[idx] = (rg < N_NODES_ && k < 92) ? x[(size_t)rg*92 + k] : 0.f;
    }
    __syncthreads();
    float acc[4][4] = {};
    for (int kc = 0; kc < 25; ++kc){
      float4 av[4], wv[4];
      #pragma unroll
      for (int i = 0; i < 4; ++i) av[i] = *(const float4*)&As[(rt + 16*i)*100 + kc*4];
      #pragma unroll
      for (int j = 0; j < 4; ++j) wv[j] = *(const float4*)&Ws[(ct*4 + j)*100 + kc*4];
      #pragma unroll
      for (int i = 0; i < 4; ++i)
        #pragma unroll
        for (int j = 0; j < 4; ++j)
          acc[i][j] += av[i].x*wv[j].x + av[i].y*wv[j].y + av[i].z*wv[j].z + av[i].w*wv[j].w;
    }
    #pragma unroll
    for (int i = 0; i < 4; ++i){
      int r = rbase + rt + 16*i;
      if (r < N_NODES_){
        float4 st;
        st.x = acc[i][0] + bias[0]; st.y = acc[i][1] + bias[1];
        st.z = acc[i][2] + bias[2]; st.w = acc[i][3] + bias[3];
        *(float4*)&h[(size_t)r*64 + ct*4] = st;
        h16[(size_t)r*32 + ct*2]     = pk_(st.x, st.y);
        h16[(size_t)r*32 + ct*2 + 1] = pk_(st.z, st.w);
      }
    }
  }
}

// ---------------- hedge gather (fp16, uint2): hmean16[he] = mean of h16 rows ----------------
__global__ void __launch_bounds__(256) k_gather_hedge(
    const u32* __restrict__ h16, const int* __restrict__ hedge_off,
    const int* __restrict__ hcnt, const int* __restrict__ edge_h,
    const float* __restrict__ hinv, u32* __restrict__ hmean16){
  int w = (blockIdx.x*256 + threadIdx.x) >> 4;
  int p = threadIdx.x & 15;
  if (w >= N_HEDGES_) return;
  int off = hedge_off[w], deg = hcnt[w];
  float a0 = 0.f, a1 = 0.f, a2 = 0.f, a3 = 0.f;
  int i = 0;
  for (; i + 1 < deg; i += 2){
    int n0 = edge_h[off+i], n1 = edge_h[off+i+1];
    uint2 u0 = *(const uint2*)&h16[(size_t)n0*32 + 2*p];
    uint2 u1 = *(const uint2*)&h16[(size_t)n1*32 + 2*p];
    a0 += lo_(u0.x) + lo_(u1.x); a1 += hi_(u0.x) + hi_(u1.x);
    a2 += lo_(u0.y) + lo_(u1.y); a3 += hi_(u0.y) + hi_(u1.y);
  }
  if (i < deg){
    uint2 u = *(const uint2*)&h16[(size_t)edge_h[off+i]*32 + 2*p];
    a0 += lo_(u.x); a1 += hi_(u.x); a2 += lo_(u.y); a3 += hi_(u.y);
  }
  float inv = hinv[w];
  uint2 st; st.x = pk_(a0*inv, a1*inv); st.y = pk_(a2*inv, a3*inv);
  *(uint2*)&hmean16[(size_t)w*32 + 2*p] = st;
}

// ---------------- hedge MLP pre-BN (dot2): tfcT[c][r] (transposed), reg-accum stats ------
__global__ void k_hedge_mlp1(const u32* __restrict__ hmean16, const u32* __restrict__ hattr16,
                             const float* __restrict__ Wf1, const float* __restrict__ bf1,
                             const float* __restrict__ Wc1, const float* __restrict__ bc1,
                             float* __restrict__ tfcT, float* __restrict__ hstats){
  __shared__ __align__(16) u32 As16[64*52];
  __shared__ __align__(16) u32 Ws16[80*52];
  __shared__ float sstat[160];
  int tid = threadIdx.x;
  for (int idx = tid; idx < 80*52; idx += 256){
    int c = idx/52, kk = idx - c*52;
    int k0 = 2*kk, k1 = 2*kk + 1;
    float w0 = 0.f, w1 = 0.f;
    if (c < 70){
      if (k0 < 99) w0 = (c < 35) ? Wf1[k0*35 + c] : Wc1[k0*35 + (c-35)];
      if (k1 < 99) w1 = (c < 35) ? Wf1[k1*35 + c] : Wc1[k1*35 + (c-35)];
    }
    Ws16[idx] = pk_(w0, w1);
  }
  for (int idx = tid; idx < 160; idx += 256) sstat[idx] = 0.f;
  int rt = tid & 15, ct = tid >> 4;
  float bias[5];
  #pragma unroll
  for (int j = 0; j < 5; ++j){
    int c = ct*5 + j;
    bias[j] = (c < 35) ? bf1[c] : (c < 70 ? bc1[c - 35] : 0.f);
  }
  float sreg[5] = {}, qreg[5] = {};
  for (int tile = blockIdx.x; tile < N_HEDGES_/64; tile += gridDim.x){
    int rbase = tile*64;
    __syncthreads();
    for (int idx = tid; idx < 64*52; idx += 256){
      int r = idx/52, kk = idx - r*52;
      int rg = rbase + r;
      u32 v = 0;
      if (kk < 32)      v = hmean16[(size_t)rg*32 + kk];
      else if (kk < 50) v = hattr16[(size_t)rg*18 + (kk - 32)];
      As16[idx] = v;
    }
    __syncthreads();
    float acc[4][5] = {};
    for (int kc = 0; kc < 13; ++kc){
      uint4 av[4], wv[5];
      #pragma unroll
      for (int i = 0; i < 4; ++i) av[i] = *(const uint4*)&As16[(rt + 16*i)*52 + kc*4];
      #pragma unroll
      for (int j = 0; j < 5; ++j) wv[j] = *(const uint4*)&Ws16[(ct*5 + j)*52 + kc*4];
      #pragma unroll
      for (int i = 0; i < 4; ++i)
        #pragma unroll
        for (int j = 0; j < 5; ++j){
          float a = acc[i][j];
          a = dot2_(av[i].x, wv[j].x, a);
          a = dot2_(av[i].y, wv[j].y, a);
          a = dot2_(av[i].z, wv[j].z, a);
          a = dot2_(av[i].w, wv[j].w, a);
          acc[i][j] = a;
        }
    }
    #pragma unroll
    for (int j = 0; j < 5; ++j){
      int c = ct*5 + j;
      if (c < 70){
        #pragma unroll
        for (int i = 0; i < 4; ++i){
          float v = acc[i][j] + bias[j];
          tfcT[(size_t)c*N_HEDGES_ + rbase + rt + 16*i] = v;
          sreg[j] += v; qreg[j] += v*v;
        }
      }
    }
  }
  int lane = tid & 63;
  #pragma unroll
  for (int j = 0; j < 5; ++j){
    float s = sreg[j], q = qreg[j];
    #pragma unroll
    for (int m = 1; m < 16; m <<= 1){
      s += __shfl_xor(s, m);
      q += __shfl_xor(q, m);
    }
    if ((lane & 15) == 0){
      int c = ct*5 + j;
      if (c < 70){
        atomicAdd(&sstat[c], s);
        atomicAdd(&sstat[80 + c], q);
      }
    }
  }
  __syncthreads();
  for (int idx = tid; idx < 160; idx += 256) atomicAdd(&hstats[idx], sstat[idx]);
}

// ---------------- BN finalize (hedge) ----------------
__global__ void k_bn_fin_hedge(const float* __restrict__ stats,
                               const float* __restrict__ gf, const float* __restrict__ btf,
                               const float* __restrict__ gc, const float* __restrict__ btc,
                               float* __restrict__ ab, float invN){
  int j = threadIdx.x;
  if (j >= 70) return;
  float m = stats[j]*invN;
  float var = stats[80+j]*invN - m*m;
  float gg = (j < 35) ? gf[j] : gc[j-35];
  float bb = (j < 35) ? btf[j] : btc[j-35];
  float a = gg*rsqrtf(var + 1e-5f);
  ab[j] = a; ab[70+j] = bb - m*a;
}

// ---------------- hedge feats + project (dot2, transposed tfcT reads): heFC2 fp16 ---------
__global__ void k_hedge_feats(const float* __restrict__ tfcT, const float* __restrict__ ab,
                              const float* __restrict__ Wf2, const float* __restrict__ bf2,
                              const float* __restrict__ Wc2, const float* __restrict__ bc2,
                              u32* __restrict__ heFC2){
  __shared__ __align__(16) u32 As16[64*20];
  __shared__ __align__(16) u32 Ws16[128*20];
  int tid = threadIdx.x;
  for (int idx = tid; idx < 128*20; idx += 256){
    int c = idx/20, kk = idx - c*20;
    int k0 = 2*kk, k1 = 2*kk + 1;
    float w0 = 0.f, w1 = 0.f;
    if (k0 < 35) w0 = (c < 64) ? Wf2[(64+k0)*64 + c] : Wc2[(64+k0)*64 + (c-64)];
    if (k1 < 35) w1 = (c < 64) ? Wf2[(64+k1)*64 + c] : Wc2[(64+k1)*64 + (c-64)];
    Ws16[idx] = pk_(w0, w1);
  }
  int rt = tid & 15, ct = tid >> 4;
  float biasF[4], biasC[4];
  #pragma unroll
  for (int j = 0; j < 4; ++j){ biasF[j] = bf2[ct*4 + j]; biasC[j] = bc2[ct*4 + j]; }
  for (int tile = blockIdx.x; tile < N_HEDGES_/64; tile += gridDim.x){
    int rbase = tile*64;
    __syncthreads();
    for (int idx = tid; idx < 64*20; idx += 256){
      int kk = idx >> 6;        // 0..19
      int r  = idx & 63;
      float a0 = 0.f, a1 = 0.f;
      if (kk < 18){
        int rg = rbase + r;
        int k0 = 2*kk, k1 = 2*kk + 1;
        {
          float tf = tfcT[(size_t)k0*N_HEDGES_ + rg];
          float tc = tfcT[(size_t)(35+k0)*N_HEDGES_ + rg];
          float zf = ab[k0]*tf + ab[70 + k0];
          float zc = ab[35+k0]*tc + ab[105 + k0];
          a0 = gate_(zf, zc);
        }
        if (k1 < 35){
          float tf = tfcT[(size_t)k1*N_HEDGES_ + rg];
          float tc = tfcT[(size_t)(35+k1)*N_HEDGES_ + rg];
          float zf = ab[k1]*tf + ab[70 + k1];
          float zc = ab[35+k1]*tc + ab[105 + k1];
          a1 = gate_(zf, zc);
        }
      }
      As16[r*20 + kk] = pk_(a0, a1);
    }
    __syncthreads();
    float accF[4][4] = {}, accC[4][4] = {};
    for (int kc = 0; kc < 5; ++kc){
      uint4 av[4], wF[4], wC[4];
      #pragma unroll
      for (int i = 0; i < 4; ++i) av[i] = *(const uint4*)&As16[(rt + 16*i)*20 + kc*4];
      #pragma unroll
      for (int j = 0; j < 4; ++j){
        wF[j] = *(const uint4*)&Ws16[(ct*4 + j)*20 + kc*4];
        wC[j] = *(const uint4*)&Ws16[(64 + ct*4 + j)*20 + kc*4];
      }
      #pragma unroll
      for (int i = 0; i < 4; ++i)
        #pragma unroll
        for (int j = 0; j < 4; ++j){
          float f = accF[i][j], c = accC[i][j];
          f = dot2_(av[i].x, wF[j].x, f); c = dot2_(av[i].x, wC[j].x, c);
          f = dot2_(av[i].y, wF[j].y, f); c = dot2_(av[i].y, wC[j].y, c);
          f = dot2_(av[i].z, wF[j].z, f); c = dot2_(av[i].z, wC[j].z, c);
          f = dot2_(av[i].w, wF[j].w, f); c = dot2_(av[i].w, wC[j].w, c);
          accF[i][j] = f; accC[i][j] = c;
        }
    }
    #pragma unroll
    for (int i = 0; i < 4; ++i){
      int r = rbase + rt + 16*i;
      #pragma unroll
      for (int j = 0; j < 4; ++j){
        heFC2[(size_t)r*64 + ct*4 + j] = pk_(accF[i][j] + biasF[j], accC[i][j] + biasC[j]);
      }
    }
  }
}

// ---------------- node projections (dot2): nFC2 packed fp16 ----------------
__global__ void k_node_lin(const u32* __restrict__ h16,
                           const float* __restrict__ Wf2, const float* __restrict__ Wc2,
                           u32* __restrict__ nFC2){
  __shared__ __align__(16) u32 As16[64*36];
  __shared__ __align__(16) u32 Ws16[128*36];
  int tid = threadIdx.x;
  for (int idx = tid; idx < 128*36; idx += 256){
    int c = idx/36, kk = idx - c*36;
    int k0 = 2*kk, k1 = 2*kk + 1;
    float w0 = 0.f, w1 = 0.f;
    if (k0 < 64) w0 = (c < 64) ? Wf2[k0*64 + c] : Wc2[k0*64 + (c-64)];
    if (k1 < 64) w1 = (c < 64) ? Wf2[k1*64 + c] : Wc2[k1*64 + (c-64)];
    Ws16[idx] = pk_(w0, w1);
  }
  int rt = tid & 15, ct = tid >> 4;
  const int ntiles = (N_NODES_ + 63)/64;
  for (int tile = blockIdx.x; tile < ntiles; tile += gridDim.x){
    int rbase = tile*64;
    __syncthreads();
    for (int idx = tid; idx < 64*36; idx += 256){
      int r = idx/36, kk = idx - r*36;
      int rg = rbase + r;
      As16[idx] = (rg < N_NODES_ && kk < 32) ? h16[(size_t)rg*32 + kk] : 0u;
    }
    __syncthreads();
    float accF[4][4] = {}, accC[4][4] = {};
    for (int kc = 0; kc < 8; ++kc){
      uint4 av[4], wF[4], wC[4];
      #pragma unroll
      for (int i = 0; i < 4; ++i) av[i] = *(const uint4*)&As16[(rt + 16*i)*36 + kc*4];
      #pragma unroll
      for (int j = 0; j < 4; ++j){
        wF[j] = *(const uint4*)&Ws16[(ct*4 + j)*36 + kc*4];
        wC[j] = *(const uint4*)&Ws16[(64 + ct*4 + j)*36 + kc*4];
      }
      #pragma unroll
      for (int i = 0; i < 4; ++i)
        #pragma unroll
        for (int j = 0; j < 4; ++j){
          float f = accF[i][j], c = accC[i][j];
          f = dot2_(av[i].x, wF[j].x, f); c = dot2_(av[i].x, wC[j].x, c);
          f = dot2_(av[i].y, wF[j].y, f); c = dot2_(av[i].y, wC[j].y, c);
          f = dot2_(av[i].z, wF[j].z, f); c = dot2_(av[i].z, wC[j].z, c);
          f = dot2_(av[i].w, wF[j].w, f); c = dot2_(av[i].w, wC[j].w, c);
          accF[i][j] = f; accC[i][j] = c;
        }
    }
    #pragma unroll
    for (int i = 0; i < 4; ++i){
      int r = rbase + rt + 16*i;
      if (r < N_NODES_){
        #pragma unroll
        for (int j = 0; j < 4; ++j){
          nFC2[(size_t)r*64 + ct*4 + j] = pk_(accF[i][j], accC[i][j]);
        }
      }
    }
  }
}

// ---------------- fused edge: node-CSR gather + gated act + mean + stats ------
__global__ void k_edge(const u32* __restrict__ nFC2, const u32* __restrict__ heFC2,
                       const int* __restrict__ node_off, const int* __restrict__ ndeg,
                       const int* __restrict__ edge_n, const float* __restrict__ ninv,
                       float* __restrict__ nmean, float* __restrict__ nstats){
  int lane = threadIdx.x & 63, wave = threadIdx.x >> 6;
  float s = 0.f, q = 0.f;
  for (int base = blockIdx.x*4; base < N_NODES_; base += gridDim.x*4){
    int n = base + wave;
    if (n < N_NODES_){
      int off = __builtin_amdgcn_readfirstlane(node_off[n]);
      int deg = __builtin_amdgcn_readfirstlane(ndeg[n]);
      u32 p0 = nFC2[(size_t)n*64 + lane];
      float acc = 0.f;
      int i = 0;
      for (; i + 3 < deg; i += 4){
        int e0 = edge_n[off+i], e1 = edge_n[off+i+1], e2 = edge_n[off+i+2], e3 = edge_n[off+i+3];
        u32 s0 = pkadd_(p0, heFC2[(size_t)e0*64 + lane]);
        u32 s1 = pkadd_(p0, heFC2[(size_t)e1*64 + lane]);
        u32 s2 = pkadd_(p0, heFC2[(size_t)e2*64 + lane]);
        u32 s3 = pkadd_(p0, heFC2[(size_t)e3*64 + lane]);
        acc += gate_(lo_(s0), hi_(s0)) + gate_(lo_(s1), hi_(s1))
             + gate_(lo_(s2), hi_(s2)) + gate_(lo_(s3), hi_(s3));
      }
      for (; i < deg; ++i){
        u32 sA = pkadd_(p0, heFC2[(size_t)edge_n[off+i]*64 + lane]);
        acc += gate_(lo_(sA), hi_(sA));
      }
      float m = acc * ninv[n];
      nmean[(size_t)n*64 + lane] = m;
      s += m; q += m*m;
    }
  }
  __shared__ float p1[256], p2[256];
  p1[threadIdx.x] = s; p2[threadIdx.x] = q;
  __syncthreads();
  if (wave == 0){
    float a = p1[lane] + p1[64+lane] + p1[128+lane] + p1[192+lane];
    float b = p2[lane] + p2[64+lane] + p2[128+lane] + p2[192+lane];
    atomicAdd(&nstats[lane], a);
    atomicAdd(&nstats[64+lane], b);
  }
}

__global__ void k_bn_fin_node(const float* __restrict__ stats, const float* __restrict__ g,
                              const float* __restrict__ bt, float* __restrict__ ab, float invN){
  int j = threadIdx.x;
  if (j >= 64) return;
  float m = stats[j]*invN;
  float var = stats[64+j]*invN - m*m;
  float a = g[j]*rsqrtf(var + 1e-5f);
  ab[j] = a; ab[64+j] = bt[j] - m*a;
}

// ---------------- node update: h' = softplus(BN(mean) + h), + fp16 mirror ----------------
__global__ void k_node_update(const float* __restrict__ nmean, const float* __restrict__ ab,
                              const float* __restrict__ h, float* __restrict__ hout,
                              u32* __restrict__ h16out){
  int t = blockIdx.x*256 + threadIdx.x;
  if (t >= N_NODES_*32) return;
  int p = t & 31;
  int f0 = 2*p, f1 = 2*p + 1;
  float2 nm = ((const float2*)nmean)[t];
  float2 hh = ((const float2*)h)[t];
  float r0 = sp_(ab[f0]*nm.x + ab[64+f0] + hh.x);
  float r1 = sp_(ab[f1]*nm.y + ab[64+f1] + hh.y);
  float2 st; st.x = r0; st.y = r1;
  ((float2*)hout)[t] = st;
  h16out[t] = pk_(r0, r1);
}

// ---------------- graph mean + head ----------------
__global__ void k_graph_agg(const float* __restrict__ h, const int* __restrict__ batch,
                            float* __restrict__ gsum){
  int t = blockIdx.x*256 + threadIdx.x;
  int n = t >> 6; if (n >= N_NODES_) return;
  int f = t & 63;
  atomicAdd(&gsum[(size_t)batch[n]*64+f], h[t]);
}

__global__ void k_head(const float* __restrict__ gsum, const int* __restrict__ gcnt,
                       const float* __restrict__ Wl2, const float* __restrict__ bl2,
                       const float* __restrict__ Wo, const float* __restrict__ bo,
                       float* __restrict__ out){
  __shared__ float gm[64];
  __shared__ float red[128];
  int g = blockIdx.x, j = threadIdx.x;
  if (j < 64) gm[j] = gsum[(size_t)g*64+j] / fmaxf((float)gcnt[g], 1.f);
  __syncthreads();
  float u = bl2[j];
  for (int f = 0; f < 64; ++f) u += gm[f]*Wl2[f*128+j];
  red[j] = sp_(u)*Wo[j];
  __syncthreads();
  for (int s = 64; s > 0; s >>= 1){
    if (j < s) red[j] += red[j+s];
    __syncthreads();
  }
  if (j == 0) out[g] = red[0] + bo[0];
}

extern "C" void kernel_launch(void* const* d_in, const int* in_sizes, int n_in,
                              void* d_out, int out_size, void* d_ws, size_t ws_size,
                              hipStream_t stream){
  (void)in_sizes; (void)n_in; (void)out_size; (void)ws_size;
  const float* x      = (const float*)d_in[0];
  const int*   ni     = (const int*)d_in[1];
  const int*   hi     = ni + E_;
  const float* hattr  = (const float*)d_in[2];
  const int*   batch  = (const int*)d_in[3];
  const float* We     = (const float*)d_in[4];
  const float* be     = (const float*)d_in[5];
  const float* Wf1    = (const float*)d_in[6];
  const float* bf1    = (const float*)d_in[7];
  const float* Wc1    = (const float*)d_in[8];
  const float* bc1    = (const float*)d_in[9];
  const float* Wf2    = (const float*)d_in[10];
  const float* bf2    = (const float*)d_in[11];
  const float* Wc2    = (const float*)d_in[12];
  const float* bc2    = (const float*)d_in[13];
  const float* bn_f_g = (const float*)d_in[14];
  const float* bn_f_b = (const float*)d_in[15];
  const float* bn_c_g = (const float*)d_in[16];
  const float* bn_c_b = (const float*)d_in[17];
  const float* bn_o_g = (const float*)d_in[18];
  const float* bn_o_b = (const float*)d_in[19];
  const float* Wl2    = (const float*)d_in[20];
  const float* bl2    = (const float*)d_in[21];
  const float* Wo     = (const float*)d_in[22];
  const float* bo     = (const float*)d_in[23];

  float* ws = (float*)d_ws;
  size_t o = 0;
  float* h0    = ws + o; o += (size_t)N_NODES_*H_;
  float* h1    = ws + o; o += (size_t)N_NODES_*H_;
  float* tfcT  = ws + o; o += (size_t)N_HEDGES_*70;    // 14.0M floats, [70][NH] transposed
  u32*   nFC2  = (u32*)tfcT;                           // alias: layer-time
  u32*   pairN = (u32*)tfcT;                           // alias: CSR-build-time only
  u32*   pairH = ((u32*)tfcT) + E_;
  float* hmR   = ws + o; o += (size_t)N_HEDGES_*H_;    // 12.8M floats region
  u32*   hmean16 = (u32*)hmR;
  u32*   heFC2   = (u32*)hmR;                          // hmean16 dead before heFC2 written
  float* nmean = ws + o; o += (size_t)N_NODES_*H_;
  u32*  h16a   = (u32*)(ws + o); o += (size_t)N_NODES_*32;
  u32*  h16b   = (u32*)(ws + o); o += (size_t)N_NODES_*32;
  u32*  hattr16= (u32*)(ws + o); o += (size_t)N_HEDGES_*18;
  float* hstats = ws + o; o += 256;
  float* habs   = ws + o; o += 256;
  float* nstats = ws + o; o += 128;
  float* nabs   = ws + o; o += 128;
  float* gsum   = ws + o; o += (size_t)G_*H_;
  float* hinv   = ws + o; o += N_HEDGES_;
  float* ninv   = ws + o; o += N_NODES_;
  int* hcnt     = (int*)(ws + o); o += N_HEDGES_;
  int* ndeg     = (int*)(ws + o); o += N_NODES_;
  int* gcnt     = (int*)(ws + o); o += G_;
  int* node_off = (int*)(ws + o); o += N_NODES_;
  int* hedge_off= (int*)(ws + o); o += N_HEDGES_;
  int* gcurN    = (int*)(ws + o); o += NBN5_;
  int* gcurH    = (int*)(ws + o); o += NBH5_;
  int* totN     = (int*)(ws + o); o += NBN5_;
  int* totH     = (int*)(ws + o); o += NBH5_;
  int* bbaseN   = (int*)(ws + o); o += NBN5_;
  int* bbaseH   = (int*)(ws + o); o += NBH5_;
  int* edge_n   = (int*)(ws + o); o += E_;
  int* edge_h   = (int*)(ws + o); o += E_;

  hipMemsetAsync(totN, 0, sizeof(int)*(NBN5_ + NBH5_), stream);  // totN,totH contiguous
  hipMemsetAsync(gcnt, 0, sizeof(int)*G_, stream);
  hipMemsetAsync(gsum, 0, sizeof(float)*G_*H_, stream);

  k_gcnt<<<(N_NODES_+255)/256, 256, 0, stream>>>(batch, gcnt);
  k_hattr_pack<<<(N_HEDGES_*18+255)/256, 256, 0, stream>>>(hattr, hattr16);

  // bucketed CSR build (no per-row atomics anywhere)
  k_bhist<<<512, 256, 0, stream>>>(ni, hi, totN, totH);
  k_bscan<<<1, 512, 0, stream>>>(totN, totH, bbaseN, bbaseH, gcurN, gcurH);
  k_binfill<<<(E_+CHUNK_-1)/CHUNK_, 256, 0, stream>>>(ni, hi, gcurN, gcurH, pairN, pairH);
  k_csrfill2<<<NBN5_, 512, 0, stream>>>(bbaseN, gcurN, pairN, N_NODES_, edge_n,
                                        node_off, ndeg, ninv);
  k_csrfill2<<<NBH5_, 512, 0, stream>>>(bbaseH, gcurH, pairH, N_HEDGES_, edge_h,
                                        hedge_off, hcnt, hinv);

  k_embed<<<768, 256, 0, stream>>>(x, We, be, h0, h16a);

  float* hcur2 = h0;  u32* hc16 = h16a;
  float* hnxt  = h1;  u32* hn16 = h16b;
  for (int l = 0; l < L_; ++l){
    const float* Wf1l = Wf1 + (size_t)l*D_*HE_;
    const float* Wc1l = Wc1 + (size_t)l*D_*HE_;
    const float* Wf2l = Wf2 + (size_t)l*D_*H_;
    const float* Wc2l = Wc2 + (size_t)l*D_*H_;

    hipMemsetAsync(hstats, 0, sizeof(float)*160, stream);
    hipMemsetAsync(nstats, 0, sizeof(float)*128, stream);

    k_gather_hedge<<<(N_HEDGES_*16)/256, 256, 0, stream>>>(hc16, hedge_off, hcnt, edge_h,
                                                           hinv, hmean16);
    k_hedge_mlp1<<<1280, 256, 0, stream>>>(hmean16, hattr16, Wf1l, bf1 + l*HE_,
                                           Wc1l, bc1 + l*HE_, tfcT, hstats);
    k_bn_fin_hedge<<<1, 128, 0, stream>>>(hstats, bn_f_g + l*HE_, bn_f_b + l*HE_,
                                          bn_c_g + l*HE_, bn_c_b + l*HE_, habs,
                                          1.f/(float)N_HEDGES_);
    k_hedge_feats<<<1536, 256, 0, stream>>>(tfcT, habs, Wf2l, bf2 + l*H_,
                                            Wc2l, bc2 + l*H_, heFC2);
    k_node_lin<<<1024, 256, 0, stream>>>(hc16, Wf2l, Wc2l, nFC2);
    k_edge<<<2048, 256, 0, stream>>>(nFC2, heFC2, node_off, ndeg, edge_n, ninv, nmean, nstats);
    k_bn_fin_node<<<1, 64, 0, stream>>>(nstats, bn_o_g + l*H_, bn_o_b + l*H_, nabs,
                                        1.f/(float)N_NODES_);
    k_node_update<<<(N_NODES_*32+255)/256, 256, 0, stream>>>(nmean, nabs, hcur2, hnxt, hn16);
    float* t2 = hcur2; hcur2 = hnxt; hnxt = t2;
    u32* t3 = hc16; hc16 = hn16; hn16 = t3;
  }

  k_graph_agg<<<(N_NODES_*H_+255)/256, 256, 0, stream>>>(hcur2, batch, gsum);
  k_head<<<G_, 128, 0, stream>>>(gsum, gcnt, Wl2, bl2, Wo, bo, (float*)d_out);
}

// Round 13
// 1284.162 us; speedup vs baseline: 1.2685x; 1.0217x over previous
//
#include <hip/hip_runtime.h>
#include <cstddef>

#define N_NODES_  100000
#define N_HEDGES_ 200000
#define E_        1200000
#define G_        512
#define H_        64
#define HE_       35
#define D_        99      // H_+HE_
#define HOUT_     128
#define L_        3
#define NBN5_     196     // ceil(N_NODES/512)
#define NBH5_     391     // ceil(N_HEDGES/512)
#define CHUNK_    4096

typedef unsigned int u32;
typedef _Float16 f2_t __attribute__((ext_vector_type(2)));

__device__ __forceinline__ float sigm_(float x){
  return __builtin_amdgcn_rcpf(1.f + __expf(-x));
}
__device__ __forceinline__ float sp_(float x){
  return fmaxf(x, 0.f) + __logf(1.f + __expf(-fabsf(x)));
}
__device__ __forceinline__ float gate_(float F, float C){ return sigm_(F)*sp_(C); }

__device__ __forceinline__ u32 pk_(float a, float b){
  return __builtin_bit_cast(u32, __builtin_amdgcn_cvt_pkrtz(a, b));
}
__device__ __forceinline__ u32 pkadd_(u32 a, u32 b){
  f2_t s = __builtin_bit_cast(f2_t, a) + __builtin_bit_cast(f2_t, b);
  return __builtin_bit_cast(u32, s);
}
__device__ __forceinline__ float dot2_(u32 a, u32 b, float c){
#if __has_builtin(__builtin_amdgcn_fdot2)
  return __builtin_amdgcn_fdot2(__builtin_bit_cast(f2_t, a),
                                __builtin_bit_cast(f2_t, b), c, false);
#else
  f2_t x = __builtin_bit_cast(f2_t, a), y = __builtin_bit_cast(f2_t, b);
  return c + (float)x[0]*(float)y[0] + (float)x[1]*(float)y[1];
#endif
}
__device__ __forceinline__ float lo_(u32 a){ return (float)__builtin_bit_cast(f2_t, a)[0]; }
__device__ __forceinline__ float hi_(u32 a){ return (float)__builtin_bit_cast(f2_t, a)[1]; }

// ---------------- graph-batch counts ----------------
__global__ void k_gcnt(const int* __restrict__ batch, int* __restrict__ gcnt){
  int n = blockIdx.x*256 + threadIdx.x;
  if (n < N_NODES_) atomicAdd(&gcnt[batch[n]], 1);
}

// ---------------- bucket histogram ----------------
__global__ void k_bhist(const int* __restrict__ ni, const int* __restrict__ hi,
                        int* __restrict__ totN, int* __restrict__ totH){
  __shared__ int hN[NBN5_], hH[NBH5_];
  for (int i = threadIdx.x; i < NBN5_; i += 256) hN[i] = 0;
  for (int i = threadIdx.x; i < NBH5_; i += 256) hH[i] = 0;
  __syncthreads();
  int stride = gridDim.x*256;
  for (int e = blockIdx.x*256 + threadIdx.x; e < E_; e += stride){
    atomicAdd(&hN[ni[e] >> 9], 1);
    atomicAdd(&hH[hi[e] >> 9], 1);
  }
  __syncthreads();
  for (int i = threadIdx.x; i < NBN5_; i += 256) if (hN[i]) atomicAdd(&totN[i], hN[i]);
  for (int i = threadIdx.x; i < NBH5_; i += 256) if (hH[i]) atomicAdd(&totH[i], hH[i]);
}

// ---------------- bucket-base scan ----------------
__global__ void k_bscan(const int* __restrict__ totN, const int* __restrict__ totH,
                        int* __restrict__ bbaseN, int* __restrict__ bbaseH,
                        int* __restrict__ gcurN, int* __restrict__ gcurH){
  __shared__ int tmp[512];
  int t = threadIdx.x;
  int v = (t < NBN5_) ? totN[t] : 0;
  tmp[t] = v; __syncthreads();
  for (int d = 1; d < 512; d <<= 1){
    int x = (t >= d) ? tmp[t-d] : 0; __syncthreads();
    tmp[t] += x; __syncthreads();
  }
  if (t < NBN5_){ int b = tmp[t] - v; bbaseN[t] = b; gcurN[t] = b; }
  __syncthreads();
  int w = (t < NBH5_) ? totH[t] : 0;
  tmp[t] = w; __syncthreads();
  for (int d = 1; d < 512; d <<= 1){
    int x = (t >= d) ? tmp[t-d] : 0; __syncthreads();
    tmp[t] += x; __syncthreads();
  }
  if (t < NBH5_){ int b = tmp[t] - w; bbaseH[t] = b; gcurH[t] = b; }
}

// ---------------- bucketed pair fill ----------------
// pair encoding: (local_row_9b << 18) | id (< 2^18)
__global__ void k_binfill(const int* __restrict__ ni, const int* __restrict__ hi,
                          int* __restrict__ gcurN, int* __restrict__ gcurH,
                          u32* __restrict__ pairN, u32* __restrict__ pairH){
  __shared__ int histN[NBN5_], histH[NBH5_];
  __shared__ int baseN[NBN5_], baseH[NBH5_];
  const int nchunks = (E_ + CHUNK_ - 1)/CHUNK_;
  for (int c = blockIdx.x; c < nchunks; c += gridDim.x){
    int e0 = c*CHUNK_;
    int e1 = e0 + CHUNK_; if (e1 > E_) e1 = E_;
    for (int i = threadIdx.x; i < NBN5_; i += 256) histN[i] = 0;
    for (int i = threadIdx.x; i < NBH5_; i += 256) histH[i] = 0;
    __syncthreads();
    for (int e = e0 + threadIdx.x; e < e1; e += 256){
      atomicAdd(&histN[ni[e] >> 9], 1);
      atomicAdd(&histH[hi[e] >> 9], 1);
    }
    __syncthreads();
    for (int i = threadIdx.x; i < NBN5_; i += 256){
      int hv = histN[i];
      baseN[i] = hv ? atomicAdd(&gcurN[i], hv) : 0;
      histN[i] = 0;
    }
    for (int i = threadIdx.x; i < NBH5_; i += 256){
      int hv = histH[i];
      baseH[i] = hv ? atomicAdd(&gcurH[i], hv) : 0;
      histH[i] = 0;
    }
    __syncthreads();
    for (int e = e0 + threadIdx.x; e < e1; e += 256){
      int n = ni[e], he = hi[e];
      int bn = n >> 9, bh = he >> 9;
      int pn = baseN[bn] + atomicAdd(&histN[bn], 1);
      pairN[pn] = ((u32)(n & 511) << 18) | (u32)he;
      int ph = baseH[bh] + atomicAdd(&histH[bh], 1);
      pairH[ph] = ((u32)(he & 511) << 18) | (u32)n;
    }
    __syncthreads();
  }
}

// ---------------- csrfill2: per-bucket count + scan + place ----------------
__global__ void __launch_bounds__(512) k_csrfill2(
    const int* __restrict__ bbase, const int* __restrict__ gcur,
    const u32* __restrict__ pair, int nrows, int* __restrict__ out,
    int* __restrict__ off_arr, int* __restrict__ cnt_arr, float* __restrict__ inv_arr){
  __shared__ int cnt[512], cur[512], tmp[512];
  int b = blockIdx.x, t = threadIdx.x;
  int nb = b*512;
  cnt[t] = 0;
  __syncthreads();
  int base = bbase[b], end = gcur[b];
  for (int pos = base + t; pos < end; pos += 512)
    atomicAdd(&cnt[pair[pos] >> 18], 1);
  __syncthreads();
  int v = cnt[t];
  tmp[t] = v; __syncthreads();
  for (int d = 1; d < 512; d <<= 1){
    int x = (t >= d) ? tmp[t-d] : 0; __syncthreads();
    tmp[t] += x; __syncthreads();
  }
  int ro = base + tmp[t] - v;
  cur[t] = ro;
  int row = nb + t;
  if (row < nrows){
    off_arr[row] = ro;
    cnt_arr[row] = v;
    inv_arr[row] = 1.f/fmaxf((float)v, 1.f);
  }
  __syncthreads();
  for (int pos = base + t; pos < end; pos += 512){
    u32 p = pair[pos];
    int idx = atomicAdd(&cur[p >> 18], 1);
    out[idx] = (int)(p & 0x3FFFFu);
  }
}

// ---------------- pack hattr to fp16 pairs [NH][18] ----------------
__global__ void k_hattr_pack(const float* __restrict__ hattr, u32* __restrict__ hattr16){
  int i = blockIdx.x*256 + threadIdx.x;
  if (i >= N_HEDGES_*18) return;
  int he = i/18, p = i - he*18;
  int k0 = 2*p, k1 = 2*p + 1;
  float w0 = (k0 < 35) ? hattr[(size_t)he*35 + k0] : 0.f;
  float w1 = (k1 < 35) ? hattr[(size_t)he*35 + k1] : 0.f;
  hattr16[i] = pk_(w0, w1);
}

// ---------------- embed: h16 = fp16( x @ We + be ) ----------------
__global__ void k_embed(const float* __restrict__ x, const float* __restrict__ We,
                        const float* __restrict__ be, u32* __restrict__ h16){
  __shared__ __align__(16) float As[64*100];
  __shared__ __align__(16) float Ws[64*100];
  int tid = threadIdx.x;
  for (int idx = tid; idx < 64*100; idx += 256){
    int c = idx/100, k = idx - c*100;
    Ws[idx] = (k < 92) ? We[k*64 + c] : 0.f;
  }
  int rt = tid & 15, ct = tid >> 4;
  float bias[4];
  #pragma unroll
  for (int j = 0; j < 4; ++j) bias[j] = be[ct*4 + j];
  const int ntiles = (N_NODES_ + 63)/64;
  for (int tile = blockIdx.x; tile < ntiles; tile += gridDim.x){
    int rbase = tile*64;
    __syncthreads();
    for (int idx = tid; idx < 64*100; idx += 256){
      int r = idx/100, k = idx - r*100;
      int rg = rbase + r;
      As[idx] = (rg < N_NODES_ && k < 92) ? x[(size_t)rg*92 + k] : 0.f;
    }
    __syncthreads();
    float acc[4][4] = {};
    for (int kc = 0; kc < 25; ++kc){
      float4 av[4], wv[4];
      #pragma unroll
      for (int i = 0; i < 4; ++i) av[i] = *(const float4*)&As[(rt + 16*i)*100 + kc*4];
      #pragma unroll
      for (int j = 0; j < 4; ++j) wv[j] = *(const float4*)&Ws[(ct*4 + j)*100 + kc*4];
      #pragma unroll
      for (int i = 0; i < 4; ++i)
        #pragma unroll
        for (int j = 0; j < 4; ++j)
          acc[i][j] += av[i].x*wv[j].x + av[i].y*wv[j].y + av[i].z*wv[j].z + av[i].w*wv[j].w;
    }
    #pragma unroll
    for (int i = 0; i < 4; ++i){
      int r = rbase + rt + 16*i;
      if (r < N_NODES_){
        h16[(size_t)r*32 + ct*2]     = pk_(acc[i][0] + bias[0], acc[i][1] + bias[1]);
        h16[(size_t)r*32 + ct*2 + 1] = pk_(acc[i][2] + bias[2], acc[i][3] + bias[3]);
      }
    }
  }
}

// ---------------- hedge gather (fp16, uint4, 8 lanes/hedge) ----------------
__global__ void __launch_bounds__(256) k_gather_hedge(
    const u32* __restrict__ h16, const int* __restrict__ hedge_off,
    const int* __restrict__ hcnt, const int* __restrict__ edge_h,
    const float* __restrict__ hinv, u32* __restrict__ hmean16){
  int w = (blockIdx.x*256 + threadIdx.x) >> 3;
  int p = threadIdx.x & 7;
  if (w >= N_HEDGES_) return;
  int off = hedge_off[w], deg = hcnt[w];
  float a[8] = {};
  int i = 0;
  for (; i + 1 < deg; i += 2){
    int n0 = edge_h[off+i], n1 = edge_h[off+i+1];
    uint4 u0 = *(const uint4*)&h16[(size_t)n0*32 + 4*p];
    uint4 u1 = *(const uint4*)&h16[(size_t)n1*32 + 4*p];
    a[0] += lo_(u0.x) + lo_(u1.x); a[1] += hi_(u0.x) + hi_(u1.x);
    a[2] += lo_(u0.y) + lo_(u1.y); a[3] += hi_(u0.y) + hi_(u1.y);
    a[4] += lo_(u0.z) + lo_(u1.z); a[5] += hi_(u0.z) + hi_(u1.z);
    a[6] += lo_(u0.w) + lo_(u1.w); a[7] += hi_(u0.w) + hi_(u1.w);
  }
  if (i < deg){
    uint4 u = *(const uint4*)&h16[(size_t)edge_h[off+i]*32 + 4*p];
    a[0] += lo_(u.x); a[1] += hi_(u.x); a[2] += lo_(u.y); a[3] += hi_(u.y);
    a[4] += lo_(u.z); a[5] += hi_(u.z); a[6] += lo_(u.w); a[7] += hi_(u.w);
  }
  float inv = hinv[w];
  uint4 st;
  st.x = pk_(a[0]*inv, a[1]*inv); st.y = pk_(a[2]*inv, a[3]*inv);
  st.z = pk_(a[4]*inv, a[5]*inv); st.w = pk_(a[6]*inv, a[7]*inv);
  *(uint4*)&hmean16[(size_t)w*32 + 4*p] = st;
}

// ---------------- hedge MLP pre-BN (dot2): tfc16T[c][r] fp16, reg-accum stats ------
__global__ void k_hedge_mlp1(const u32* __restrict__ hmean16, const u32* __restrict__ hattr16,
                             const float* __restrict__ Wf1, const float* __restrict__ bf1,
                             const float* __restrict__ Wc1, const float* __restrict__ bc1,
                             __fp16* __restrict__ tfc16T, float* __restrict__ hstats){
  __shared__ __align__(16) u32 As16[64*52];
  __shared__ __align__(16) u32 Ws16[80*52];
  __shared__ float sstat[160];
  int tid = threadIdx.x;
  for (int idx = tid; idx < 80*52; idx += 256){
    int c = idx/52, kk = idx - c*52;
    int k0 = 2*kk, k1 = 2*kk + 1;
    float w0 = 0.f, w1 = 0.f;
    if (c < 70){
      if (k0 < 99) w0 = (c < 35) ? Wf1[k0*35 + c] : Wc1[k0*35 + (c-35)];
      if (k1 < 99) w1 = (c < 35) ? Wf1[k1*35 + c] : Wc1[k1*35 + (c-35)];
    }
    Ws16[idx] = pk_(w0, w1);
  }
  for (int idx = tid; idx < 160; idx += 256) sstat[idx] = 0.f;
  int rt = tid & 15, ct = tid >> 4;
  float bias[5];
  #pragma unroll
  for (int j = 0; j < 5; ++j){
    int c = ct*5 + j;
    bias[j] = (c < 35) ? bf1[c] : (c < 70 ? bc1[c - 35] : 0.f);
  }
  float sreg[5] = {}, qreg[5] = {};
  for (int tile = blockIdx.x; tile < N_HEDGES_/64; tile += gridDim.x){
    int rbase = tile*64;
    __syncthreads();
    for (int idx = tid; idx < 64*52; idx += 256){
      int r = idx/52, kk = idx - r*52;
      int rg = rbase + r;
      u32 v = 0;
      if (kk < 32)      v = hmean16[(size_t)rg*32 + kk];
      else if (kk < 50) v = hattr16[(size_t)rg*18 + (kk - 32)];
      As16[idx] = v;
    }
    __syncthreads();
    float acc[4][5] = {};
    for (int kc = 0; kc < 13; ++kc){
      uint4 av[4], wv[5];
      #pragma unroll
      for (int i = 0; i < 4; ++i) av[i] = *(const uint4*)&As16[(rt + 16*i)*52 + kc*4];
      #pragma unroll
      for (int j = 0; j < 5; ++j) wv[j] = *(const uint4*)&Ws16[(ct*5 + j)*52 + kc*4];
      #pragma unroll
      for (int i = 0; i < 4; ++i)
        #pragma unroll
        for (int j = 0; j < 5; ++j){
          float a = acc[i][j];
          a = dot2_(av[i].x, wv[j].x, a);
          a = dot2_(av[i].y, wv[j].y, a);
          a = dot2_(av[i].z, wv[j].z, a);
          a = dot2_(av[i].w, wv[j].w, a);
          acc[i][j] = a;
        }
    }
    #pragma unroll
    for (int j = 0; j < 5; ++j){
      int c = ct*5 + j;
      if (c < 70){
        #pragma unroll
        for (int i = 0; i < 4; ++i){
          float v = acc[i][j] + bias[j];
          tfc16T[(size_t)c*N_HEDGES_ + rbase + rt + 16*i] = (__fp16)v;
          sreg[j] += v; qreg[j] += v*v;
        }
      }
    }
  }
  int lane = tid & 63;
  #pragma unroll
  for (int j = 0; j < 5; ++j){
    float s = sreg[j], q = qreg[j];
    #pragma unroll
    for (int m = 1; m < 16; m <<= 1){
      s += __shfl_xor(s, m);
      q += __shfl_xor(q, m);
    }
    if ((lane & 15) == 0){
      int c = ct*5 + j;
      if (c < 70){
        atomicAdd(&sstat[c], s);
        atomicAdd(&sstat[80 + c], q);
      }
    }
  }
  __syncthreads();
  for (int idx = tid; idx < 160; idx += 256) atomicAdd(&hstats[idx], sstat[idx]);
}

// ---------------- BN finalize (hedge) ----------------
__global__ void k_bn_fin_hedge(const float* __restrict__ stats,
                               const float* __restrict__ gf, const float* __restrict__ btf,
                               const float* __restrict__ gc, const float* __restrict__ btc,
                               float* __restrict__ ab, float invN){
  int j = threadIdx.x;
  if (j >= 70) return;
  float m = stats[j]*invN;
  float var = stats[80+j]*invN - m*m;
  float gg = (j < 35) ? gf[j] : gc[j-35];
  float bb = (j < 35) ? btf[j] : btc[j-35];
  float a = gg*rsqrtf(var + 1e-5f);
  ab[j] = a; ab[70+j] = bb - m*a;
}

// ---------------- hedge feats + project (dot2, fp16 tfc16T reads): heFC2 fp16 ---------
__global__ void k_hedge_feats(const __fp16* __restrict__ tfc16T, const float* __restrict__ ab,
                              const float* __restrict__ Wf2, const float* __restrict__ bf2,
                              const float* __restrict__ Wc2, const float* __restrict__ bc2,
                              u32* __restrict__ heFC2){
  __shared__ __align__(16) u32 As16[64*20];
  __shared__ __align__(16) u32 Ws16[128*20];
  int tid = threadIdx.x;
  for (int idx = tid; idx < 128*20; idx += 256){
    int c = idx/20, kk = idx - c*20;
    int k0 = 2*kk, k1 = 2*kk + 1;
    float w0 = 0.f, w1 = 0.f;
    if (k0 < 35) w0 = (c < 64) ? Wf2[(64+k0)*64 + c] : Wc2[(64+k0)*64 + (c-64)];
    if (k1 < 35) w1 = (c < 64) ? Wf2[(64+k1)*64 + c] : Wc2[(64+k1)*64 + (c-64)];
    Ws16[idx] = pk_(w0, w1);
  }
  int rt = tid & 15, ct = tid >> 4;
  float biasF[4], biasC[4];
  #pragma unroll
  for (int j = 0; j < 4; ++j){ biasF[j] = bf2[ct*4 + j]; biasC[j] = bc2[ct*4 + j]; }
  for (int tile = blockIdx.x; tile < N_HEDGES_/64; tile += gridDim.x){
    int rbase = tile*64;
    __syncthreads();
    for (int idx = tid; idx < 64*20; idx += 256){
      int kk = idx >> 6;        // 0..19
      int r  = idx & 63;
      float a0 = 0.f, a1 = 0.f;
      if (kk < 18){
        int rg = rbase + r;
        int k0 = 2*kk, k1 = 2*kk + 1;
        {
          float tf = (float)tfc16T[(size_t)k0*N_HEDGES_ + rg];
          float tc = (float)tfc16T[(size_t)(35+k0)*N_HEDGES_ + rg];
          float zf = ab[k0]*tf + ab[70 + k0];
          float zc = ab[35+k0]*tc + ab[105 + k0];
          a0 = gate_(zf, zc);
        }
        if (k1 < 35){
          float tf = (float)tfc16T[(size_t)k1*N_HEDGES_ + rg];
          float tc = (float)tfc16T[(size_t)(35+k1)*N_HEDGES_ + rg];
          float zf = ab[k1]*tf + ab[70 + k1];
          float zc = ab[35+k1]*tc + ab[105 + k1];
          a1 = gate_(zf, zc);
        }
      }
      As16[r*20 + kk] = pk_(a0, a1);
    }
    __syncthreads();
    float accF[4][4] = {}, accC[4][4] = {};
    for (int kc = 0; kc < 5; ++kc){
      uint4 av[4], wF[4], wC[4];
      #pragma unroll
      for (int i = 0; i < 4; ++i) av[i] = *(const uint4*)&As16[(rt + 16*i)*20 + kc*4];
      #pragma unroll
      for (int j = 0; j < 4; ++j){
        wF[j] = *(const uint4*)&Ws16[(ct*4 + j)*20 + kc*4];
        wC[j] = *(const uint4*)&Ws16[(64 + ct*4 + j)*20 + kc*4];
      }
      #pragma unroll
      for (int i = 0; i < 4; ++i)
        #pragma unroll
        for (int j = 0; j < 4; ++j){
          float f = accF[i][j], c = accC[i][j];
          f = dot2_(av[i].x, wF[j].x, f); c = dot2_(av[i].x, wC[j].x, c);
          f = dot2_(av[i].y, wF[j].y, f); c = dot2_(av[i].y, wC[j].y, c);
          f = dot2_(av[i].z, wF[j].z, f); c = dot2_(av[i].z, wC[j].z, c);
          f = dot2_(av[i].w, wF[j].w, f); c = dot2_(av[i].w, wC[j].w, c);
          accF[i][j] = f; accC[i][j] = c;
        }
    }
    #pragma unroll
    for (int i = 0; i < 4; ++i){
      int r = rbase + rt + 16*i;
      #pragma unroll
      for (int j = 0; j < 4; ++j){
        heFC2[(size_t)r*64 + ct*4 + j] = pk_(accF[i][j] + biasF[j], accC[i][j] + biasC[j]);
      }
    }
  }
}

// ---------------- node projections (dot2): nFC2 packed fp16 ----------------
__global__ void k_node_lin(const u32* __restrict__ h16,
                           const float* __restrict__ Wf2, const float* __restrict__ Wc2,
                           u32* __restrict__ nFC2){
  __shared__ __align__(16) u32 As16[64*36];
  __shared__ __align__(16) u32 Ws16[128*36];
  int tid = threadIdx.x;
  for (int idx = tid; idx < 128*36; idx += 256){
    int c = idx/36, kk = idx - c*36;
    int k0 = 2*kk, k1 = 2*kk + 1;
    float w0 = 0.f, w1 = 0.f;
    if (k0 < 64) w0 = (c < 64) ? Wf2[k0*64 + c] : Wc2[k0*64 + (c-64)];
    if (k1 < 64) w1 = (c < 64) ? Wf2[k1*64 + c] : Wc2[k1*64 + (c-64)];
    Ws16[idx] = pk_(w0, w1);
  }
  int rt = tid & 15, ct = tid >> 4;
  const int ntiles = (N_NODES_ + 63)/64;
  for (int tile = blockIdx.x; tile < ntiles; tile += gridDim.x){
    int rbase = tile*64;
    __syncthreads();
    for (int idx = tid; idx < 64*36; idx += 256){
      int r = idx/36, kk = idx - r*36;
      int rg = rbase + r;
      As16[idx] = (rg < N_NODES_ && kk < 32) ? h16[(size_t)rg*32 + kk] : 0u;
    }
    __syncthreads();
    float accF[4][4] = {}, accC[4][4] = {};
    for (int kc = 0; kc < 8; ++kc){
      uint4 av[4], wF[4], wC[4];
      #pragma unroll
      for (int i = 0; i < 4; ++i) av[i] = *(const uint4*)&As16[(rt + 16*i)*36 + kc*4];
      #pragma unroll
      for (int j = 0; j < 4; ++j){
        wF[j] = *(const uint4*)&Ws16[(ct*4 + j)*36 + kc*4];
        wC[j] = *(const uint4*)&Ws16[(64 + ct*4 + j)*36 + kc*4];
      }
      #pragma unroll
      for (int i = 0; i < 4; ++i)
        #pragma unroll
        for (int j = 0; j < 4; ++j){
          float f = accF[i][j], c = accC[i][j];
          f = dot2_(av[i].x, wF[j].x, f); c = dot2_(av[i].x, wC[j].x, c);
          f = dot2_(av[i].y, wF[j].y, f); c = dot2_(av[i].y, wC[j].y, c);
          f = dot2_(av[i].z, wF[j].z, f); c = dot2_(av[i].z, wC[j].z, c);
          f = dot2_(av[i].w, wF[j].w, f); c = dot2_(av[i].w, wC[j].w, c);
          accF[i][j] = f; accC[i][j] = c;
        }
    }
    #pragma unroll
    for (int i = 0; i < 4; ++i){
      int r = rbase + rt + 16*i;
      if (r < N_NODES_){
        #pragma unroll
        for (int j = 0; j < 4; ++j){
          nFC2[(size_t)r*64 + ct*4 + j] = pk_(accF[i][j], accC[i][j]);
        }
      }
    }
  }
}

// ---------------- fused edge: node-CSR gather + gated act + mean(fp16) + stats ------
__global__ void k_edge(const u32* __restrict__ nFC2, const u32* __restrict__ heFC2,
                       const int* __restrict__ node_off, const int* __restrict__ ndeg,
                       const int* __restrict__ edge_n, const float* __restrict__ ninv,
                       __fp16* __restrict__ nmean16, float* __restrict__ nstats){
  int lane = threadIdx.x & 63, wave = threadIdx.x >> 6;
  float s = 0.f, q = 0.f;
  for (int base = blockIdx.x*4; base < N_NODES_; base += gridDim.x*4){
    int n = base + wave;
    if (n < N_NODES_){
      int off = __builtin_amdgcn_readfirstlane(node_off[n]);
      int deg = __builtin_amdgcn_readfirstlane(ndeg[n]);
      u32 p0 = nFC2[(size_t)n*64 + lane];
      float acc = 0.f;
      int i = 0;
      for (; i + 7 < deg; i += 8){
        int e0 = edge_n[off+i],   e1 = edge_n[off+i+1], e2 = edge_n[off+i+2], e3 = edge_n[off+i+3];
        int e4 = edge_n[off+i+4], e5 = edge_n[off+i+5], e6 = edge_n[off+i+6], e7 = edge_n[off+i+7];
        u32 s0 = pkadd_(p0, heFC2[(size_t)e0*64 + lane]);
        u32 s1 = pkadd_(p0, heFC2[(size_t)e1*64 + lane]);
        u32 s2 = pkadd_(p0, heFC2[(size_t)e2*64 + lane]);
        u32 s3 = pkadd_(p0, heFC2[(size_t)e3*64 + lane]);
        u32 s4 = pkadd_(p0, heFC2[(size_t)e4*64 + lane]);
        u32 s5 = pkadd_(p0, heFC2[(size_t)e5*64 + lane]);
        u32 s6 = pkadd_(p0, heFC2[(size_t)e6*64 + lane]);
        u32 s7 = pkadd_(p0, heFC2[(size_t)e7*64 + lane]);
        acc += gate_(lo_(s0), hi_(s0)) + gate_(lo_(s1), hi_(s1))
             + gate_(lo_(s2), hi_(s2)) + gate_(lo_(s3), hi_(s3))
             + gate_(lo_(s4), hi_(s4)) + gate_(lo_(s5), hi_(s5))
             + gate_(lo_(s6), hi_(s6)) + gate_(lo_(s7), hi_(s7));
      }
      for (; i + 3 < deg; i += 4){
        int e0 = edge_n[off+i], e1 = edge_n[off+i+1], e2 = edge_n[off+i+2], e3 = edge_n[off+i+3];
        u32 s0 = pkadd_(p0, heFC2[(size_t)e0*64 + lane]);
        u32 s1 = pkadd_(p0, heFC2[(size_t)e1*64 + lane]);
        u32 s2 = pkadd_(p0, heFC2[(size_t)e2*64 + lane]);
        u32 s3 = pkadd_(p0, heFC2[(size_t)e3*64 + lane]);
        acc += gate_(lo_(s0), hi_(s0)) + gate_(lo_(s1), hi_(s1))
             + gate_(lo_(s2), hi_(s2)) + gate_(lo_(s3), hi_(s3));
      }
      for (; i < deg; ++i){
        u32 sA = pkadd_(p0, heFC2[(size_t)edge_n[off+i]*64 + lane]);
        acc += gate_(lo_(sA), hi_(sA));
      }
      float m = acc * ninv[n];
      nmean16[(size_t)n*64 + lane] = (__fp16)m;
      s += m; q += m*m;
    }
  }
  __shared__ float p1[256], p2[256];
  p1[threadIdx.x] = s; p2[threadIdx.x] = q;
  __syncthreads();
  if (wave == 0){
    float a = p1[lane] + p1[64+lane] + p1[128+lane] + p1[192+lane];
    float b = p2[lane] + p2[64+lane] + p2[128+lane] + p2[192+lane];
    atomicAdd(&nstats[lane], a);
    atomicAdd(&nstats[64+lane], b);
  }
}

__global__ void k_bn_fin_node(const float* __restrict__ stats, const float* __restrict__ g,
                              const float* __restrict__ bt, float* __restrict__ ab, float invN){
  int j = threadIdx.x;
  if (j >= 64) return;
  float m = stats[j]*invN;
  float var = stats[64+j]*invN - m*m;
  float a = g[j]*rsqrtf(var + 1e-5f);
  ab[j] = a; ab[64+j] = bt[j] - m*a;
}

// ---------------- node update: h16' = fp16(softplus(BN(mean) + h16)) ----------------
__global__ void k_node_update(const u32* __restrict__ nmean16, const float* __restrict__ ab,
                              const u32* __restrict__ h16, u32* __restrict__ h16out){
  int t = blockIdx.x*256 + threadIdx.x;
  if (t >= N_NODES_*32) return;
  int p = t & 31;
  int f0 = 2*p, f1 = 2*p + 1;
  u32 nm = nmean16[t];
  u32 hh = h16[t];
  float r0 = sp_(ab[f0]*lo_(nm) + ab[64+f0] + lo_(hh));
  float r1 = sp_(ab[f1]*hi_(nm) + ab[64+f1] + hi_(hh));
  h16out[t] = pk_(r0, r1);
}

// ---------------- graph mean + head ----------------
__global__ void k_graph_agg(const u32* __restrict__ h16, const int* __restrict__ batch,
                            float* __restrict__ gsum){
  int t = blockIdx.x*256 + threadIdx.x;
  int n = t >> 5; if (n >= N_NODES_) return;
  int p = t & 31;
  u32 u = h16[t];
  int g = batch[n];
  atomicAdd(&gsum[(size_t)g*64 + 2*p],     lo_(u));
  atomicAdd(&gsum[(size_t)g*64 + 2*p + 1], hi_(u));
}

__global__ void k_head(const float* __restrict__ gsum, const int* __restrict__ gcnt,
                       const float* __restrict__ Wl2, const float* __restrict__ bl2,
                       const float* __restrict__ Wo, const float* __restrict__ bo,
                       float* __restrict__ out){
  __shared__ float gm[64];
  __shared__ float red[128];
  int g = blockIdx.x, j = threadIdx.x;
  if (j < 64) gm[j] = gsum[(size_t)g*64+j] / fmaxf((float)gcnt[g], 1.f);
  __syncthreads();
  float u = bl2[j];
  for (int f = 0; f < 64; ++f) u += gm[f]*Wl2[f*128+j];
  red[j] = sp_(u)*Wo[j];
  __syncthreads();
  for (int s = 64; s > 0; s >>= 1){
    if (j < s) red[j] += red[j+s];
    __syncthreads();
  }
  if (j == 0) out[g] = red[0] + bo[0];
}

extern "C" void kernel_launch(void* const* d_in, const int* in_sizes, int n_in,
                              void* d_out, int out_size, void* d_ws, size_t ws_size,
                              hipStream_t stream){
  (void)in_sizes; (void)n_in; (void)out_size; (void)ws_size;
  const float* x      = (const float*)d_in[0];
  const int*   ni     = (const int*)d_in[1];
  const int*   hi     = ni + E_;
  const float* hattr  = (const float*)d_in[2];
  const int*   batch  = (const int*)d_in[3];
  const float* We     = (const float*)d_in[4];
  const float* be     = (const float*)d_in[5];
  const float* Wf1    = (const float*)d_in[6];
  const float* bf1    = (const float*)d_in[7];
  const float* Wc1    = (const float*)d_in[8];
  const float* bc1    = (const float*)d_in[9];
  const float* Wf2    = (const float*)d_in[10];
  const float* bf2    = (const float*)d_in[11];
  const float* Wc2    = (const float*)d_in[12];
  const float* bc2    = (const float*)d_in[13];
  const float* bn_f_g = (const float*)d_in[14];
  const float* bn_f_b = (const float*)d_in[15];
  const float* bn_c_g = (const float*)d_in[16];
  const float* bn_c_b = (const float*)d_in[17];
  const float* bn_o_g = (const float*)d_in[18];
  const float* bn_o_b = (const float*)d_in[19];
  const float* Wl2    = (const float*)d_in[20];
  const float* bl2    = (const float*)d_in[21];
  const float* Wo     = (const float*)d_in[22];
  const float* bo     = (const float*)d_in[23];

  float* ws = (float*)d_ws;
  size_t o = 0;
  // region A: tfc16T (28MB) / nFC2 (25.6MB) / pairN+pairH (9.6MB) — time-disjoint
  __fp16* tfc16T = (__fp16*)(ws + o); o += (size_t)N_HEDGES_*70/2 + 64;
  u32*   nFC2  = (u32*)tfc16T;
  u32*   pairN = (u32*)tfc16T;
  u32*   pairH = pairN + E_;
  // region B: hmean16 (25.6MB) / heFC2 (51.2MB) — time-disjoint
  float* hmR   = ws + o; o += (size_t)N_HEDGES_*H_;
  u32*   hmean16 = (u32*)hmR;
  u32*   heFC2   = (u32*)hmR;
  __fp16* nmean16 = (__fp16*)(ws + o); o += (size_t)N_NODES_*H_/2 + 64;
  u32*  h16a   = (u32*)(ws + o); o += (size_t)N_NODES_*32;
  u32*  h16b   = (u32*)(ws + o); o += (size_t)N_NODES_*32;
  u32*  hattr16= (u32*)(ws + o); o += (size_t)N_HEDGES_*18;
  float* hstats = ws + o; o += 256;
  float* habs   = ws + o; o += 256;
  float* nstats = ws + o; o += 128;
  float* nabs   = ws + o; o += 128;
  float* gsum   = ws + o; o += (size_t)G_*H_;
  float* hinv   = ws + o; o += N_HEDGES_;
  float* ninv   = ws + o; o += N_NODES_;
  int* hcnt     = (int*)(ws + o); o += N_HEDGES_;
  int* ndeg     = (int*)(ws + o); o += N_NODES_;
  int* gcnt     = (int*)(ws + o); o += G_;
  int* node_off = (int*)(ws + o); o += N_NODES_;
  int* hedge_off= (int*)(ws + o); o += N_HEDGES_;
  int* gcurN    = (int*)(ws + o); o += NBN5_;
  int* gcurH    = (int*)(ws + o); o += NBH5_;
  int* totN     = (int*)(ws + o); o += NBN5_;
  int* totH     = (int*)(ws + o); o += NBH5_;
  int* bbaseN   = (int*)(ws + o); o += NBN5_;
  int* bbaseH   = (int*)(ws + o); o += NBH5_;
  int* edge_n   = (int*)(ws + o); o += E_;
  int* edge_h   = (int*)(ws + o); o += E_;

  hipMemsetAsync(totN, 0, sizeof(int)*(NBN5_ + NBH5_), stream);  // totN,totH contiguous
  hipMemsetAsync(gcnt, 0, sizeof(int)*G_, stream);
  hipMemsetAsync(gsum, 0, sizeof(float)*G_*H_, stream);

  k_gcnt<<<(N_NODES_+255)/256, 256, 0, stream>>>(batch, gcnt);
  k_hattr_pack<<<(N_HEDGES_*18+255)/256, 256, 0, stream>>>(hattr, hattr16);

  // bucketed CSR build (no per-row atomics anywhere)
  k_bhist<<<512, 256, 0, stream>>>(ni, hi, totN, totH);
  k_bscan<<<1, 512, 0, stream>>>(totN, totH, bbaseN, bbaseH, gcurN, gcurH);
  k_binfill<<<(E_+CHUNK_-1)/CHUNK_, 256, 0, stream>>>(ni, hi, gcurN, gcurH, pairN, pairH);
  k_csrfill2<<<NBN5_, 512, 0, stream>>>(bbaseN, gcurN, pairN, N_NODES_, edge_n,
                                        node_off, ndeg, ninv);
  k_csrfill2<<<NBH5_, 512, 0, stream>>>(bbaseH, gcurH, pairH, N_HEDGES_, edge_h,
                                        hedge_off, hcnt, hinv);

  k_embed<<<768, 256, 0, stream>>>(x, We, be, h16a);

  u32* hc16 = h16a;
  u32* hn16 = h16b;
  for (int l = 0; l < L_; ++l){
    const float* Wf1l = Wf1 + (size_t)l*D_*HE_;
    const float* Wc1l = Wc1 + (size_t)l*D_*HE_;
    const float* Wf2l = Wf2 + (size_t)l*D_*H_;
    const float* Wc2l = Wc2 + (size_t)l*D_*H_;

    hipMemsetAsync(hstats, 0, sizeof(float)*160, stream);
    hipMemsetAsync(nstats, 0, sizeof(float)*128, stream);

    k_gather_hedge<<<(N_HEDGES_*8+255)/256, 256, 0, stream>>>(hc16, hedge_off, hcnt, edge_h,
                                                              hinv, hmean16);
    k_hedge_mlp1<<<1280, 256, 0, stream>>>(hmean16, hattr16, Wf1l, bf1 + l*HE_,
                                           Wc1l, bc1 + l*HE_, tfc16T, hstats);
    k_bn_fin_hedge<<<1, 128, 0, stream>>>(hstats, bn_f_g + l*HE_, bn_f_b + l*HE_,
                                          bn_c_g + l*HE_, bn_c_b + l*HE_, habs,
                                          1.f/(float)N_HEDGES_);
    k_hedge_feats<<<1536, 256, 0, stream>>>(tfc16T, habs, Wf2l, bf2 + l*H_,
                                            Wc2l, bc2 + l*H_, heFC2);
    k_node_lin<<<1024, 256, 0, stream>>>(hc16, Wf2l, Wc2l, nFC2);
    k_edge<<<2048, 256, 0, stream>>>(nFC2, heFC2, node_off, ndeg, edge_n, ninv,
                                     nmean16, nstats);
    k_bn_fin_node<<<1, 64, 0, stream>>>(nstats, bn_o_g + l*H_, bn_o_b + l*H_, nabs,
                                        1.f/(float)N_NODES_);
    k_node_update<<<(N_NODES_*32+255)/256, 256, 0, stream>>>((const u32*)nmean16, nabs,
                                                             hc16, hn16);
    u32* t3 = hc16; hc16 = hn16; hn16 = t3;
  }

  k_graph_agg<<<(N_NODES_*32+255)/256, 256, 0, stream>>>(hc16, batch, gsum);
  k_head<<<G_, 128, 0, stream>>>(gsum, gcnt, Wl2, bl2, Wo, bo, (float*)d_out);
}

// Round 14
// 1184.126 us; speedup vs baseline: 1.3757x; 1.0845x over previous
//
#include <hip/hip_runtime.h>
#include <cstddef>

#define N_NODES_  100000
#define N_HEDGES_ 200000
#define E_        1200000
#define G_        512
#define H_        64
#define HE_       35
#define D_        99      // H_+HE_
#define HOUT_     128
#define L_        3
#define NBN5_     196     // ceil(N_NODES/512)
#define NBH5_     391     // ceil(N_HEDGES/512)
#define CHUNK_    4096

typedef unsigned int u32;
typedef _Float16 f2_t __attribute__((ext_vector_type(2)));

__device__ __forceinline__ float sigm_(float x){
  return __builtin_amdgcn_rcpf(1.f + __expf(-x));
}
__device__ __forceinline__ float sp_(float x){
  return fmaxf(x, 0.f) + __logf(1.f + __expf(-fabsf(x)));
}
__device__ __forceinline__ float gate_(float F, float C){ return sigm_(F)*sp_(C); }

__device__ __forceinline__ u32 pk_(float a, float b){
  return __builtin_bit_cast(u32, __builtin_amdgcn_cvt_pkrtz(a, b));
}
__device__ __forceinline__ u32 pkadd_(u32 a, u32 b){
  f2_t s = __builtin_bit_cast(f2_t, a) + __builtin_bit_cast(f2_t, b);
  return __builtin_bit_cast(u32, s);
}
__device__ __forceinline__ float dot2_(u32 a, u32 b, float c){
#if __has_builtin(__builtin_amdgcn_fdot2)
  return __builtin_amdgcn_fdot2(__builtin_bit_cast(f2_t, a),
                                __builtin_bit_cast(f2_t, b), c, false);
#else
  f2_t x = __builtin_bit_cast(f2_t, a), y = __builtin_bit_cast(f2_t, b);
  return c + (float)x[0]*(float)y[0] + (float)x[1]*(float)y[1];
#endif
}
__device__ __forceinline__ float lo_(u32 a){ return (float)__builtin_bit_cast(f2_t, a)[0]; }
__device__ __forceinline__ float hi_(u32 a){ return (float)__builtin_bit_cast(f2_t, a)[1]; }

// ---------------- graph-batch counts + offsets ----------------
__global__ void k_gcnt(const int* __restrict__ batch, int* __restrict__ gcnt){
  int n = blockIdx.x*256 + threadIdx.x;
  if (n < N_NODES_) atomicAdd(&gcnt[batch[n]], 1);
}
__global__ void k_gscan(const int* __restrict__ gcnt, int* __restrict__ goff){
  __shared__ int tmp[512];
  int t = threadIdx.x;
  int v = gcnt[t];
  tmp[t] = v; __syncthreads();
  for (int d = 1; d < 512; d <<= 1){
    int x = (t >= d) ? tmp[t-d] : 0; __syncthreads();
    tmp[t] += x; __syncthreads();
  }
  goff[t] = tmp[t] - v;
  if (t == 511) goff[512] = tmp[511];
}

// ---------------- bucket histogram ----------------
__global__ void k_bhist(const int* __restrict__ ni, const int* __restrict__ hi,
                        int* __restrict__ totN, int* __restrict__ totH){
  __shared__ int hN[NBN5_], hH[NBH5_];
  for (int i = threadIdx.x; i < NBN5_; i += 256) hN[i] = 0;
  for (int i = threadIdx.x; i < NBH5_; i += 256) hH[i] = 0;
  __syncthreads();
  int stride = gridDim.x*256;
  for (int e = blockIdx.x*256 + threadIdx.x; e < E_; e += stride){
    atomicAdd(&hN[ni[e] >> 9], 1);
    atomicAdd(&hH[hi[e] >> 9], 1);
  }
  __syncthreads();
  for (int i = threadIdx.x; i < NBN5_; i += 256) if (hN[i]) atomicAdd(&totN[i], hN[i]);
  for (int i = threadIdx.x; i < NBH5_; i += 256) if (hH[i]) atomicAdd(&totH[i], hH[i]);
}

// ---------------- bucket-base scan ----------------
__global__ void k_bscan(const int* __restrict__ totN, const int* __restrict__ totH,
                        int* __restrict__ bbaseN, int* __restrict__ bbaseH,
                        int* __restrict__ gcurN, int* __restrict__ gcurH){
  __shared__ int tmp[512];
  int t = threadIdx.x;
  int v = (t < NBN5_) ? totN[t] : 0;
  tmp[t] = v; __syncthreads();
  for (int d = 1; d < 512; d <<= 1){
    int x = (t >= d) ? tmp[t-d] : 0; __syncthreads();
    tmp[t] += x; __syncthreads();
  }
  if (t < NBN5_){ int b = tmp[t] - v; bbaseN[t] = b; gcurN[t] = b; }
  __syncthreads();
  int w = (t < NBH5_) ? totH[t] : 0;
  tmp[t] = w; __syncthreads();
  for (int d = 1; d < 512; d <<= 1){
    int x = (t >= d) ? tmp[t-d] : 0; __syncthreads();
    tmp[t] += x; __syncthreads();
  }
  if (t < NBH5_){ int b = tmp[t] - w; bbaseH[t] = b; gcurH[t] = b; }
}

// ---------------- bucketed pair fill ----------------
// pair encoding: (local_row_9b << 18) | id (< 2^18)
__global__ void k_binfill(const int* __restrict__ ni, const int* __restrict__ hi,
                          int* __restrict__ gcurN, int* __restrict__ gcurH,
                          u32* __restrict__ pairN, u32* __restrict__ pairH){
  __shared__ int histN[NBN5_], histH[NBH5_];
  __shared__ int baseN[NBN5_], baseH[NBH5_];
  const int nchunks = (E_ + CHUNK_ - 1)/CHUNK_;
  for (int c = blockIdx.x; c < nchunks; c += gridDim.x){
    int e0 = c*CHUNK_;
    int e1 = e0 + CHUNK_; if (e1 > E_) e1 = E_;
    for (int i = threadIdx.x; i < NBN5_; i += 256) histN[i] = 0;
    for (int i = threadIdx.x; i < NBH5_; i += 256) histH[i] = 0;
    __syncthreads();
    for (int e = e0 + threadIdx.x; e < e1; e += 256){
      atomicAdd(&histN[ni[e] >> 9], 1);
      atomicAdd(&histH[hi[e] >> 9], 1);
    }
    __syncthreads();
    for (int i = threadIdx.x; i < NBN5_; i += 256){
      int hv = histN[i];
      baseN[i] = hv ? atomicAdd(&gcurN[i], hv) : 0;
      histN[i] = 0;
    }
    for (int i = threadIdx.x; i < NBH5_; i += 256){
      int hv = histH[i];
      baseH[i] = hv ? atomicAdd(&gcurH[i], hv) : 0;
      histH[i] = 0;
    }
    __syncthreads();
    for (int e = e0 + threadIdx.x; e < e1; e += 256){
      int n = ni[e], he = hi[e];
      int bn = n >> 9, bh = he >> 9;
      int pn = baseN[bn] + atomicAdd(&histN[bn], 1);
      pairN[pn] = ((u32)(n & 511) << 18) | (u32)he;
      int ph = baseH[bh] + atomicAdd(&histH[bh], 1);
      pairH[ph] = ((u32)(he & 511) << 18) | (u32)n;
    }
    __syncthreads();
  }
}

// ---------------- csrfill2: per-bucket count + scan + place ----------------
__global__ void __launch_bounds__(512) k_csrfill2(
    const int* __restrict__ bbase, const int* __restrict__ gcur,
    const u32* __restrict__ pair, int nrows, int* __restrict__ out,
    int* __restrict__ off_arr, int* __restrict__ cnt_arr, float* __restrict__ inv_arr){
  __shared__ int cnt[512], cur[512], tmp[512];
  int b = blockIdx.x, t = threadIdx.x;
  int nb = b*512;
  cnt[t] = 0;
  __syncthreads();
  int base = bbase[b], end = gcur[b];
  for (int pos = base + t; pos < end; pos += 512)
    atomicAdd(&cnt[pair[pos] >> 18], 1);
  __syncthreads();
  int v = cnt[t];
  tmp[t] = v; __syncthreads();
  for (int d = 1; d < 512; d <<= 1){
    int x = (t >= d) ? tmp[t-d] : 0; __syncthreads();
    tmp[t] += x; __syncthreads();
  }
  int ro = base + tmp[t] - v;
  cur[t] = ro;
  int row = nb + t;
  if (row < nrows){
    off_arr[row] = ro;
    cnt_arr[row] = v;
    inv_arr[row] = 1.f/fmaxf((float)v, 1.f);
  }
  __syncthreads();
  for (int pos = base + t; pos < end; pos += 512){
    u32 p = pair[pos];
    int idx = atomicAdd(&cur[p >> 18], 1);
    out[idx] = (int)(p & 0x3FFFFu);
  }
}

// ---------------- pack hattr to fp16 pairs [NH][18] ----------------
__global__ void k_hattr_pack(const float* __restrict__ hattr, u32* __restrict__ hattr16){
  int i = blockIdx.x*256 + threadIdx.x;
  if (i >= N_HEDGES_*18) return;
  int he = i/18, p = i - he*18;
  int k0 = 2*p, k1 = 2*p + 1;
  float w0 = (k0 < 35) ? hattr[(size_t)he*35 + k0] : 0.f;
  float w1 = (k1 < 35) ? hattr[(size_t)he*35 + k1] : 0.f;
  hattr16[i] = pk_(w0, w1);
}

// ---------------- embed: h16 = fp16( x @ We + be ) ----------------
__global__ void k_embed(const float* __restrict__ x, const float* __restrict__ We,
                        const float* __restrict__ be, u32* __restrict__ h16){
  __shared__ __align__(16) float As[64*100];
  __shared__ __align__(16) float Ws[64*100];
  int tid = threadIdx.x;
  for (int idx = tid; idx < 64*100; idx += 256){
    int c = idx/100, k = idx - c*100;
    Ws[idx] = (k < 92) ? We[k*64 + c] : 0.f;
  }
  int rt = tid & 15, ct = tid >> 4;
  float bias[4];
  #pragma unroll
  for (int j = 0; j < 4; ++j) bias[j] = be[ct*4 + j];
  const int ntiles = (N_NODES_ + 63)/64;
  for (int tile = blockIdx.x; tile < ntiles; tile += gridDim.x){
    int rbase = tile*64;
    __syncthreads();
    for (int idx = tid; idx < 64*100; idx += 256){
      int r = idx/100, k = idx - r*100;
      int rg = rbase + r;
      As[idx] = (rg < N_NODES_ && k < 92) ? x[(size_t)rg*92 + k] : 0.f;
    }
    __syncthreads();
    float acc[4][4] = {};
    for (int kc = 0; kc < 25; ++kc){
      float4 av[4], wv[4];
      #pragma unroll
      for (int i = 0; i < 4; ++i) av[i] = *(const float4*)&As[(rt + 16*i)*100 + kc*4];
      #pragma unroll
      for (int j = 0; j < 4; ++j) wv[j] = *(const float4*)&Ws[(ct*4 + j)*100 + kc*4];
      #pragma unroll
      for (int i = 0; i < 4; ++i)
        #pragma unroll
        for (int j = 0; j < 4; ++j)
          acc[i][j] += av[i].x*wv[j].x + av[i].y*wv[j].y + av[i].z*wv[j].z + av[i].w*wv[j].w;
    }
    #pragma unroll
    for (int i = 0; i < 4; ++i){
      int r = rbase + rt + 16*i;
      if (r < N_NODES_){
        h16[(size_t)r*32 + ct*2]     = pk_(acc[i][0] + bias[0], acc[i][1] + bias[1]);
        h16[(size_t)r*32 + ct*2 + 1] = pk_(acc[i][2] + bias[2], acc[i][3] + bias[3]);
      }
    }
  }
}

// ---------------- hedge gather (fp16, uint4, 8 lanes/hedge) ----------------
__global__ void __launch_bounds__(256) k_gather_hedge(
    const u32* __restrict__ h16, const int* __restrict__ hedge_off,
    const int* __restrict__ hcnt, const int* __restrict__ edge_h,
    const float* __restrict__ hinv, u32* __restrict__ hmean16){
  int w = (blockIdx.x*256 + threadIdx.x) >> 3;
  int p = threadIdx.x & 7;
  if (w >= N_HEDGES_) return;
  int off = hedge_off[w], deg = hcnt[w];
  float a[8] = {};
  int i = 0;
  for (; i + 1 < deg; i += 2){
    int n0 = edge_h[off+i], n1 = edge_h[off+i+1];
    uint4 u0 = *(const uint4*)&h16[(size_t)n0*32 + 4*p];
    uint4 u1 = *(const uint4*)&h16[(size_t)n1*32 + 4*p];
    a[0] += lo_(u0.x) + lo_(u1.x); a[1] += hi_(u0.x) + hi_(u1.x);
    a[2] += lo_(u0.y) + lo_(u1.y); a[3] += hi_(u0.y) + hi_(u1.y);
    a[4] += lo_(u0.z) + lo_(u1.z); a[5] += hi_(u0.z) + hi_(u1.z);
    a[6] += lo_(u0.w) + lo_(u1.w); a[7] += hi_(u0.w) + hi_(u1.w);
  }
  if (i < deg){
    uint4 u = *(const uint4*)&h16[(size_t)edge_h[off+i]*32 + 4*p];
    a[0] += lo_(u.x); a[1] += hi_(u.x); a[2] += lo_(u.y); a[3] += hi_(u.y);
    a[4] += lo_(u.z); a[5] += hi_(u.z); a[6] += lo_(u.w); a[7] += hi_(u.w);
  }
  float inv = hinv[w];
  uint4 st;
  st.x = pk_(a[0]*inv, a[1]*inv); st.y = pk_(a[2]*inv, a[3]*inv);
  st.z = pk_(a[4]*inv, a[5]*inv); st.w = pk_(a[6]*inv, a[7]*inv);
  *(uint4*)&hmean16[(size_t)w*32 + 4*p] = st;
}

// ---------------- hedge MLP pre-BN (dot2): tfc16T[c][r] fp16, reg-accum stats ------
__global__ void k_hedge_mlp1(const u32* __restrict__ hmean16, const u32* __restrict__ hattr16,
                             const float* __restrict__ Wf1, const float* __restrict__ bf1,
                             const float* __restrict__ Wc1, const float* __restrict__ bc1,
                             __fp16* __restrict__ tfc16T, float* __restrict__ hstats){
  __shared__ __align__(16) u32 As16[64*52];
  __shared__ __align__(16) u32 Ws16[80*52];
  __shared__ float sstat[160];
  int tid = threadIdx.x;
  for (int idx = tid; idx < 80*52; idx += 256){
    int c = idx/52, kk = idx - c*52;
    int k0 = 2*kk, k1 = 2*kk + 1;
    float w0 = 0.f, w1 = 0.f;
    if (c < 70){
      if (k0 < 99) w0 = (c < 35) ? Wf1[k0*35 + c] : Wc1[k0*35 + (c-35)];
      if (k1 < 99) w1 = (c < 35) ? Wf1[k1*35 + c] : Wc1[k1*35 + (c-35)];
    }
    Ws16[idx] = pk_(w0, w1);
  }
  for (int idx = tid; idx < 160; idx += 256) sstat[idx] = 0.f;
  int rt = tid & 15, ct = tid >> 4;
  float bias[5];
  #pragma unroll
  for (int j = 0; j < 5; ++j){
    int c = ct*5 + j;
    bias[j] = (c < 35) ? bf1[c] : (c < 70 ? bc1[c - 35] : 0.f);
  }
  float sreg[5] = {}, qreg[5] = {};
  for (int tile = blockIdx.x; tile < N_HEDGES_/64; tile += gridDim.x){
    int rbase = tile*64;
    __syncthreads();
    for (int idx = tid; idx < 64*52; idx += 256){
      int r = idx/52, kk = idx - r*52;
      int rg = rbase + r;
      u32 v = 0;
      if (kk < 32)      v = hmean16[(size_t)rg*32 + kk];
      else if (kk < 50) v = hattr16[(size_t)rg*18 + (kk - 32)];
      As16[idx] = v;
    }
    __syncthreads();
    float acc[4][5] = {};
    for (int kc = 0; kc < 13; ++kc){
      uint4 av[4], wv[5];
      #pragma unroll
      for (int i = 0; i < 4; ++i) av[i] = *(const uint4*)&As16[(rt + 16*i)*52 + kc*4];
      #pragma unroll
      for (int j = 0; j < 5; ++j) wv[j] = *(const uint4*)&Ws16[(ct*5 + j)*52 + kc*4];
      #pragma unroll
      for (int i = 0; i < 4; ++i)
        #pragma unroll
        for (int j = 0; j < 5; ++j){
          float a = acc[i][j];
          a = dot2_(av[i].x, wv[j].x, a);
          a = dot2_(av[i].y, wv[j].y, a);
          a = dot2_(av[i].z, wv[j].z, a);
          a = dot2_(av[i].w, wv[j].w, a);
          acc[i][j] = a;
        }
    }
    #pragma unroll
    for (int j = 0; j < 5; ++j){
      int c = ct*5 + j;
      if (c < 70){
        #pragma unroll
        for (int i = 0; i < 4; ++i){
          float v = acc[i][j] + bias[j];
          tfc16T[(size_t)c*N_HEDGES_ + rbase + rt + 16*i] = (__fp16)v;
          sreg[j] += v; qreg[j] += v*v;
        }
      }
    }
  }
  int lane = tid & 63;
  #pragma unroll
  for (int j = 0; j < 5; ++j){
    float s = sreg[j], q = qreg[j];
    #pragma unroll
    for (int m = 1; m < 16; m <<= 1){
      s += __shfl_xor(s, m);
      q += __shfl_xor(q, m);
    }
    if ((lane & 15) == 0){
      int c = ct*5 + j;
      if (c < 70){
        atomicAdd(&sstat[c], s);
        atomicAdd(&sstat[80 + c], q);
      }
    }
  }
  __syncthreads();
  for (int idx = tid; idx < 160; idx += 256) atomicAdd(&hstats[idx], sstat[idx]);
}

// ---------------- BN finalize (hedge) ----------------
__global__ void k_bn_fin_hedge(const float* __restrict__ stats,
                               const float* __restrict__ gf, const float* __restrict__ btf,
                               const float* __restrict__ gc, const float* __restrict__ btc,
                               float* __restrict__ ab, float invN){
  int j = threadIdx.x;
  if (j >= 70) return;
  float m = stats[j]*invN;
  float var = stats[80+j]*invN - m*m;
  float gg = (j < 35) ? gf[j] : gc[j-35];
  float bb = (j < 35) ? btf[j] : btc[j-35];
  float a = gg*rsqrtf(var + 1e-5f);
  ab[j] = a; ab[70+j] = bb - m*a;
}

// ---------------- hedge feats + project (dot2, fp16 tfc16T reads): heFC2 fp16 ---------
__global__ void k_hedge_feats(const __fp16* __restrict__ tfc16T, const float* __restrict__ ab,
                              const float* __restrict__ Wf2, const float* __restrict__ bf2,
                              const float* __restrict__ Wc2, const float* __restrict__ bc2,
                              u32* __restrict__ heFC2){
  __shared__ __align__(16) u32 As16[64*20];
  __shared__ __align__(16) u32 Ws16[128*20];
  int tid = threadIdx.x;
  for (int idx = tid; idx < 128*20; idx += 256){
    int c = idx/20, kk = idx - c*20;
    int k0 = 2*kk, k1 = 2*kk + 1;
    float w0 = 0.f, w1 = 0.f;
    if (k0 < 35) w0 = (c < 64) ? Wf2[(64+k0)*64 + c] : Wc2[(64+k0)*64 + (c-64)];
    if (k1 < 35) w1 = (c < 64) ? Wf2[(64+k1)*64 + c] : Wc2[(64+k1)*64 + (c-64)];
    Ws16[idx] = pk_(w0, w1);
  }
  int rt = tid & 15, ct = tid >> 4;
  float biasF[4], biasC[4];
  #pragma unroll
  for (int j = 0; j < 4; ++j){ biasF[j] = bf2[ct*4 + j]; biasC[j] = bc2[ct*4 + j]; }
  for (int tile = blockIdx.x; tile < N_HEDGES_/64; tile += gridDim.x){
    int rbase = tile*64;
    __syncthreads();
    for (int idx = tid; idx < 64*20; idx += 256){
      int kk = idx >> 6;        // 0..19
      int r  = idx & 63;
      float a0 = 0.f, a1 = 0.f;
      if (kk < 18){
        int rg = rbase + r;
        int k0 = 2*kk, k1 = 2*kk + 1;
        {
          float tf = (float)tfc16T[(size_t)k0*N_HEDGES_ + rg];
          float tc = (float)tfc16T[(size_t)(35+k0)*N_HEDGES_ + rg];
          float zf = ab[k0]*tf + ab[70 + k0];
          float zc = ab[35+k0]*tc + ab[105 + k0];
          a0 = gate_(zf, zc);
        }
        if (k1 < 35){
          float tf = (float)tfc16T[(size_t)k1*N_HEDGES_ + rg];
          float tc = (float)tfc16T[(size_t)(35+k1)*N_HEDGES_ + rg];
          float zf = ab[k1]*tf + ab[70 + k1];
          float zc = ab[35+k1]*tc + ab[105 + k1];
          a1 = gate_(zf, zc);
        }
      }
      As16[r*20 + kk] = pk_(a0, a1);
    }
    __syncthreads();
    float accF[4][4] = {}, accC[4][4] = {};
    for (int kc = 0; kc < 5; ++kc){
      uint4 av[4], wF[4], wC[4];
      #pragma unroll
      for (int i = 0; i < 4; ++i) av[i] = *(const uint4*)&As16[(rt + 16*i)*20 + kc*4];
      #pragma unroll
      for (int j = 0; j < 4; ++j){
        wF[j] = *(const uint4*)&Ws16[(ct*4 + j)*20 + kc*4];
        wC[j] = *(const uint4*)&Ws16[(64 + ct*4 + j)*20 + kc*4];
      }
      #pragma unroll
      for (int i = 0; i < 4; ++i)
        #pragma unroll
        for (int j = 0; j < 4; ++j){
          float f = accF[i][j], c = accC[i][j];
          f = dot2_(av[i].x, wF[j].x, f); c = dot2_(av[i].x, wC[j].x, c);
          f = dot2_(av[i].y, wF[j].y, f); c = dot2_(av[i].y, wC[j].y, c);
          f = dot2_(av[i].z, wF[j].z, f); c = dot2_(av[i].z, wC[j].z, c);
          f = dot2_(av[i].w, wF[j].w, f); c = dot2_(av[i].w, wC[j].w, c);
          accF[i][j] = f; accC[i][j] = c;
        }
    }
    #pragma unroll
    for (int i = 0; i < 4; ++i){
      int r = rbase + rt + 16*i;
      #pragma unroll
      for (int j = 0; j < 4; ++j){
        heFC2[(size_t)r*64 + ct*4 + j] = pk_(accF[i][j] + biasF[j], accC[i][j] + biasC[j]);
      }
    }
  }
}

// ---------------- node projections (dot2): nFC2 packed fp16 ----------------
__global__ void k_node_lin(const u32* __restrict__ h16,
                           const float* __restrict__ Wf2, const float* __restrict__ Wc2,
                           u32* __restrict__ nFC2){
  __shared__ __align__(16) u32 As16[64*36];
  __shared__ __align__(16) u32 Ws16[128*36];
  int tid = threadIdx.x;
  for (int idx = tid; idx < 128*36; idx += 256){
    int c = idx/36, kk = idx - c*36;
    int k0 = 2*kk, k1 = 2*kk + 1;
    float w0 = 0.f, w1 = 0.f;
    if (k0 < 64) w0 = (c < 64) ? Wf2[k0*64 + c] : Wc2[k0*64 + (c-64)];
    if (k1 < 64) w1 = (c < 64) ? Wf2[k1*64 + c] : Wc2[k1*64 + (c-64)];
    Ws16[idx] = pk_(w0, w1);
  }
  int rt = tid & 15, ct = tid >> 4;
  const int ntiles = (N_NODES_ + 63)/64;
  for (int tile = blockIdx.x; tile < ntiles; tile += gridDim.x){
    int rbase = tile*64;
    __syncthreads();
    for (int idx = tid; idx < 64*36; idx += 256){
      int r = idx/36, kk = idx - r*36;
      int rg = rbase + r;
      As16[idx] = (rg < N_NODES_ && kk < 32) ? h16[(size_t)rg*32 + kk] : 0u;
    }
    __syncthreads();
    float accF[4][4] = {}, accC[4][4] = {};
    for (int kc = 0; kc < 8; ++kc){
      uint4 av[4], wF[4], wC[4];
      #pragma unroll
      for (int i = 0; i < 4; ++i) av[i] = *(const uint4*)&As16[(rt + 16*i)*36 + kc*4];
      #pragma unroll
      for (int j = 0; j < 4; ++j){
        wF[j] = *(const uint4*)&Ws16[(ct*4 + j)*36 + kc*4];
        wC[j] = *(const uint4*)&Ws16[(64 + ct*4 + j)*36 + kc*4];
      }
      #pragma unroll
      for (int i = 0; i < 4; ++i)
        #pragma unroll
        for (int j = 0; j < 4; ++j){
          float f = accF[i][j], c = accC[i][j];
          f = dot2_(av[i].x, wF[j].x, f); c = dot2_(av[i].x, wC[j].x, c);
          f = dot2_(av[i].y, wF[j].y, f); c = dot2_(av[i].y, wC[j].y, c);
          f = dot2_(av[i].z, wF[j].z, f); c = dot2_(av[i].z, wC[j].z, c);
          f = dot2_(av[i].w, wF[j].w, f); c = dot2_(av[i].w, wC[j].w, c);
          accF[i][j] = f; accC[i][j] = c;
        }
    }
    #pragma unroll
    for (int i = 0; i < 4; ++i){
      int r = rbase + rt + 16*i;
      if (r < N_NODES_){
        #pragma unroll
        for (int j = 0; j < 4; ++j){
          nFC2[(size_t)r*64 + ct*4 + j] = pk_(accF[i][j], accC[i][j]);
        }
      }
    }
  }
}

// ---------------- fused edge: node-CSR gather + gated act + mean(fp16) + stats ------
__global__ void k_edge(const u32* __restrict__ nFC2, const u32* __restrict__ heFC2,
                       const int* __restrict__ node_off, const int* __restrict__ ndeg,
                       const int* __restrict__ edge_n, const float* __restrict__ ninv,
                       __fp16* __restrict__ nmean16, float* __restrict__ nstats){
  int lane = threadIdx.x & 63, wave = threadIdx.x >> 6;
  float s = 0.f, q = 0.f;
  for (int base = blockIdx.x*4; base < N_NODES_; base += gridDim.x*4){
    int n = base + wave;
    if (n < N_NODES_){
      int off = __builtin_amdgcn_readfirstlane(node_off[n]);
      int deg = __builtin_amdgcn_readfirstlane(ndeg[n]);
      u32 p0 = nFC2[(size_t)n*64 + lane];
      float acc = 0.f;
      int i = 0;
      for (; i + 7 < deg; i += 8){
        int e0 = edge_n[off+i],   e1 = edge_n[off+i+1], e2 = edge_n[off+i+2], e3 = edge_n[off+i+3];
        int e4 = edge_n[off+i+4], e5 = edge_n[off+i+5], e6 = edge_n[off+i+6], e7 = edge_n[off+i+7];
        u32 s0 = pkadd_(p0, heFC2[(size_t)e0*64 + lane]);
        u32 s1 = pkadd_(p0, heFC2[(size_t)e1*64 + lane]);
        u32 s2 = pkadd_(p0, heFC2[(size_t)e2*64 + lane]);
        u32 s3 = pkadd_(p0, heFC2[(size_t)e3*64 + lane]);
        u32 s4 = pkadd_(p0, heFC2[(size_t)e4*64 + lane]);
        u32 s5 = pkadd_(p0, heFC2[(size_t)e5*64 + lane]);
        u32 s6 = pkadd_(p0, heFC2[(size_t)e6*64 + lane]);
        u32 s7 = pkadd_(p0, heFC2[(size_t)e7*64 + lane]);
        acc += gate_(lo_(s0), hi_(s0)) + gate_(lo_(s1), hi_(s1))
             + gate_(lo_(s2), hi_(s2)) + gate_(lo_(s3), hi_(s3))
             + gate_(lo_(s4), hi_(s4)) + gate_(lo_(s5), hi_(s5))
             + gate_(lo_(s6), hi_(s6)) + gate_(lo_(s7), hi_(s7));
      }
      for (; i + 3 < deg; i += 4){
        int e0 = edge_n[off+i], e1 = edge_n[off+i+1], e2 = edge_n[off+i+2], e3 = edge_n[off+i+3];
        u32 s0 = pkadd_(p0, heFC2[(size_t)e0*64 + lane]);
        u32 s1 = pkadd_(p0, heFC2[(size_t)e1*64 + lane]);
        u32 s2 = pkadd_(p0, heFC2[(size_t)e2*64 + lane]);
        u32 s3 = pkadd_(p0, heFC2[(size_t)e3*64 + lane]);
        acc += gate_(lo_(s0), hi_(s0)) + gate_(lo_(s1), hi_(s1))
             + gate_(lo_(s2), hi_(s2)) + gate_(lo_(s3), hi_(s3));
      }
      for (; i < deg; ++i){
        u32 sA = pkadd_(p0, heFC2[(size_t)edge_n[off+i]*64 + lane]);
        acc += gate_(lo_(sA), hi_(sA));
      }
      float m = acc * ninv[n];
      nmean16[(size_t)n*64 + lane] = (__fp16)m;
      s += m; q += m*m;
    }
  }
  __shared__ float p1[256], p2[256];
  p1[threadIdx.x] = s; p2[threadIdx.x] = q;
  __syncthreads();
  if (wave == 0){
    float a = p1[lane] + p1[64+lane] + p1[128+lane] + p1[192+lane];
    float b = p2[lane] + p2[64+lane] + p2[128+lane] + p2[192+lane];
    atomicAdd(&nstats[lane], a);
    atomicAdd(&nstats[64+lane], b);
  }
}

__global__ void k_bn_fin_node(const float* __restrict__ stats, const float* __restrict__ g,
                              const float* __restrict__ bt, float* __restrict__ ab, float invN){
  int j = threadIdx.x;
  if (j >= 64) return;
  float m = stats[j]*invN;
  float var = stats[64+j]*invN - m*m;
  float a = g[j]*rsqrtf(var + 1e-5f);
  ab[j] = a; ab[64+j] = bt[j] - m*a;
}

// ---------------- node update: h16' = fp16(softplus(BN(mean) + h16)) ----------------
__global__ void k_node_update(const u32* __restrict__ nmean16, const float* __restrict__ ab,
                              const u32* __restrict__ h16, u32* __restrict__ h16out){
  int t = blockIdx.x*256 + threadIdx.x;
  if (t >= N_NODES_*32) return;
  int p = t & 31;
  int f0 = 2*p, f1 = 2*p + 1;
  u32 nm = nmean16[t];
  u32 hh = h16[t];
  float r0 = sp_(ab[f0]*lo_(nm) + ab[64+f0] + lo_(hh));
  float r1 = sp_(ab[f1]*hi_(nm) + ab[64+f1] + hi_(hh));
  h16out[t] = pk_(r0, r1);
}

// ---------------- graph mean (sorted batch; one block per graph, no atomics) ----------
__global__ void __launch_bounds__(256) k_graph_agg2(
    const u32* __restrict__ h16, const int* __restrict__ goff,
    float* __restrict__ gmean){
  __shared__ float s0[256], s1[256];
  int g = blockIdx.x;
  int st = goff[g], en = goff[g+1];
  int p = threadIdx.x & 31;   // word index
  int r = threadIdx.x >> 5;   // row group 0..7
  float a0 = 0.f, a1 = 0.f;
  for (int n = st + r; n < en; n += 8){
    u32 u = h16[(size_t)n*32 + p];
    a0 += lo_(u); a1 += hi_(u);
  }
  s0[threadIdx.x] = a0; s1[threadIdx.x] = a1;
  __syncthreads();
  for (int d = 128; d >= 32; d >>= 1){
    if (threadIdx.x < d){
      s0[threadIdx.x] += s0[threadIdx.x + d];
      s1[threadIdx.x] += s1[threadIdx.x + d];
    }
    __syncthreads();
  }
  if (threadIdx.x < 32){
    float inv = 1.f/fmaxf((float)(en - st), 1.f);
    gmean[(size_t)g*64 + 2*threadIdx.x]     = s0[threadIdx.x]*inv;
    gmean[(size_t)g*64 + 2*threadIdx.x + 1] = s1[threadIdx.x]*inv;
  }
}

__global__ void k_head(const float* __restrict__ gmean,
                       const float* __restrict__ Wl2, const float* __restrict__ bl2,
                       const float* __restrict__ Wo, const float* __restrict__ bo,
                       float* __restrict__ out){
  __shared__ float gm[64];
  __shared__ float red[128];
  int g = blockIdx.x, j = threadIdx.x;
  if (j < 64) gm[j] = gmean[(size_t)g*64+j];
  __syncthreads();
  float u = bl2[j];
  for (int f = 0; f < 64; ++f) u += gm[f]*Wl2[f*128+j];
  red[j] = sp_(u)*Wo[j];
  __syncthreads();
  for (int s = 64; s > 0; s >>= 1){
    if (j < s) red[j] += red[j+s];
    __syncthreads();
  }
  if (j == 0) out[g] = red[0] + bo[0];
}

extern "C" void kernel_launch(void* const* d_in, const int* in_sizes, int n_in,
                              void* d_out, int out_size, void* d_ws, size_t ws_size,
                              hipStream_t stream){
  (void)in_sizes; (void)n_in; (void)out_size; (void)ws_size;
  const float* x      = (const float*)d_in[0];
  const int*   ni     = (const int*)d_in[1];
  const int*   hi     = ni + E_;
  const float* hattr  = (const float*)d_in[2];
  const int*   batch  = (const int*)d_in[3];
  const float* We     = (const float*)d_in[4];
  const float* be     = (const float*)d_in[5];
  const float* Wf1    = (const float*)d_in[6];
  const float* bf1    = (const float*)d_in[7];
  const float* Wc1    = (const float*)d_in[8];
  const float* bc1    = (const float*)d_in[9];
  const float* Wf2    = (const float*)d_in[10];
  const float* bf2    = (const float*)d_in[11];
  const float* Wc2    = (const float*)d_in[12];
  const float* bc2    = (const float*)d_in[13];
  const float* bn_f_g = (const float*)d_in[14];
  const float* bn_f_b = (const float*)d_in[15];
  const float* bn_c_g = (const float*)d_in[16];
  const float* bn_c_b = (const float*)d_in[17];
  const float* bn_o_g = (const float*)d_in[18];
  const float* bn_o_b = (const float*)d_in[19];
  const float* Wl2    = (const float*)d_in[20];
  const float* bl2    = (const float*)d_in[21];
  const float* Wo     = (const float*)d_in[22];
  const float* bo     = (const float*)d_in[23];

  float* ws = (float*)d_ws;
  size_t o = 0;
  // region A: tfc16T (28MB) / nFC2 (25.6MB) / pairN+pairH (9.6MB) — time-disjoint
  __fp16* tfc16T = (__fp16*)(ws + o); o += (size_t)N_HEDGES_*70/2 + 64;
  u32*   nFC2  = (u32*)tfc16T;
  u32*   pairN = (u32*)tfc16T;
  u32*   pairH = pairN + E_;
  // region B: hmean16 (25.6MB) / heFC2 (51.2MB) — time-disjoint
  float* hmR   = ws + o; o += (size_t)N_HEDGES_*H_;
  u32*   hmean16 = (u32*)hmR;
  u32*   heFC2   = (u32*)hmR;
  __fp16* nmean16 = (__fp16*)(ws + o); o += (size_t)N_NODES_*H_/2 + 64;
  u32*  h16a   = (u32*)(ws + o); o += (size_t)N_NODES_*32;
  u32*  h16b   = (u32*)(ws + o); o += (size_t)N_NODES_*32;
  u32*  hattr16= (u32*)(ws + o); o += (size_t)N_HEDGES_*18;
  float* hstats = ws + o; o += 256;
  float* habs   = ws + o; o += 256;
  float* nstats = ws + o; o += 128;
  float* nabs   = ws + o; o += 128;
  float* gmean  = ws + o; o += (size_t)G_*H_;
  float* hinv   = ws + o; o += N_HEDGES_;
  float* ninv   = ws + o; o += N_NODES_;
  int* hcnt     = (int*)(ws + o); o += N_HEDGES_;
  int* ndeg     = (int*)(ws + o); o += N_NODES_;
  int* gcnt     = (int*)(ws + o); o += G_;
  int* goff     = (int*)(ws + o); o += G_ + 1;
  int* node_off = (int*)(ws + o); o += N_NODES_;
  int* hedge_off= (int*)(ws + o); o += N_HEDGES_;
  int* gcurN    = (int*)(ws + o); o += NBN5_;
  int* gcurH    = (int*)(ws + o); o += NBH5_;
  int* totN     = (int*)(ws + o); o += NBN5_;
  int* totH     = (int*)(ws + o); o += NBH5_;
  int* bbaseN   = (int*)(ws + o); o += NBN5_;
  int* bbaseH   = (int*)(ws + o); o += NBH5_;
  int* edge_n   = (int*)(ws + o); o += E_;
  int* edge_h   = (int*)(ws + o); o += E_;

  hipMemsetAsync(totN, 0, sizeof(int)*(NBN5_ + NBH5_), stream);  // totN,totH contiguous
  hipMemsetAsync(gcnt, 0, sizeof(int)*G_, stream);

  k_gcnt<<<(N_NODES_+255)/256, 256, 0, stream>>>(batch, gcnt);
  k_gscan<<<1, 512, 0, stream>>>(gcnt, goff);
  k_hattr_pack<<<(N_HEDGES_*18+255)/256, 256, 0, stream>>>(hattr, hattr16);

  // bucketed CSR build (no per-row atomics anywhere)
  k_bhist<<<512, 256, 0, stream>>>(ni, hi, totN, totH);
  k_bscan<<<1, 512, 0, stream>>>(totN, totH, bbaseN, bbaseH, gcurN, gcurH);
  k_binfill<<<(E_+CHUNK_-1)/CHUNK_, 256, 0, stream>>>(ni, hi, gcurN, gcurH, pairN, pairH);
  k_csrfill2<<<NBN5_, 512, 0, stream>>>(bbaseN, gcurN, pairN, N_NODES_, edge_n,
                                        node_off, ndeg, ninv);
  k_csrfill2<<<NBH5_, 512, 0, stream>>>(bbaseH, gcurH, pairH, N_HEDGES_, edge_h,
                                        hedge_off, hcnt, hinv);

  k_embed<<<768, 256, 0, stream>>>(x, We, be, h16a);

  u32* hc16 = h16a;
  u32* hn16 = h16b;
  for (int l = 0; l < L_; ++l){
    const float* Wf1l = Wf1 + (size_t)l*D_*HE_;
    const float* Wc1l = Wc1 + (size_t)l*D_*HE_;
    const float* Wf2l = Wf2 + (size_t)l*D_*H_;
    const float* Wc2l = Wc2 + (size_t)l*D_*H_;

    hipMemsetAsync(hstats, 0, sizeof(float)*160, stream);
    hipMemsetAsync(nstats, 0, sizeof(float)*128, stream);

    k_gather_hedge<<<(N_HEDGES_*8+255)/256, 256, 0, stream>>>(hc16, hedge_off, hcnt, edge_h,
                                                              hinv, hmean16);
    k_hedge_mlp1<<<1280, 256, 0, stream>>>(hmean16, hattr16, Wf1l, bf1 + l*HE_,
                                           Wc1l, bc1 + l*HE_, tfc16T, hstats);
    k_bn_fin_hedge<<<1, 128, 0, stream>>>(hstats, bn_f_g + l*HE_, bn_f_b + l*HE_,
                                          bn_c_g + l*HE_, bn_c_b + l*HE_, habs,
                                          1.f/(float)N_HEDGES_);
    k_hedge_feats<<<1536, 256, 0, stream>>>(tfc16T, habs, Wf2l, bf2 + l*H_,
                                            Wc2l, bc2 + l*H_, heFC2);
    k_node_lin<<<1024, 256, 0, stream>>>(hc16, Wf2l, Wc2l, nFC2);
    k_edge<<<2048, 256, 0, stream>>>(nFC2, heFC2, node_off, ndeg, edge_n, ninv,
                                     nmean16, nstats);
    k_bn_fin_node<<<1, 64, 0, stream>>>(nstats, bn_o_g + l*H_, bn_o_b + l*H_, nabs,
                                        1.f/(float)N_NODES_);
    k_node_update<<<(N_NODES_*32+255)/256, 256, 0, stream>>>((const u32*)nmean16, nabs,
                                                             hc16, hn16);
    u32* t3 = hc16; hc16 = hn16; hn16 = t3;
  }

  k_graph_agg2<<<G_, 256, 0, stream>>>(hc16, goff, gmean);
  k_head<<<G_, 128, 0, stream>>>(gmean, Wl2, bl2, Wo, bo, (float*)d_out);
}

// Round 15
// 1161.396 us; speedup vs baseline: 1.4026x; 1.0196x over previous
//
#include <hip/hip_runtime.h>
#include <cstddef>

#define N_NODES_  100000
#define N_HEDGES_ 200000
#define E_        1200000
#define G_        512
#define H_        64
#define HE_       35
#define D_        99      // H_+HE_
#define HOUT_     128
#define L_        3
#define NBN5_     196     // ceil(N_NODES/512)
#define NBH5_     391     // ceil(N_HEDGES/512)
#define CHUNK_    4096

typedef unsigned int u32;
typedef _Float16 f2_t __attribute__((ext_vector_type(2)));
typedef _Float16 h8_t __attribute__((ext_vector_type(8)));
typedef float f32x4 __attribute__((ext_vector_type(4)));

__device__ __forceinline__ float sigm_(float x){
  return __builtin_amdgcn_rcpf(1.f + __expf(-x));
}
__device__ __forceinline__ float sp_(float x){
  return fmaxf(x, 0.f) + __logf(1.f + __expf(-fabsf(x)));
}
__device__ __forceinline__ float gate_(float F, float C){ return sigm_(F)*sp_(C); }

__device__ __forceinline__ u32 pk_(float a, float b){
  return __builtin_bit_cast(u32, __builtin_amdgcn_cvt_pkrtz(a, b));
}
__device__ __forceinline__ u32 pkadd_(u32 a, u32 b){
  f2_t s = __builtin_bit_cast(f2_t, a) + __builtin_bit_cast(f2_t, b);
  return __builtin_bit_cast(u32, s);
}
__device__ __forceinline__ float dot2_(u32 a, u32 b, float c){
#if __has_builtin(__builtin_amdgcn_fdot2)
  return __builtin_amdgcn_fdot2(__builtin_bit_cast(f2_t, a),
                                __builtin_bit_cast(f2_t, b), c, false);
#else
  f2_t x = __builtin_bit_cast(f2_t, a), y = __builtin_bit_cast(f2_t, b);
  return c + (float)x[0]*(float)y[0] + (float)x[1]*(float)y[1];
#endif
}
__device__ __forceinline__ float lo_(u32 a){ return (float)__builtin_bit_cast(f2_t, a)[0]; }
__device__ __forceinline__ float hi_(u32 a){ return (float)__builtin_bit_cast(f2_t, a)[1]; }

// ---------------- graph-batch counts + offsets ----------------
__global__ void k_gcnt(const int* __restrict__ batch, int* __restrict__ gcnt){
  int n = blockIdx.x*256 + threadIdx.x;
  if (n < N_NODES_) atomicAdd(&gcnt[batch[n]], 1);
}
__global__ void k_gscan(const int* __restrict__ gcnt, int* __restrict__ goff){
  __shared__ int tmp[512];
  int t = threadIdx.x;
  int v = gcnt[t];
  tmp[t] = v; __syncthreads();
  for (int d = 1; d < 512; d <<= 1){
    int x = (t >= d) ? tmp[t-d] : 0; __syncthreads();
    tmp[t] += x; __syncthreads();
  }
  goff[t] = tmp[t] - v;
  if (t == 511) goff[512] = tmp[511];
}

// ---------------- bucket histogram ----------------
__global__ void k_bhist(const int* __restrict__ ni, const int* __restrict__ hi,
                        int* __restrict__ totN, int* __restrict__ totH){
  __shared__ int hN[NBN5_], hH[NBH5_];
  for (int i = threadIdx.x; i < NBN5_; i += 256) hN[i] = 0;
  for (int i = threadIdx.x; i < NBH5_; i += 256) hH[i] = 0;
  __syncthreads();
  int stride = gridDim.x*256;
  for (int e = blockIdx.x*256 + threadIdx.x; e < E_; e += stride){
    atomicAdd(&hN[ni[e] >> 9], 1);
    atomicAdd(&hH[hi[e] >> 9], 1);
  }
  __syncthreads();
  for (int i = threadIdx.x; i < NBN5_; i += 256) if (hN[i]) atomicAdd(&totN[i], hN[i]);
  for (int i = threadIdx.x; i < NBH5_; i += 256) if (hH[i]) atomicAdd(&totH[i], hH[i]);
}

// ---------------- bucket-base scan ----------------
__global__ void k_bscan(const int* __restrict__ totN, const int* __restrict__ totH,
                        int* __restrict__ bbaseN, int* __restrict__ bbaseH,
                        int* __restrict__ gcurN, int* __restrict__ gcurH){
  __shared__ int tmp[512];
  int t = threadIdx.x;
  int v = (t < NBN5_) ? totN[t] : 0;
  tmp[t] = v; __syncthreads();
  for (int d = 1; d < 512; d <<= 1){
    int x = (t >= d) ? tmp[t-d] : 0; __syncthreads();
    tmp[t] += x; __syncthreads();
  }
  if (t < NBN5_){ int b = tmp[t] - v; bbaseN[t] = b; gcurN[t] = b; }
  __syncthreads();
  int w = (t < NBH5_) ? totH[t] : 0;
  tmp[t] = w; __syncthreads();
  for (int d = 1; d < 512; d <<= 1){
    int x = (t >= d) ? tmp[t-d] : 0; __syncthreads();
    tmp[t] += x; __syncthreads();
  }
  if (t < NBH5_){ int b = tmp[t] - w; bbaseH[t] = b; gcurH[t] = b; }
}

// ---------------- bucketed pair fill ----------------
// pair encoding: (local_row_9b << 18) | id (< 2^18)
__global__ void k_binfill(const int* __restrict__ ni, const int* __restrict__ hi,
                          int* __restrict__ gcurN, int* __restrict__ gcurH,
                          u32* __restrict__ pairN, u32* __restrict__ pairH){
  __shared__ int histN[NBN5_], histH[NBH5_];
  __shared__ int baseN[NBN5_], baseH[NBH5_];
  const int nchunks = (E_ + CHUNK_ - 1)/CHUNK_;
  for (int c = blockIdx.x; c < nchunks; c += gridDim.x){
    int e0 = c*CHUNK_;
    int e1 = e0 + CHUNK_; if (e1 > E_) e1 = E_;
    for (int i = threadIdx.x; i < NBN5_; i += 256) histN[i] = 0;
    for (int i = threadIdx.x; i < NBH5_; i += 256) histH[i] = 0;
    __syncthreads();
    for (int e = e0 + threadIdx.x; e < e1; e += 256){
      atomicAdd(&histN[ni[e] >> 9], 1);
      atomicAdd(&histH[hi[e] >> 9], 1);
    }
    __syncthreads();
    for (int i = threadIdx.x; i < NBN5_; i += 256){
      int hv = histN[i];
      baseN[i] = hv ? atomicAdd(&gcurN[i], hv) : 0;
      histN[i] = 0;
    }
    for (int i = threadIdx.x; i < NBH5_; i += 256){
      int hv = histH[i];
      baseH[i] = hv ? atomicAdd(&gcurH[i], hv) : 0;
      histH[i] = 0;
    }
    __syncthreads();
    for (int e = e0 + threadIdx.x; e < e1; e += 256){
      int n = ni[e], he = hi[e];
      int bn = n >> 9, bh = he >> 9;
      int pn = baseN[bn] + atomicAdd(&histN[bn], 1);
      pairN[pn] = ((u32)(n & 511) << 18) | (u32)he;
      int ph = baseH[bh] + atomicAdd(&histH[bh], 1);
      pairH[ph] = ((u32)(he & 511) << 18) | (u32)n;
    }
    __syncthreads();
  }
}

// ---------------- csrfill2: per-bucket count + scan + place ----------------
__global__ void __launch_bounds__(512) k_csrfill2(
    const int* __restrict__ bbase, const int* __restrict__ gcur,
    const u32* __restrict__ pair, int nrows, int* __restrict__ out,
    int* __restrict__ off_arr, int* __restrict__ cnt_arr, float* __restrict__ inv_arr){
  __shared__ int cnt[512], cur[512], tmp[512];
  int b = blockIdx.x, t = threadIdx.x;
  int nb = b*512;
  cnt[t] = 0;
  __syncthreads();
  int base = bbase[b], end = gcur[b];
  for (int pos = base + t; pos < end; pos += 512)
    atomicAdd(&cnt[pair[pos] >> 18], 1);
  __syncthreads();
  int v = cnt[t];
  tmp[t] = v; __syncthreads();
  for (int d = 1; d < 512; d <<= 1){
    int x = (t >= d) ? tmp[t-d] : 0; __syncthreads();
    tmp[t] += x; __syncthreads();
  }
  int ro = base + tmp[t] - v;
  cur[t] = ro;
  int row = nb + t;
  if (row < nrows){
    off_arr[row] = ro;
    cnt_arr[row] = v;
    inv_arr[row] = 1.f/fmaxf((float)v, 1.f);
  }
  __syncthreads();
  for (int pos = base + t; pos < end; pos += 512){
    u32 p = pair[pos];
    int idx = atomicAdd(&cur[p >> 18], 1);
    out[idx] = (int)(p & 0x3FFFFu);
  }
}

// ---------------- pack hattr to fp16 pairs [NH][18] ----------------
__global__ void k_hattr_pack(const float* __restrict__ hattr, u32* __restrict__ hattr16){
  int i = blockIdx.x*256 + threadIdx.x;
  if (i >= N_HEDGES_*18) return;
  int he = i/18, p = i - he*18;
  int k0 = 2*p, k1 = 2*p + 1;
  float w0 = (k0 < 35) ? hattr[(size_t)he*35 + k0] : 0.f;
  float w1 = (k1 < 35) ? hattr[(size_t)he*35 + k1] : 0.f;
  hattr16[i] = pk_(w0, w1);
}

// ---------------- embed: h16 = fp16( x @ We + be ) ----------------
__global__ void k_embed(const float* __restrict__ x, const float* __restrict__ We,
                        const float* __restrict__ be, u32* __restrict__ h16){
  __shared__ __align__(16) float As[64*100];
  __shared__ __align__(16) float Ws[64*100];
  int tid = threadIdx.x;
  for (int idx = tid; idx < 64*100; idx += 256){
    int c = idx/100, k = idx - c*100;
    Ws[idx] = (k < 92) ? We[k*64 + c] : 0.f;
  }
  int rt = tid & 15, ct = tid >> 4;
  float bias[4];
  #pragma unroll
  for (int j = 0; j < 4; ++j) bias[j] = be[ct*4 + j];
  const int ntiles = (N_NODES_ + 63)/64;
  for (int tile = blockIdx.x; tile < ntiles; tile += gridDim.x){
    int rbase = tile*64;
    __syncthreads();
    for (int idx = tid; idx < 64*100; idx += 256){
      int r = idx/100, k = idx - r*100;
      int rg = rbase + r;
      As[idx] = (rg < N_NODES_ && k < 92) ? x[(size_t)rg*92 + k] : 0.f;
    }
    __syncthreads();
    float acc[4][4] = {};
    for (int kc = 0; kc < 25; ++kc){
      float4 av[4], wv[4];
      #pragma unroll
      for (int i = 0; i < 4; ++i) av[i] = *(const float4*)&As[(rt + 16*i)*100 + kc*4];
      #pragma unroll
      for (int j = 0; j < 4; ++j) wv[j] = *(const float4*)&Ws[(ct*4 + j)*100 + kc*4];
      #pragma unroll
      for (int i = 0; i < 4; ++i)
        #pragma unroll
        for (int j = 0; j < 4; ++j)
          acc[i][j] += av[i].x*wv[j].x + av[i].y*wv[j].y + av[i].z*wv[j].z + av[i].w*wv[j].w;
    }
    #pragma unroll
    for (int i = 0; i < 4; ++i){
      int r = rbase + rt + 16*i;
      if (r < N_NODES_){
        h16[(size_t)r*32 + ct*2]     = pk_(acc[i][0] + bias[0], acc[i][1] + bias[1]);
        h16[(size_t)r*32 + ct*2 + 1] = pk_(acc[i][2] + bias[2], acc[i][3] + bias[3]);
      }
    }
  }
}

// ---------------- hedge gather (fp16, uint4, 8 lanes/hedge) ----------------
__global__ void __launch_bounds__(256) k_gather_hedge(
    const u32* __restrict__ h16, const int* __restrict__ hedge_off,
    const int* __restrict__ hcnt, const int* __restrict__ edge_h,
    const float* __restrict__ hinv, u32* __restrict__ hmean16){
  int w = (blockIdx.x*256 + threadIdx.x) >> 3;
  int p = threadIdx.x & 7;
  if (w >= N_HEDGES_) return;
  int off = hedge_off[w], deg = hcnt[w];
  float a[8] = {};
  int i = 0;
  for (; i + 1 < deg; i += 2){
    int n0 = edge_h[off+i], n1 = edge_h[off+i+1];
    uint4 u0 = *(const uint4*)&h16[(size_t)n0*32 + 4*p];
    uint4 u1 = *(const uint4*)&h16[(size_t)n1*32 + 4*p];
    a[0] += lo_(u0.x) + lo_(u1.x); a[1] += hi_(u0.x) + hi_(u1.x);
    a[2] += lo_(u0.y) + lo_(u1.y); a[3] += hi_(u0.y) + hi_(u1.y);
    a[4] += lo_(u0.z) + lo_(u1.z); a[5] += hi_(u0.z) + hi_(u1.z);
    a[6] += lo_(u0.w) + lo_(u1.w); a[7] += hi_(u0.w) + hi_(u1.w);
  }
  if (i < deg){
    uint4 u = *(const uint4*)&h16[(size_t)edge_h[off+i]*32 + 4*p];
    a[0] += lo_(u.x); a[1] += hi_(u.x); a[2] += lo_(u.y); a[3] += hi_(u.y);
    a[4] += lo_(u.z); a[5] += hi_(u.z); a[6] += lo_(u.w); a[7] += hi_(u.w);
  }
  float inv = hinv[w];
  uint4 st;
  st.x = pk_(a[0]*inv, a[1]*inv); st.y = pk_(a[2]*inv, a[3]*inv);
  st.z = pk_(a[4]*inv, a[5]*inv); st.w = pk_(a[6]*inv, a[7]*inv);
  *(uint4*)&hmean16[(size_t)w*32 + 4*p] = st;
}

// ---------------- hedge MLP pre-BN (MFMA 16x16x32 f16): tfc16T[c][r], reg stats ------
// Tile 64 rows x 80 cols; 4 waves, each 16 rows x 5 col-tiles; K padded to 128.
// A frag: a[j]=A[lane&15][(lane>>4)*8+j]; B frag: b[j]=B[(lane>>4)*8+j][lane&15];
// D: d[q]=D[(lane>>4)*4+q][lane&15].
__global__ void k_hedge_mlp1(const u32* __restrict__ hmean16, const u32* __restrict__ hattr16,
                             const float* __restrict__ Wf1, const float* __restrict__ bf1,
                             const float* __restrict__ Wc1, const float* __restrict__ bc1,
                             __fp16* __restrict__ tfc16T, float* __restrict__ hstats){
  __shared__ __align__(16) u32 As16[64*68];   // [row][68 u32 = 136 fp16 k, 128 used]
  __shared__ __align__(16) u32 Ws16[80*68];   // [col][68 u32]
  __shared__ float sstat[160];
  int tid = threadIdx.x;
  for (int idx = tid; idx < 80*68; idx += 256){
    int c = idx/68, kk = idx - c*68;
    int k0 = 2*kk, k1 = k0 + 1;
    float w0 = 0.f, w1 = 0.f;
    if (c < 70){
      int cc = (c < 35) ? c : c - 35;
      const float* W = (c < 35) ? Wf1 : Wc1;
      if (k0 < 99) w0 = W[k0*35 + cc];
      if (k1 < 99) w1 = W[k1*35 + cc];
    }
    Ws16[idx] = pk_(w0, w1);
  }
  for (int idx = tid; idx < 160; idx += 256) sstat[idx] = 0.f;
  int lane = tid & 63, wv = tid >> 6;
  int l15 = lane & 15, lg = lane >> 4;      // lg 0..3
  float bias[5];
  #pragma unroll
  for (int t = 0; t < 5; ++t){
    int c = t*16 + l15;
    bias[t] = (c < 35) ? bf1[c] : (c < 70 ? bc1[c - 35] : 0.f);
  }
  float sreg[5] = {}, qreg[5] = {};
  for (int tile = blockIdx.x; tile < N_HEDGES_/64; tile += gridDim.x){
    int rbase = tile*64;
    __syncthreads();   // Cs region (aliases As16) free from previous copy-out
    for (int idx = tid; idx < 64*68; idx += 256){
      int r = idx/68, kk = idx - r*68;
      int rg = rbase + r;
      u32 v = 0;
      if (kk < 32)      v = hmean16[(size_t)rg*32 + kk];
      else if (kk < 50) v = hattr16[(size_t)rg*18 + (kk - 32)];
      As16[idx] = v;
    }
    __syncthreads();
    // load this wave's A fragments (16 rows x 128 k)
    h8_t af[4];
    int arow = wv*16 + l15;
    #pragma unroll
    for (int ks = 0; ks < 4; ++ks)
      af[ks] = *(const h8_t*)&As16[arow*68 + ks*16 + lg*4];
    __syncthreads();   // all waves done reading As16 -> reuse as Cs
    __fp16* Cs = (__fp16*)As16;               // [80 cols][72 rows fp16]
    f32x4 acc[5];
    #pragma unroll
    for (int t = 0; t < 5; ++t) acc[t] = (f32x4){0.f,0.f,0.f,0.f};
    #pragma unroll
    for (int t = 0; t < 5; ++t){
      int bcol = t*16 + l15;
      #pragma unroll
      for (int ks = 0; ks < 4; ++ks){
        h8_t bf = *(const h8_t*)&Ws16[bcol*68 + ks*16 + lg*4];
        acc[t] = __builtin_amdgcn_mfma_f32_16x16x32_f16(af[ks], bf, acc[t], 0, 0, 0);
      }
    }
    #pragma unroll
    for (int t = 0; t < 5; ++t){
      int col = t*16 + l15;
      #pragma unroll
      for (int q = 0; q < 4; ++q){
        float v = acc[t][q] + bias[t];
        int row = wv*16 + lg*4 + q;
        Cs[col*72 + row] = (__fp16)v;
        sreg[t] += v; qreg[t] += v*v;
      }
    }
    __syncthreads();
    // coalesced copy-out of cols 0..69
    for (int idx = tid; idx < 70*8; idx += 256){
      int col = idx >> 3, seg = idx & 7;
      uint4 v = *(const uint4*)&Cs[col*72 + seg*8];
      *(uint4*)&tfc16T[(size_t)col*N_HEDGES_ + rbase + seg*8] = v;
    }
  }
  // reduce stats across lg (lane bits 4,5), one LDS atomic per col per wave-group
  #pragma unroll
  for (int t = 0; t < 5; ++t){
    float s = sreg[t], q = qreg[t];
    s += __shfl_xor(s, 16); q += __shfl_xor(q, 16);
    s += __shfl_xor(s, 32); q += __shfl_xor(q, 32);
    if (lg == 0){
      int c = t*16 + l15;
      if (c < 70){
        atomicAdd(&sstat[c], s);
        atomicAdd(&sstat[80 + c], q);
      }
    }
  }
  __syncthreads();
  for (int idx = tid; idx < 160; idx += 256) atomicAdd(&hstats[idx], sstat[idx]);
}

// ---------------- BN finalize (hedge) ----------------
__global__ void k_bn_fin_hedge(const float* __restrict__ stats,
                               const float* __restrict__ gf, const float* __restrict__ btf,
                               const float* __restrict__ gc, const float* __restrict__ btc,
                               float* __restrict__ ab, float invN){
  int j = threadIdx.x;
  if (j >= 70) return;
  float m = stats[j]*invN;
  float var = stats[80+j]*invN - m*m;
  float gg = (j < 35) ? gf[j] : gc[j-35];
  float bb = (j < 35) ? btf[j] : btc[j-35];
  float a = gg*rsqrtf(var + 1e-5f);
  ab[j] = a; ab[70+j] = bb - m*a;
}

// ---------------- hedge feats + project (dot2, fp16 tfc16T reads): heFC2 fp16 ---------
__global__ void k_hedge_feats(const __fp16* __restrict__ tfc16T, const float* __restrict__ ab,
                              const float* __restrict__ Wf2, const float* __restrict__ bf2,
                              const float* __restrict__ Wc2, const float* __restrict__ bc2,
                              u32* __restrict__ heFC2){
  __shared__ __align__(16) u32 As16[64*20];
  __shared__ __align__(16) u32 Ws16[128*20];
  int tid = threadIdx.x;
  for (int idx = tid; idx < 128*20; idx += 256){
    int c = idx/20, kk = idx - c*20;
    int k0 = 2*kk, k1 = 2*kk + 1;
    float w0 = 0.f, w1 = 0.f;
    if (k0 < 35) w0 = (c < 64) ? Wf2[(64+k0)*64 + c] : Wc2[(64+k0)*64 + (c-64)];
    if (k1 < 35) w1 = (c < 64) ? Wf2[(64+k1)*64 + c] : Wc2[(64+k1)*64 + (c-64)];
    Ws16[idx] = pk_(w0, w1);
  }
  int rt = tid & 15, ct = tid >> 4;
  float biasF[4], biasC[4];
  #pragma unroll
  for (int j = 0; j < 4; ++j){ biasF[j] = bf2[ct*4 + j]; biasC[j] = bc2[ct*4 + j]; }
  for (int tile = blockIdx.x; tile < N_HEDGES_/64; tile += gridDim.x){
    int rbase = tile*64;
    __syncthreads();
    for (int idx = tid; idx < 64*20; idx += 256){
      int kk = idx >> 6;        // 0..19
      int r  = idx & 63;
      float a0 = 0.f, a1 = 0.f;
      if (kk < 18){
        int rg = rbase + r;
        int k0 = 2*kk, k1 = 2*kk + 1;
        {
          float tf = (float)tfc16T[(size_t)k0*N_HEDGES_ + rg];
          float tc = (float)tfc16T[(size_t)(35+k0)*N_HEDGES_ + rg];
          float zf = ab[k0]*tf + ab[70 + k0];
          float zc = ab[35+k0]*tc + ab[105 + k0];
          a0 = gate_(zf, zc);
        }
        if (k1 < 35){
          float tf = (float)tfc16T[(size_t)k1*N_HEDGES_ + rg];
          float tc = (float)tfc16T[(size_t)(35+k1)*N_HEDGES_ + rg];
          float zf = ab[k1]*tf + ab[70 + k1];
          float zc = ab[35+k1]*tc + ab[105 + k1];
          a1 = gate_(zf, zc);
        }
      }
      As16[r*20 + kk] = pk_(a0, a1);
    }
    __syncthreads();
    float accF[4][4] = {}, accC[4][4] = {};
    for (int kc = 0; kc < 5; ++kc){
      uint4 av[4], wF[4], wC[4];
      #pragma unroll
      for (int i = 0; i < 4; ++i) av[i] = *(const uint4*)&As16[(rt + 16*i)*20 + kc*4];
      #pragma unroll
      for (int j = 0; j < 4; ++j){
        wF[j] = *(const uint4*)&Ws16[(ct*4 + j)*20 + kc*4];
        wC[j] = *(const uint4*)&Ws16[(64 + ct*4 + j)*20 + kc*4];
      }
      #pragma unroll
      for (int i = 0; i < 4; ++i)
        #pragma unroll
        for (int j = 0; j < 4; ++j){
          float f = accF[i][j], c = accC[i][j];
          f = dot2_(av[i].x, wF[j].x, f); c = dot2_(av[i].x, wC[j].x, c);
          f = dot2_(av[i].y, wF[j].y, f); c = dot2_(av[i].y, wC[j].y, c);
          f = dot2_(av[i].z, wF[j].z, f); c = dot2_(av[i].z, wC[j].z, c);
          f = dot2_(av[i].w, wF[j].w, f); c = dot2_(av[i].w, wC[j].w, c);
          accF[i][j] = f; accC[i][j] = c;
        }
    }
    #pragma unroll
    for (int i = 0; i < 4; ++i){
      int r = rbase + rt + 16*i;
      #pragma unroll
      for (int j = 0; j < 4; ++j){
        heFC2[(size_t)r*64 + ct*4 + j] = pk_(accF[i][j] + biasF[j], accC[i][j] + biasC[j]);
      }
    }
  }
}

// ---------------- node projections (dot2): nFC2 packed fp16 ----------------
__global__ void k_node_lin(const u32* __restrict__ h16,
                           const float* __restrict__ Wf2, const float* __restrict__ Wc2,
                           u32* __restrict__ nFC2){
  __shared__ __align__(16) u32 As16[64*36];
  __shared__ __align__(16) u32 Ws16[128*36];
  int tid = threadIdx.x;
  for (int idx = tid; idx < 128*36; idx += 256){
    int c = idx/36, kk = idx - c*36;
    int k0 = 2*kk, k1 = 2*kk + 1;
    float w0 = 0.f, w1 = 0.f;
    if (k0 < 64) w0 = (c < 64) ? Wf2[k0*64 + c] : Wc2[k0*64 + (c-64)];
    if (k1 < 64) w1 = (c < 64) ? Wf2[k1*64 + c] : Wc2[k1*64 + (c-64)];
    Ws16[idx] = pk_(w0, w1);
  }
  int rt = tid & 15, ct = tid >> 4;
  const int ntiles = (N_NODES_ + 63)/64;
  for (int tile = blockIdx.x; tile < ntiles; tile += gridDim.x){
    int rbase = tile*64;
    __syncthreads();
    for (int idx = tid; idx < 64*36; idx += 256){
      int r = idx/36, kk = idx - r*36;
      int rg = rbase + r;
      As16[idx] = (rg < N_NODES_ && kk < 32) ? h16[(size_t)rg*32 + kk] : 0u;
    }
    __syncthreads();
    float accF[4][4] = {}, accC[4][4] = {};
    for (int kc = 0; kc < 8; ++kc){
      uint4 av[4], wF[4], wC[4];
      #pragma unroll
      for (int i = 0; i < 4; ++i) av[i] = *(const uint4*)&As16[(rt + 16*i)*36 + kc*4];
      #pragma unroll
      for (int j = 0; j < 4; ++j){
        wF[j] = *(const uint4*)&Ws16[(ct*4 + j)*36 + kc*4];
        wC[j] = *(const uint4*)&Ws16[(64 + ct*4 + j)*36 + kc*4];
      }
      #pragma unroll
      for (int i = 0; i < 4; ++i)
        #pragma unroll
        for (int j = 0; j < 4; ++j){
          float f = accF[i][j], c = accC[i][j];
          f = dot2_(av[i].x, wF[j].x, f); c = dot2_(av[i].x, wC[j].x, c);
          f = dot2_(av[i].y, wF[j].y, f); c = dot2_(av[i].y, wC[j].y, c);
          f = dot2_(av[i].z, wF[j].z, f); c = dot2_(av[i].z, wC[j].z, c);
          f = dot2_(av[i].w, wF[j].w, f); c = dot2_(av[i].w, wC[j].w, c);
          accF[i][j] = f; accC[i][j] = c;
        }
    }
    #pragma unroll
    for (int i = 0; i < 4; ++i){
      int r = rbase + rt + 16*i;
      if (r < N_NODES_){
        #pragma unroll
        for (int j = 0; j < 4; ++j){
          nFC2[(size_t)r*64 + ct*4 + j] = pk_(accF[i][j], accC[i][j]);
        }
      }
    }
  }
}

// ---------------- fused edge: node-CSR gather + gated act + mean(fp16) + stats ------
__global__ void k_edge(const u32* __restrict__ nFC2, const u32* __restrict__ heFC2,
                       const int* __restrict__ node_off, const int* __restrict__ ndeg,
                       const int* __restrict__ edge_n, const float* __restrict__ ninv,
                       __fp16* __restrict__ nmean16, float* __restrict__ nstats){
  int lane = threadIdx.x & 63, wave = threadIdx.x >> 6;
  float s = 0.f, q = 0.f;
  for (int base = blockIdx.x*4; base < N_NODES_; base += gridDim.x*4){
    int n = base + wave;
    if (n < N_NODES_){
      int off = __builtin_amdgcn_readfirstlane(node_off[n]);
      int deg = __builtin_amdgcn_readfirstlane(ndeg[n]);
      u32 p0 = nFC2[(size_t)n*64 + lane];
      float acc = 0.f;
      int i = 0;
      for (; i + 7 < deg; i += 8){
        int e0 = edge_n[off+i],   e1 = edge_n[off+i+1], e2 = edge_n[off+i+2], e3 = edge_n[off+i+3];
        int e4 = edge_n[off+i+4], e5 = edge_n[off+i+5], e6 = edge_n[off+i+6], e7 = edge_n[off+i+7];
        u32 s0 = pkadd_(p0, heFC2[(size_t)e0*64 + lane]);
        u32 s1 = pkadd_(p0, heFC2[(size_t)e1*64 + lane]);
        u32 s2 = pkadd_(p0, heFC2[(size_t)e2*64 + lane]);
        u32 s3 = pkadd_(p0, heFC2[(size_t)e3*64 + lane]);
        u32 s4 = pkadd_(p0, heFC2[(size_t)e4*64 + lane]);
        u32 s5 = pkadd_(p0, heFC2[(size_t)e5*64 + lane]);
        u32 s6 = pkadd_(p0, heFC2[(size_t)e6*64 + lane]);
        u32 s7 = pkadd_(p0, heFC2[(size_t)e7*64 + lane]);
        acc += gate_(lo_(s0), hi_(s0)) + gate_(lo_(s1), hi_(s1))
             + gate_(lo_(s2), hi_(s2)) + gate_(lo_(s3), hi_(s3))
             + gate_(lo_(s4), hi_(s4)) + gate_(lo_(s5), hi_(s5))
             + gate_(lo_(s6), hi_(s6)) + gate_(lo_(s7), hi_(s7));
      }
      for (; i + 3 < deg; i += 4){
        int e0 = edge_n[off+i], e1 = edge_n[off+i+1], e2 = edge_n[off+i+2], e3 = edge_n[off+i+3];
        u32 s0 = pkadd_(p0, heFC2[(size_t)e0*64 + lane]);
        u32 s1 = pkadd_(p0, heFC2[(size_t)e1*64 + lane]);
        u32 s2 = pkadd_(p0, heFC2[(size_t)e2*64 + lane]);
        u32 s3 = pkadd_(p0, heFC2[(size_t)e3*64 + lane]);
        acc += gate_(lo_(s0), hi_(s0)) + gate_(lo_(s1), hi_(s1))
             + gate_(lo_(s2), hi_(s2)) + gate_(lo_(s3), hi_(s3));
      }
      for (; i < deg; ++i){
        u32 sA = pkadd_(p0, heFC2[(size_t)edge_n[off+i]*64 + lane]);
        acc += gate_(lo_(sA), hi_(sA));
      }
      float m = acc * ninv[n];
      nmean16[(size_t)n*64 + lane] = (__fp16)m;
      s += m; q += m*m;
    }
  }
  __shared__ float p1[256], p2[256];
  p1[threadIdx.x] = s; p2[threadIdx.x] = q;
  __syncthreads();
  if (wave == 0){
    float a = p1[lane] + p1[64+lane] + p1[128+lane] + p1[192+lane];
    float b = p2[lane] + p2[64+lane] + p2[128+lane] + p2[192+lane];
    atomicAdd(&nstats[lane], a);
    atomicAdd(&nstats[64+lane], b);
  }
}

__global__ void k_bn_fin_node(const float* __restrict__ stats, const float* __restrict__ g,
                              const float* __restrict__ bt, float* __restrict__ ab, float invN){
  int j = threadIdx.x;
  if (j >= 64) return;
  float m = stats[j]*invN;
  float var = stats[64+j]*invN - m*m;
  float a = g[j]*rsqrtf(var + 1e-5f);
  ab[j] = a; ab[64+j] = bt[j] - m*a;
}

// ---------------- node update: h16' = fp16(softplus(BN(mean) + h16)) ----------------
__global__ void k_node_update(const u32* __restrict__ nmean16, const float* __restrict__ ab,
                              const u32* __restrict__ h16, u32* __restrict__ h16out){
  int t = blockIdx.x*256 + threadIdx.x;
  if (t >= N_NODES_*32) return;
  int p = t & 31;
  int f0 = 2*p, f1 = 2*p + 1;
  u32 nm = nmean16[t];
  u32 hh = h16[t];
  float r0 = sp_(ab[f0]*lo_(nm) + ab[64+f0] + lo_(hh));
  float r1 = sp_(ab[f1]*hi_(nm) + ab[64+f1] + hi_(hh));
  h16out[t] = pk_(r0, r1);
}

// ---------------- graph mean (sorted batch; one block per graph, no atomics) ----------
__global__ void __launch_bounds__(256) k_graph_agg2(
    const u32* __restrict__ h16, const int* __restrict__ goff,
    float* __restrict__ gmean){
  __shared__ float s0[256], s1[256];
  int g = blockIdx.x;
  int st = goff[g], en = goff[g+1];
  int p = threadIdx.x & 31;   // word index
  int r = threadIdx.x >> 5;   // row group 0..7
  float a0 = 0.f, a1 = 0.f;
  for (int n = st + r; n < en; n += 8){
    u32 u = h16[(size_t)n*32 + p];
    a0 += lo_(u); a1 += hi_(u);
  }
  s0[threadIdx.x] = a0; s1[threadIdx.x] = a1;
  __syncthreads();
  for (int d = 128; d >= 32; d >>= 1){
    if (threadIdx.x < d){
      s0[threadIdx.x] += s0[threadIdx.x + d];
      s1[threadIdx.x] += s1[threadIdx.x + d];
    }
    __syncthreads();
  }
  if (threadIdx.x < 32){
    float inv = 1.f/fmaxf((float)(en - st), 1.f);
    gmean[(size_t)g*64 + 2*threadIdx.x]     = s0[threadIdx.x]*inv;
    gmean[(size_t)g*64 + 2*threadIdx.x + 1] = s1[threadIdx.x]*inv;
  }
}

__global__ void k_head(const float* __restrict__ gmean,
                       const float* __restrict__ Wl2, const float* __restrict__ bl2,
                       const float* __restrict__ Wo, const float* __restrict__ bo,
                       float* __restrict__ out){
  __shared__ float gm[64];
  __shared__ float red[128];
  int g = blockIdx.x, j = threadIdx.x;
  if (j < 64) gm[j] = gmean[(size_t)g*64+j];
  __syncthreads();
  float u = bl2[j];
  for (int f = 0; f < 64; ++f) u += gm[f]*Wl2[f*128+j];
  red[j] = sp_(u)*Wo[j];
  __syncthreads();
  for (int s = 64; s > 0; s >>= 1){
    if (j < s) red[j] += red[j+s];
    __syncthreads();
  }
  if (j == 0) out[g] = red[0] + bo[0];
}

extern "C" void kernel_launch(void* const* d_in, const int* in_sizes, int n_in,
                              void* d_out, int out_size, void* d_ws, size_t ws_size,
                              hipStream_t stream){
  (void)in_sizes; (void)n_in; (void)out_size; (void)ws_size;
  const float* x      = (const float*)d_in[0];
  const int*   ni     = (const int*)d_in[1];
  const int*   hi     = ni + E_;
  const float* hattr  = (const float*)d_in[2];
  const int*   batch  = (const int*)d_in[3];
  const float* We     = (const float*)d_in[4];
  const float* be     = (const float*)d_in[5];
  const float* Wf1    = (const float*)d_in[6];
  const float* bf1    = (const float*)d_in[7];
  const float* Wc1    = (const float*)d_in[8];
  const float* bc1    = (const float*)d_in[9];
  const float* Wf2    = (const float*)d_in[10];
  const float* bf2    = (const float*)d_in[11];
  const float* Wc2    = (const float*)d_in[12];
  const float* bc2    = (const float*)d_in[13];
  const float* bn_f_g = (const float*)d_in[14];
  const float* bn_f_b = (const float*)d_in[15];
  const float* bn_c_g = (const float*)d_in[16];
  const float* bn_c_b = (const float*)d_in[17];
  const float* bn_o_g = (const float*)d_in[18];
  const float* bn_o_b = (const float*)d_in[19];
  const float* Wl2    = (const float*)d_in[20];
  const float* bl2    = (const float*)d_in[21];
  const float* Wo     = (const float*)d_in[22];
  const float* bo     = (const float*)d_in[23];

  float* ws = (float*)d_ws;
  size_t o = 0;
  // region A: tfc16T (28MB) / nFC2 (25.6MB) / pairN+pairH (9.6MB) — time-disjoint
  __fp16* tfc16T = (__fp16*)(ws + o); o += (size_t)N_HEDGES_*70/2 + 64;
  u32*   nFC2  = (u32*)tfc16T;
  u32*   pairN = (u32*)tfc16T;
  u32*   pairH = pairN + E_;
  // region B: hmean16 (25.6MB) / heFC2 (51.2MB) — time-disjoint
  float* hmR   = ws + o; o += (size_t)N_HEDGES_*H_;
  u32*   hmean16 = (u32*)hmR;
  u32*   heFC2   = (u32*)hmR;
  __fp16* nmean16 = (__fp16*)(ws + o); o += (size_t)N_NODES_*H_/2 + 64;
  u32*  h16a   = (u32*)(ws + o); o += (size_t)N_NODES_*32;
  u32*  h16b   = (u32*)(ws + o); o += (size_t)N_NODES_*32;
  u32*  hattr16= (u32*)(ws + o); o += (size_t)N_HEDGES_*18;
  float* hstats = ws + o; o += 256;
  float* habs   = ws + o; o += 256;
  float* nstats = ws + o; o += 128;
  float* nabs   = ws + o; o += 128;
  float* gmean  = ws + o; o += (size_t)G_*H_;
  float* hinv   = ws + o; o += N_HEDGES_;
  float* ninv   = ws + o; o += N_NODES_;
  int* hcnt     = (int*)(ws + o); o += N_HEDGES_;
  int* ndeg     = (int*)(ws + o); o += N_NODES_;
  int* gcnt     = (int*)(ws + o); o += G_;
  int* goff     = (int*)(ws + o); o += G_ + 1;
  int* node_off = (int*)(ws + o); o += N_NODES_;
  int* hedge_off= (int*)(ws + o); o += N_HEDGES_;
  int* gcurN    = (int*)(ws + o); o += NBN5_;
  int* gcurH    = (int*)(ws + o); o += NBH5_;
  int* totN     = (int*)(ws + o); o += NBN5_;
  int* totH     = (int*)(ws + o); o += NBH5_;
  int* bbaseN   = (int*)(ws + o); o += NBN5_;
  int* bbaseH   = (int*)(ws + o); o += NBH5_;
  int* edge_n   = (int*)(ws + o); o += E_;
  int* edge_h   = (int*)(ws + o); o += E_;

  hipMemsetAsync(totN, 0, sizeof(int)*(NBN5_ + NBH5_), stream);  // totN,totH contiguous
  hipMemsetAsync(gcnt, 0, sizeof(int)*G_, stream);

  k_gcnt<<<(N_NODES_+255)/256, 256, 0, stream>>>(batch, gcnt);
  k_gscan<<<1, 512, 0, stream>>>(gcnt, goff);
  k_hattr_pack<<<(N_HEDGES_*18+255)/256, 256, 0, stream>>>(hattr, hattr16);

  // bucketed CSR build (no per-row atomics anywhere)
  k_bhist<<<512, 256, 0, stream>>>(ni, hi, totN, totH);
  k_bscan<<<1, 512, 0, stream>>>(totN, totH, bbaseN, bbaseH, gcurN, gcurH);
  k_binfill<<<(E_+CHUNK_-1)/CHUNK_, 256, 0, stream>>>(ni, hi, gcurN, gcurH, pairN, pairH);
  k_csrfill2<<<NBN5_, 512, 0, stream>>>(bbaseN, gcurN, pairN, N_NODES_, edge_n,
                                        node_off, ndeg, ninv);
  k_csrfill2<<<NBH5_, 512, 0, stream>>>(bbaseH, gcurH, pairH, N_HEDGES_, edge_h,
                                        hedge_off, hcnt, hinv);

  k_embed<<<768, 256, 0, stream>>>(x, We, be, h16a);

  u32* hc16 = h16a;
  u32* hn16 = h16b;
  for (int l = 0; l < L_; ++l){
    const float* Wf1l = Wf1 + (size_t)l*D_*HE_;
    const float* Wc1l = Wc1 + (size_t)l*D_*HE_;
    const float* Wf2l = Wf2 + (size_t)l*D_*H_;
    const float* Wc2l = Wc2 + (size_t)l*D_*H_;

    hipMemsetAsync(hstats, 0, sizeof(float)*160, stream);
    hipMemsetAsync(nstats, 0, sizeof(float)*128, stream);

    k_gather_hedge<<<(N_HEDGES_*8+255)/256, 256, 0, stream>>>(hc16, hedge_off, hcnt, edge_h,
                                                              hinv, hmean16);
    k_hedge_mlp1<<<1280, 256, 0, stream>>>(hmean16, hattr16, Wf1l, bf1 + l*HE_,
                                           Wc1l, bc1 + l*HE_, tfc16T, hstats);
    k_bn_fin_hedge<<<1, 128, 0, stream>>>(hstats, bn_f_g + l*HE_, bn_f_b + l*HE_,
                                          bn_c_g + l*HE_, bn_c_b + l*HE_, habs,
                                          1.f/(float)N_HEDGES_);
    k_hedge_feats<<<1536, 256, 0, stream>>>(tfc16T, habs, Wf2l, bf2 + l*H_,
                                            Wc2l, bc2 + l*H_, heFC2);
    k_node_lin<<<1024, 256, 0, stream>>>(hc16, Wf2l, Wc2l, nFC2);
    k_edge<<<2048, 256, 0, stream>>>(nFC2, heFC2, node_off, ndeg, edge_n, ninv,
                                     nmean16, nstats);
    k_bn_fin_node<<<1, 64, 0, stream>>>(nstats, bn_o_g + l*H_, bn_o_b + l*H_, nabs,
                                        1.f/(float)N_NODES_);
    k_node_update<<<(N_NODES_*32+255)/256, 256, 0, stream>>>((const u32*)nmean16, nabs,
                                                             hc16, hn16);
    u32* t3 = hc16; hc16 = hn16; hn16 = t3;
  }

  k_graph_agg2<<<G_, 256, 0, stream>>>(hc16, goff, gmean);
  k_head<<<G_, 128, 0, stream>>>(gmean, Wl2, bl2, Wo, bo, (float*)d_out);
}

// Round 16
// 1017.476 us; speedup vs baseline: 1.6010x; 1.1414x over previous
//
#include <hip/hip_runtime.h>
#include <cstddef>

#define N_NODES_  100000
#define N_HEDGES_ 200000
#define E_        1200000
#define G_        512
#define H_        64
#define HE_       35
#define D_        99      // H_+HE_
#define HOUT_     128
#define L_        3
#define NBN5_     196     // ceil(N_NODES/512)
#define NBH5_     391     // ceil(N_HEDGES/512)
#define CHUNK_    4096

typedef unsigned int u32;
typedef _Float16 f2_t __attribute__((ext_vector_type(2)));
typedef _Float16 h8_t __attribute__((ext_vector_type(8)));
typedef float f32x4 __attribute__((ext_vector_type(4)));

__device__ __forceinline__ float sigm_(float x){
  return __builtin_amdgcn_rcpf(1.f + __expf(-x));
}
__device__ __forceinline__ float sp_(float x){
  return fmaxf(x, 0.f) + __logf(1.f + __expf(-fabsf(x)));
}
__device__ __forceinline__ float gate_(float F, float C){ return sigm_(F)*sp_(C); }

__device__ __forceinline__ u32 pk_(float a, float b){
  return __builtin_bit_cast(u32, __builtin_amdgcn_cvt_pkrtz(a, b));
}
__device__ __forceinline__ u32 pkadd_(u32 a, u32 b){
  f2_t s = __builtin_bit_cast(f2_t, a) + __builtin_bit_cast(f2_t, b);
  return __builtin_bit_cast(u32, s);
}
__device__ __forceinline__ float dot2_(u32 a, u32 b, float c){
#if __has_builtin(__builtin_amdgcn_fdot2)
  return __builtin_amdgcn_fdot2(__builtin_bit_cast(f2_t, a),
                                __builtin_bit_cast(f2_t, b), c, false);
#else
  f2_t x = __builtin_bit_cast(f2_t, a), y = __builtin_bit_cast(f2_t, b);
  return c + (float)x[0]*(float)y[0] + (float)x[1]*(float)y[1];
#endif
}
__device__ __forceinline__ float lo_(u32 a){ return (float)__builtin_bit_cast(f2_t, a)[0]; }
__device__ __forceinline__ float hi_(u32 a){ return (float)__builtin_bit_cast(f2_t, a)[1]; }

// ---------------- graph-batch counts + offsets ----------------
__global__ void k_gcnt(const int* __restrict__ batch, int* __restrict__ gcnt){
  int n = blockIdx.x*256 + threadIdx.x;
  if (n < N_NODES_) atomicAdd(&gcnt[batch[n]], 1);
}
__global__ void k_gscan(const int* __restrict__ gcnt, int* __restrict__ goff){
  __shared__ int tmp[512];
  int t = threadIdx.x;
  int v = gcnt[t];
  tmp[t] = v; __syncthreads();
  for (int d = 1; d < 512; d <<= 1){
    int x = (t >= d) ? tmp[t-d] : 0; __syncthreads();
    tmp[t] += x; __syncthreads();
  }
  goff[t] = tmp[t] - v;
  if (t == 511) goff[512] = tmp[511];
}

// ---------------- bucket histogram ----------------
__global__ void k_bhist(const int* __restrict__ ni, const int* __restrict__ hi,
                        int* __restrict__ totN, int* __restrict__ totH){
  __shared__ int hN[NBN5_], hH[NBH5_];
  for (int i = threadIdx.x; i < NBN5_; i += 256) hN[i] = 0;
  for (int i = threadIdx.x; i < NBH5_; i += 256) hH[i] = 0;
  __syncthreads();
  int stride = gridDim.x*256;
  for (int e = blockIdx.x*256 + threadIdx.x; e < E_; e += stride){
    atomicAdd(&hN[ni[e] >> 9], 1);
    atomicAdd(&hH[hi[e] >> 9], 1);
  }
  __syncthreads();
  for (int i = threadIdx.x; i < NBN5_; i += 256) if (hN[i]) atomicAdd(&totN[i], hN[i]);
  for (int i = threadIdx.x; i < NBH5_; i += 256) if (hH[i]) atomicAdd(&totH[i], hH[i]);
}

// ---------------- bucket-base scan ----------------
__global__ void k_bscan(const int* __restrict__ totN, const int* __restrict__ totH,
                        int* __restrict__ bbaseN, int* __restrict__ bbaseH,
                        int* __restrict__ gcurN, int* __restrict__ gcurH){
  __shared__ int tmp[512];
  int t = threadIdx.x;
  int v = (t < NBN5_) ? totN[t] : 0;
  tmp[t] = v; __syncthreads();
  for (int d = 1; d < 512; d <<= 1){
    int x = (t >= d) ? tmp[t-d] : 0; __syncthreads();
    tmp[t] += x; __syncthreads();
  }
  if (t < NBN5_){ int b = tmp[t] - v; bbaseN[t] = b; gcurN[t] = b; }
  __syncthreads();
  int w = (t < NBH5_) ? totH[t] : 0;
  tmp[t] = w; __syncthreads();
  for (int d = 1; d < 512; d <<= 1){
    int x = (t >= d) ? tmp[t-d] : 0; __syncthreads();
    tmp[t] += x; __syncthreads();
  }
  if (t < NBH5_){ int b = tmp[t] - w; bbaseH[t] = b; gcurH[t] = b; }
}

// ---------------- bucketed pair fill ----------------
// pair encoding: (local_row_9b << 18) | id (< 2^18)
__global__ void k_binfill(const int* __restrict__ ni, const int* __restrict__ hi,
                          int* __restrict__ gcurN, int* __restrict__ gcurH,
                          u32* __restrict__ pairN, u32* __restrict__ pairH){
  __shared__ int histN[NBN5_], histH[NBH5_];
  __shared__ int baseN[NBN5_], baseH[NBH5_];
  const int nchunks = (E_ + CHUNK_ - 1)/CHUNK_;
  for (int c = blockIdx.x; c < nchunks; c += gridDim.x){
    int e0 = c*CHUNK_;
    int e1 = e0 + CHUNK_; if (e1 > E_) e1 = E_;
    for (int i = threadIdx.x; i < NBN5_; i += 256) histN[i] = 0;
    for (int i = threadIdx.x; i < NBH5_; i += 256) histH[i] = 0;
    __syncthreads();
    for (int e = e0 + threadIdx.x; e < e1; e += 256){
      atomicAdd(&histN[ni[e] >> 9], 1);
      atomicAdd(&histH[hi[e] >> 9], 1);
    }
    __syncthreads();
    for (int i = threadIdx.x; i < NBN5_; i += 256){
      int hv = histN[i];
      baseN[i] = hv ? atomicAdd(&gcurN[i], hv) : 0;
      histN[i] = 0;
    }
    for (int i = threadIdx.x; i < NBH5_; i += 256){
      int hv = histH[i];
      baseH[i] = hv ? atomicAdd(&gcurH[i], hv) : 0;
      histH[i] = 0;
    }
    __syncthreads();
    for (int e = e0 + threadIdx.x; e < e1; e += 256){
      int n = ni[e], he = hi[e];
      int bn = n >> 9, bh = he >> 9;
      int pn = baseN[bn] + atomicAdd(&histN[bn], 1);
      pairN[pn] = ((u32)(n & 511) << 18) | (u32)he;
      int ph = baseH[bh] + atomicAdd(&histH[bh], 1);
      pairH[ph] = ((u32)(he & 511) << 18) | (u32)n;
    }
    __syncthreads();
  }
}

// ---------------- csrfill2: per-bucket count + scan + place ----------------
__global__ void __launch_bounds__(512) k_csrfill2(
    const int* __restrict__ bbase, const int* __restrict__ gcur,
    const u32* __restrict__ pair, int nrows, int* __restrict__ out,
    int* __restrict__ off_arr, int* __restrict__ cnt_arr, float* __restrict__ inv_arr){
  __shared__ int cnt[512], cur[512], tmp[512];
  int b = blockIdx.x, t = threadIdx.x;
  int nb = b*512;
  cnt[t] = 0;
  __syncthreads();
  int base = bbase[b], end = gcur[b];
  for (int pos = base + t; pos < end; pos += 512)
    atomicAdd(&cnt[pair[pos] >> 18], 1);
  __syncthreads();
  int v = cnt[t];
  tmp[t] = v; __syncthreads();
  for (int d = 1; d < 512; d <<= 1){
    int x = (t >= d) ? tmp[t-d] : 0; __syncthreads();
    tmp[t] += x; __syncthreads();
  }
  int ro = base + tmp[t] - v;
  cur[t] = ro;
  int row = nb + t;
  if (row < nrows){
    off_arr[row] = ro;
    cnt_arr[row] = v;
    inv_arr[row] = 1.f/fmaxf((float)v, 1.f);
  }
  __syncthreads();
  for (int pos = base + t; pos < end; pos += 512){
    u32 p = pair[pos];
    int idx = atomicAdd(&cur[p >> 18], 1);
    out[idx] = (int)(p & 0x3FFFFu);
  }
}

// ---------------- pack hattr to fp16 pairs [NH][18] ----------------
__global__ void k_hattr_pack(const float* __restrict__ hattr, u32* __restrict__ hattr16){
  int i = blockIdx.x*256 + threadIdx.x;
  if (i >= N_HEDGES_*18) return;
  int he = i/18, p = i - he*18;
  int k0 = 2*p, k1 = 2*p + 1;
  float w0 = (k0 < 35) ? hattr[(size_t)he*35 + k0] : 0.f;
  float w1 = (k1 < 35) ? hattr[(size_t)he*35 + k1] : 0.f;
  hattr16[i] = pk_(w0, w1);
}

// ---------------- embed: h16 = fp16( x @ We + be ) ----------------
__global__ void k_embed(const float* __restrict__ x, const float* __restrict__ We,
                        const float* __restrict__ be, u32* __restrict__ h16){
  __shared__ __align__(16) float As[64*100];
  __shared__ __align__(16) float Ws[64*100];
  int tid = threadIdx.x;
  for (int idx = tid; idx < 64*100; idx += 256){
    int c = idx/100, k = idx - c*100;
    Ws[idx] = (k < 92) ? We[k*64 + c] : 0.f;
  }
  int rt = tid & 15, ct = tid >> 4;
  float bias[4];
  #pragma unroll
  for (int j = 0; j < 4; ++j) bias[j] = be[ct*4 + j];
  const int ntiles = (N_NODES_ + 63)/64;
  for (int tile = blockIdx.x; tile < ntiles; tile += gridDim.x){
    int rbase = tile*64;
    __syncthreads();
    for (int idx = tid; idx < 64*100; idx += 256){
      int r = idx/100, k = idx - r*100;
      int rg = rbase + r;
      As[idx] = (rg < N_NODES_ && k < 92) ? x[(size_t)rg*92 + k] : 0.f;
    }
    __syncthreads();
    float acc[4][4] = {};
    for (int kc = 0; kc < 25; ++kc){
      float4 av[4], wv[4];
      #pragma unroll
      for (int i = 0; i < 4; ++i) av[i] = *(const float4*)&As[(rt + 16*i)*100 + kc*4];
      #pragma unroll
      for (int j = 0; j < 4; ++j) wv[j] = *(const float4*)&Ws[(ct*4 + j)*100 + kc*4];
      #pragma unroll
      for (int i = 0; i < 4; ++i)
        #pragma unroll
        for (int j = 0; j < 4; ++j)
          acc[i][j] += av[i].x*wv[j].x + av[i].y*wv[j].y + av[i].z*wv[j].z + av[i].w*wv[j].w;
    }
    #pragma unroll
    for (int i = 0; i < 4; ++i){
      int r = rbase + rt + 16*i;
      if (r < N_NODES_){
        h16[(size_t)r*32 + ct*2]     = pk_(acc[i][0] + bias[0], acc[i][1] + bias[1]);
        h16[(size_t)r*32 + ct*2 + 1] = pk_(acc[i][2] + bias[2], acc[i][3] + bias[3]);
      }
    }
  }
}

// ---------------- hedge gather (fp16, uint4, 8 lanes/hedge) ----------------
__global__ void __launch_bounds__(256) k_gather_hedge(
    const u32* __restrict__ h16, const int* __restrict__ hedge_off,
    const int* __restrict__ hcnt, const int* __restrict__ edge_h,
    const float* __restrict__ hinv, u32* __restrict__ hmean16){
  int w = (blockIdx.x*256 + threadIdx.x) >> 3;
  int p = threadIdx.x & 7;
  if (w >= N_HEDGES_) return;
  int off = hedge_off[w], deg = hcnt[w];
  float a[8] = {};
  int i = 0;
  for (; i + 1 < deg; i += 2){
    int n0 = edge_h[off+i], n1 = edge_h[off+i+1];
    uint4 u0 = *(const uint4*)&h16[(size_t)n0*32 + 4*p];
    uint4 u1 = *(const uint4*)&h16[(size_t)n1*32 + 4*p];
    a[0] += lo_(u0.x) + lo_(u1.x); a[1] += hi_(u0.x) + hi_(u1.x);
    a[2] += lo_(u0.y) + lo_(u1.y); a[3] += hi_(u0.y) + hi_(u1.y);
    a[4] += lo_(u0.z) + lo_(u1.z); a[5] += hi_(u0.z) + hi_(u1.z);
    a[6] += lo_(u0.w) + lo_(u1.w); a[7] += hi_(u0.w) + hi_(u1.w);
  }
  if (i < deg){
    uint4 u = *(const uint4*)&h16[(size_t)edge_h[off+i]*32 + 4*p];
    a[0] += lo_(u.x); a[1] += hi_(u.x); a[2] += lo_(u.y); a[3] += hi_(u.y);
    a[4] += lo_(u.z); a[5] += hi_(u.z); a[6] += lo_(u.w); a[7] += hi_(u.w);
  }
  float inv = hinv[w];
  uint4 st;
  st.x = pk_(a[0]*inv, a[1]*inv); st.y = pk_(a[2]*inv, a[3]*inv);
  st.z = pk_(a[4]*inv, a[5]*inv); st.w = pk_(a[6]*inv, a[7]*inv);
  *(uint4*)&hmean16[(size_t)w*32 + 4*p] = st;
}

// ---------------- hedge MLP pre-BN (MFMA, direct global A-frags, no in-loop barriers) ---
// A frag: a[j]=A[lane&15][(lane>>4)*8+j]; B frag: b[j]=B[(lane>>4)*8+j][lane&15];
// D: d[q]=D[(lane>>4)*4+q][lane&15]. K=128 (99 used), rows from hmean16/hattr16 directly.
__global__ void __launch_bounds__(256) k_hedge_mlp1(
    const u32* __restrict__ hmean16, const u32* __restrict__ hattr16,
    const float* __restrict__ Wf1, const float* __restrict__ bf1,
    const float* __restrict__ Wc1, const float* __restrict__ bc1,
    __fp16* __restrict__ tfc16T, float* __restrict__ hstats){
  __shared__ __align__(16) u32 Ws16[80*68];   // [col][68 u32], 64 used
  __shared__ float sstat[160];
  int tid = threadIdx.x;
  for (int idx = tid; idx < 80*68; idx += 256){
    int c = idx/68, kk = idx - c*68;
    int k0 = 2*kk, k1 = k0 + 1;
    float w0 = 0.f, w1 = 0.f;
    if (c < 70){
      int cc = (c < 35) ? c : c - 35;
      const float* W = (c < 35) ? Wf1 : Wc1;
      if (k0 < 99) w0 = W[k0*35 + cc];
      if (k1 < 99) w1 = W[k1*35 + cc];
    }
    Ws16[idx] = pk_(w0, w1);
  }
  for (int idx = tid; idx < 160; idx += 256) sstat[idx] = 0.f;
  __syncthreads();
  int lane = tid & 63, wv = tid >> 6;
  int l15 = lane & 15, lg = lane >> 4;
  float bias[5];
  #pragma unroll
  for (int t = 0; t < 5; ++t){
    int c = t*16 + l15;
    bias[t] = (c < 35) ? bf1[c] : (c < 70 ? bc1[c - 35] : 0.f);
  }
  float sreg[5] = {}, qreg[5] = {};
  for (int tile = blockIdx.x; tile < N_HEDGES_/64; tile += gridDim.x){
    int rbase = tile*64;
    int arow = rbase + wv*16 + l15;
    // A fragments direct from global (k contiguous)
    h8_t af0 = *(const h8_t*)&hmean16[(size_t)arow*32 + lg*4];        // k 0..31 chunk
    h8_t af1 = *(const h8_t*)&hmean16[(size_t)arow*32 + 16 + lg*4];   // k 32..63
    uint2 b0 = *(const uint2*)&hattr16[(size_t)arow*18 + lg*4];       // k 64..95 (8B aligned)
    uint2 b1 = *(const uint2*)&hattr16[(size_t)arow*18 + lg*4 + 2];
    uint4 a2; a2.x = b0.x; a2.y = b0.y; a2.z = b1.x; a2.w = b1.y;
    h8_t af2 = __builtin_bit_cast(h8_t, a2);
    uint4 a3 = {0u,0u,0u,0u};
    if (lg == 0){
      uint2 u = *(const uint2*)&hattr16[(size_t)arow*18 + 16];        // k 96..99
      a3.x = u.x; a3.y = u.y;
    }
    h8_t af3 = __builtin_bit_cast(h8_t, a3);
    f32x4 acc[5];
    #pragma unroll
    for (int t = 0; t < 5; ++t) acc[t] = (f32x4){0.f,0.f,0.f,0.f};
    #pragma unroll
    for (int t = 0; t < 5; ++t){
      int bcol = t*16 + l15;
      h8_t bf0 = *(const h8_t*)&Ws16[bcol*68 + 0*16 + lg*4];
      h8_t bf1_ = *(const h8_t*)&Ws16[bcol*68 + 1*16 + lg*4];
      h8_t bf2_ = *(const h8_t*)&Ws16[bcol*68 + 2*16 + lg*4];
      h8_t bf3_ = *(const h8_t*)&Ws16[bcol*68 + 3*16 + lg*4];
      acc[t] = __builtin_amdgcn_mfma_f32_16x16x32_f16(af0, bf0, acc[t], 0, 0, 0);
      acc[t] = __builtin_amdgcn_mfma_f32_16x16x32_f16(af1, bf1_, acc[t], 0, 0, 0);
      acc[t] = __builtin_amdgcn_mfma_f32_16x16x32_f16(af2, bf2_, acc[t], 0, 0, 0);
      acc[t] = __builtin_amdgcn_mfma_f32_16x16x32_f16(af3, bf3_, acc[t], 0, 0, 0);
    }
    #pragma unroll
    for (int t = 0; t < 5; ++t){
      int col = t*16 + l15;
      float v0 = acc[t][0] + bias[t], v1 = acc[t][1] + bias[t];
      float v2 = acc[t][2] + bias[t], v3 = acc[t][3] + bias[t];
      sreg[t] += v0 + v1 + v2 + v3;
      qreg[t] += v0*v0 + v1*v1 + v2*v2 + v3*v3;
      if (col < 70){
        uint2 st; st.x = pk_(v0, v1); st.y = pk_(v2, v3);
        *(uint2*)&tfc16T[(size_t)col*N_HEDGES_ + rbase + wv*16 + lg*4] = st;
      }
    }
  }
  #pragma unroll
  for (int t = 0; t < 5; ++t){
    float s = sreg[t], q = qreg[t];
    s += __shfl_xor(s, 16); q += __shfl_xor(q, 16);
    s += __shfl_xor(s, 32); q += __shfl_xor(q, 32);
    if (lg == 0){
      int c = t*16 + l15;
      if (c < 70){
        atomicAdd(&sstat[c], s);
        atomicAdd(&sstat[80 + c], q);
      }
    }
  }
  __syncthreads();
  for (int idx = tid; idx < 160; idx += 256) atomicAdd(&hstats[idx], sstat[idx]);
}

// ---------------- BN finalize (hedge) ----------------
__global__ void k_bn_fin_hedge(const float* __restrict__ stats,
                               const float* __restrict__ gf, const float* __restrict__ btf,
                               const float* __restrict__ gc, const float* __restrict__ btc,
                               float* __restrict__ ab, float invN){
  int j = threadIdx.x;
  if (j >= 70) return;
  float m = stats[j]*invN;
  float var = stats[80+j]*invN - m*m;
  float gg = (j < 35) ? gf[j] : gc[j-35];
  float bb = (j < 35) ? btf[j] : btc[j-35];
  float a = gg*rsqrtf(var + 1e-5f);
  ab[j] = a; ab[70+j] = bb - m*a;
}

// ---------------- hedge feats + project (dot2, fp16 tfc16T reads): heFC2 fp16 ---------
__global__ void k_hedge_feats(const __fp16* __restrict__ tfc16T, const float* __restrict__ ab,
                              const float* __restrict__ Wf2, const float* __restrict__ bf2,
                              const float* __restrict__ Wc2, const float* __restrict__ bc2,
                              u32* __restrict__ heFC2){
  __shared__ __align__(16) u32 As16[64*20];
  __shared__ __align__(16) u32 Ws16[128*20];
  int tid = threadIdx.x;
  for (int idx = tid; idx < 128*20; idx += 256){
    int c = idx/20, kk = idx - c*20;
    int k0 = 2*kk, k1 = 2*kk + 1;
    float w0 = 0.f, w1 = 0.f;
    if (k0 < 35) w0 = (c < 64) ? Wf2[(64+k0)*64 + c] : Wc2[(64+k0)*64 + (c-64)];
    if (k1 < 35) w1 = (c < 64) ? Wf2[(64+k1)*64 + c] : Wc2[(64+k1)*64 + (c-64)];
    Ws16[idx] = pk_(w0, w1);
  }
  int rt = tid & 15, ct = tid >> 4;
  float biasF[4], biasC[4];
  #pragma unroll
  for (int j = 0; j < 4; ++j){ biasF[j] = bf2[ct*4 + j]; biasC[j] = bc2[ct*4 + j]; }
  for (int tile = blockIdx.x; tile < N_HEDGES_/64; tile += gridDim.x){
    int rbase = tile*64;
    __syncthreads();
    for (int idx = tid; idx < 64*20; idx += 256){
      int kk = idx >> 6;        // 0..19
      int r  = idx & 63;
      float a0 = 0.f, a1 = 0.f;
      if (kk < 18){
        int rg = rbase + r;
        int k0 = 2*kk, k1 = 2*kk + 1;
        {
          float tf = (float)tfc16T[(size_t)k0*N_HEDGES_ + rg];
          float tc = (float)tfc16T[(size_t)(35+k0)*N_HEDGES_ + rg];
          float zf = ab[k0]*tf + ab[70 + k0];
          float zc = ab[35+k0]*tc + ab[105 + k0];
          a0 = gate_(zf, zc);
        }
        if (k1 < 35){
          float tf = (float)tfc16T[(size_t)k1*N_HEDGES_ + rg];
          float tc = (float)tfc16T[(size_t)(35+k1)*N_HEDGES_ + rg];
          float zf = ab[k1]*tf + ab[70 + k1];
          float zc = ab[35+k1]*tc + ab[105 + k1];
          a1 = gate_(zf, zc);
        }
      }
      As16[r*20 + kk] = pk_(a0, a1);
    }
    __syncthreads();
    float accF[4][4] = {}, accC[4][4] = {};
    for (int kc = 0; kc < 5; ++kc){
      uint4 av[4], wF[4], wC[4];
      #pragma unroll
      for (int i = 0; i < 4; ++i) av[i] = *(const uint4*)&As16[(rt + 16*i)*20 + kc*4];
      #pragma unroll
      for (int j = 0; j < 4; ++j){
        wF[j] = *(const uint4*)&Ws16[(ct*4 + j)*20 + kc*4];
        wC[j] = *(const uint4*)&Ws16[(64 + ct*4 + j)*20 + kc*4];
      }
      #pragma unroll
      for (int i = 0; i < 4; ++i)
        #pragma unroll
        for (int j = 0; j < 4; ++j){
          float f = accF[i][j], c = accC[i][j];
          f = dot2_(av[i].x, wF[j].x, f); c = dot2_(av[i].x, wC[j].x, c);
          f = dot2_(av[i].y, wF[j].y, f); c = dot2_(av[i].y, wC[j].y, c);
          f = dot2_(av[i].z, wF[j].z, f); c = dot2_(av[i].z, wC[j].z, c);
          f = dot2_(av[i].w, wF[j].w, f); c = dot2_(av[i].w, wC[j].w, c);
          accF[i][j] = f; accC[i][j] = c;
        }
    }
    #pragma unroll
    for (int i = 0; i < 4; ++i){
      int r = rbase + rt + 16*i;
      #pragma unroll
      for (int j = 0; j < 4; ++j){
        heFC2[(size_t)r*64 + ct*4 + j] = pk_(accF[i][j] + biasF[j], accC[i][j] + biasC[j]);
      }
    }
  }
}

// ---------------- node projections (MFMA, direct global A-frags): nFC2 packed fp16 -------
__global__ void __launch_bounds__(256) k_node_lin(
    const u32* __restrict__ h16,
    const float* __restrict__ Wf2, const float* __restrict__ Wc2,
    u32* __restrict__ nFC2){
  __shared__ __align__(16) u32 Ws16[128*36];   // [col][36 u32], 32 used
  int tid = threadIdx.x;
  for (int idx = tid; idx < 128*36; idx += 256){
    int c = idx/36, kk = idx - c*36;
    int k0 = 2*kk, k1 = k0 + 1;
    float w0 = 0.f, w1 = 0.f;
    if (k0 < 64) w0 = (c < 64) ? Wf2[k0*64 + c] : Wc2[k0*64 + (c-64)];
    if (k1 < 64) w1 = (c < 64) ? Wf2[k1*64 + c] : Wc2[k1*64 + (c-64)];
    Ws16[idx] = pk_(w0, w1);
  }
  __syncthreads();
  int lane = tid & 63, wv = tid >> 6;
  int l15 = lane & 15, lg = lane >> 4;
  const int ntiles = (N_NODES_ + 63)/64;
  for (int tile = blockIdx.x; tile < ntiles; tile += gridDim.x){
    int rbase = tile*64;
    int arow = rbase + wv*16 + l15;
    h8_t af0, af1;
    if (arow < N_NODES_){
      af0 = *(const h8_t*)&h16[(size_t)arow*32 + lg*4];
      af1 = *(const h8_t*)&h16[(size_t)arow*32 + 16 + lg*4];
    } else {
      uint4 z = {0u,0u,0u,0u};
      af0 = __builtin_bit_cast(h8_t, z);
      af1 = __builtin_bit_cast(h8_t, z);
    }
    f32x4 acc[8];
    #pragma unroll
    for (int t = 0; t < 8; ++t) acc[t] = (f32x4){0.f,0.f,0.f,0.f};
    #pragma unroll
    for (int t = 0; t < 8; ++t){
      int bcol = t*16 + l15;
      h8_t bf0 = *(const h8_t*)&Ws16[bcol*36 + 0*16 + lg*4];
      h8_t bf1 = *(const h8_t*)&Ws16[bcol*36 + 1*16 + lg*4];
      acc[t] = __builtin_amdgcn_mfma_f32_16x16x32_f16(af0, bf0, acc[t], 0, 0, 0);
      acc[t] = __builtin_amdgcn_mfma_f32_16x16x32_f16(af1, bf1, acc[t], 0, 0, 0);
    }
    #pragma unroll
    for (int t = 0; t < 4; ++t){
      #pragma unroll
      for (int q = 0; q < 4; ++q){
        int row = rbase + wv*16 + lg*4 + q;
        if (row < N_NODES_)
          nFC2[(size_t)row*64 + t*16 + l15] = pk_(acc[t][q], acc[t+4][q]);
      }
    }
  }
}

// ---------------- fused edge: node-CSR gather + gated act + mean(fp16) + stats ------
__global__ void k_edge(const u32* __restrict__ nFC2, const u32* __restrict__ heFC2,
                       const int* __restrict__ node_off, const int* __restrict__ ndeg,
                       const int* __restrict__ edge_n, const float* __restrict__ ninv,
                       __fp16* __restrict__ nmean16, float* __restrict__ nstats){
  int lane = threadIdx.x & 63, wave = threadIdx.x >> 6;
  float s = 0.f, q = 0.f;
  for (int base = blockIdx.x*4; base < N_NODES_; base += gridDim.x*4){
    int n = base + wave;
    if (n < N_NODES_){
      int off = __builtin_amdgcn_readfirstlane(node_off[n]);
      int deg = __builtin_amdgcn_readfirstlane(ndeg[n]);
      u32 p0 = nFC2[(size_t)n*64 + lane];
      float acc = 0.f;
      int i = 0;
      for (; i + 7 < deg; i += 8){
        int e0 = edge_n[off+i],   e1 = edge_n[off+i+1], e2 = edge_n[off+i+2], e3 = edge_n[off+i+3];
        int e4 = edge_n[off+i+4], e5 = edge_n[off+i+5], e6 = edge_n[off+i+6], e7 = edge_n[off+i+7];
        u32 s0 = pkadd_(p0, heFC2[(size_t)e0*64 + lane]);
        u32 s1 = pkadd_(p0, heFC2[(size_t)e1*64 + lane]);
        u32 s2 = pkadd_(p0, heFC2[(size_t)e2*64 + lane]);
        u32 s3 = pkadd_(p0, heFC2[(size_t)e3*64 + lane]);
        u32 s4 = pkadd_(p0, heFC2[(size_t)e4*64 + lane]);
        u32 s5 = pkadd_(p0, heFC2[(size_t)e5*64 + lane]);
        u32 s6 = pkadd_(p0, heFC2[(size_t)e6*64 + lane]);
        u32 s7 = pkadd_(p0, heFC2[(size_t)e7*64 + lane]);
        acc += gate_(lo_(s0), hi_(s0)) + gate_(lo_(s1), hi_(s1))
             + gate_(lo_(s2), hi_(s2)) + gate_(lo_(s3), hi_(s3))
             + gate_(lo_(s4), hi_(s4)) + gate_(lo_(s5), hi_(s5))
             + gate_(lo_(s6), hi_(s6)) + gate_(lo_(s7), hi_(s7));
      }
      for (; i + 3 < deg; i += 4){
        int e0 = edge_n[off+i], e1 = edge_n[off+i+1], e2 = edge_n[off+i+2], e3 = edge_n[off+i+3];
        u32 s0 = pkadd_(p0, heFC2[(size_t)e0*64 + lane]);
        u32 s1 = pkadd_(p0, heFC2[(size_t)e1*64 + lane]);
        u32 s2 = pkadd_(p0, heFC2[(size_t)e2*64 + lane]);
        u32 s3 = pkadd_(p0, heFC2[(size_t)e3*64 + lane]);
        acc += gate_(lo_(s0), hi_(s0)) + gate_(lo_(s1), hi_(s1))
             + gate_(lo_(s2), hi_(s2)) + gate_(lo_(s3), hi_(s3));
      }
      for (; i < deg; ++i){
        u32 sA = pkadd_(p0, heFC2[(size_t)edge_n[off+i]*64 + lane]);
        acc += gate_(lo_(sA), hi_(sA));
      }
      float m = acc * ninv[n];
      nmean16[(size_t)n*64 + lane] = (__fp16)m;
      s += m; q += m*m;
    }
  }
  __shared__ float p1[256], p2[256];
  p1[threadIdx.x] = s; p2[threadIdx.x] = q;
  __syncthreads();
  if (wave == 0){
    float a = p1[lane] + p1[64+lane] + p1[128+lane] + p1[192+lane];
    float b = p2[lane] + p2[64+lane] + p2[128+lane] + p2[192+lane];
    atomicAdd(&nstats[lane], a);
    atomicAdd(&nstats[64+lane], b);
  }
}

__global__ void k_bn_fin_node(const float* __restrict__ stats, const float* __restrict__ g,
                              const float* __restrict__ bt, float* __restrict__ ab, float invN){
  int j = threadIdx.x;
  if (j >= 64) return;
  float m = stats[j]*invN;
  float var = stats[64+j]*invN - m*m;
  float a = g[j]*rsqrtf(var + 1e-5f);
  ab[j] = a; ab[64+j] = bt[j] - m*a;
}

// ---------------- node update: h16' = fp16(softplus(BN(mean) + h16)) ----------------
__global__ void k_node_update(const u32* __restrict__ nmean16, const float* __restrict__ ab,
                              const u32* __restrict__ h16, u32* __restrict__ h16out){
  int t = blockIdx.x*256 + threadIdx.x;
  if (t >= N_NODES_*32) return;
  int p = t & 31;
  int f0 = 2*p, f1 = 2*p + 1;
  u32 nm = nmean16[t];
  u32 hh = h16[t];
  float r0 = sp_(ab[f0]*lo_(nm) + ab[64+f0] + lo_(hh));
  float r1 = sp_(ab[f1]*hi_(nm) + ab[64+f1] + hi_(hh));
  h16out[t] = pk_(r0, r1);
}

// ---------------- graph mean (sorted batch; one block per graph, no atomics) ----------
__global__ void __launch_bounds__(256) k_graph_agg2(
    const u32* __restrict__ h16, const int* __restrict__ goff,
    float* __restrict__ gmean){
  __shared__ float s0[256], s1[256];
  int g = blockIdx.x;
  int st = goff[g], en = goff[g+1];
  int p = threadIdx.x & 31;   // word index
  int r = threadIdx.x >> 5;   // row group 0..7
  float a0 = 0.f, a1 = 0.f;
  for (int n = st + r; n < en; n += 8){
    u32 u = h16[(size_t)n*32 + p];
    a0 += lo_(u); a1 += hi_(u);
  }
  s0[threadIdx.x] = a0; s1[threadIdx.x] = a1;
  __syncthreads();
  for (int d = 128; d >= 32; d >>= 1){
    if (threadIdx.x < d){
      s0[threadIdx.x] += s0[threadIdx.x + d];
      s1[threadIdx.x] += s1[threadIdx.x + d];
    }
    __syncthreads();
  }
  if (threadIdx.x < 32){
    float inv = 1.f/fmaxf((float)(en - st), 1.f);
    gmean[(size_t)g*64 + 2*threadIdx.x]     = s0[threadIdx.x]*inv;
    gmean[(size_t)g*64 + 2*threadIdx.x + 1] = s1[threadIdx.x]*inv;
  }
}

__global__ void k_head(const float* __restrict__ gmean,
                       const float* __restrict__ Wl2, const float* __restrict__ bl2,
                       const float* __restrict__ Wo, const float* __restrict__ bo,
                       float* __restrict__ out){
  __shared__ float gm[64];
  __shared__ float red[128];
  int g = blockIdx.x, j = threadIdx.x;
  if (j < 64) gm[j] = gmean[(size_t)g*64+j];
  __syncthreads();
  float u = bl2[j];
  for (int f = 0; f < 64; ++f) u += gm[f]*Wl2[f*128+j];
  red[j] = sp_(u)*Wo[j];
  __syncthreads();
  for (int s = 64; s > 0; s >>= 1){
    if (j < s) red[j] += red[j+s];
    __syncthreads();
  }
  if (j == 0) out[g] = red[0] + bo[0];
}

extern "C" void kernel_launch(void* const* d_in, const int* in_sizes, int n_in,
                              void* d_out, int out_size, void* d_ws, size_t ws_size,
                              hipStream_t stream){
  (void)in_sizes; (void)n_in; (void)out_size; (void)ws_size;
  const float* x      = (const float*)d_in[0];
  const int*   ni     = (const int*)d_in[1];
  const int*   hi     = ni + E_;
  const float* hattr  = (const float*)d_in[2];
  const int*   batch  = (const int*)d_in[3];
  const float* We     = (const float*)d_in[4];
  const float* be     = (const float*)d_in[5];
  const float* Wf1    = (const float*)d_in[6];
  const float* bf1    = (const float*)d_in[7];
  const float* Wc1    = (const float*)d_in[8];
  const float* bc1    = (const float*)d_in[9];
  const float* Wf2    = (const float*)d_in[10];
  const float* bf2    = (const float*)d_in[11];
  const float* Wc2    = (const float*)d_in[12];
  const float* bc2    = (const float*)d_in[13];
  const float* bn_f_g = (const float*)d_in[14];
  const float* bn_f_b = (const float*)d_in[15];
  const float* bn_c_g = (const float*)d_in[16];
  const float* bn_c_b = (const float*)d_in[17];
  const float* bn_o_g = (const float*)d_in[18];
  const float* bn_o_b = (const float*)d_in[19];
  const float* Wl2    = (const float*)d_in[20];
  const float* bl2    = (const float*)d_in[21];
  const float* Wo     = (const float*)d_in[22];
  const float* bo     = (const float*)d_in[23];

  float* ws = (float*)d_ws;
  size_t o = 0;
  // region A: tfc16T (28MB) / nFC2 (25.6MB) / pairN+pairH (9.6MB) — time-disjoint
  __fp16* tfc16T = (__fp16*)(ws + o); o += (size_t)N_HEDGES_*70/2 + 64;
  u32*   nFC2  = (u32*)tfc16T;
  u32*   pairN = (u32*)tfc16T;
  u32*   pairH = pairN + E_;
  // region B: hmean16 (25.6MB) / heFC2 (51.2MB) — time-disjoint
  float* hmR   = ws + o; o += (size_t)N_HEDGES_*H_;
  u32*   hmean16 = (u32*)hmR;
  u32*   heFC2   = (u32*)hmR;
  __fp16* nmean16 = (__fp16*)(ws + o); o += (size_t)N_NODES_*H_/2 + 64;
  u32*  h16a   = (u32*)(ws + o); o += (size_t)N_NODES_*32;
  u32*  h16b   = (u32*)(ws + o); o += (size_t)N_NODES_*32;
  u32*  hattr16= (u32*)(ws + o); o += (size_t)N_HEDGES_*18;
  float* hstats = ws + o; o += 256;
  float* habs   = ws + o; o += 256;
  float* nstats = ws + o; o += 128;
  float* nabs   = ws + o; o += 128;
  float* gmean  = ws + o; o += (size_t)G_*H_;
  float* hinv   = ws + o; o += N_HEDGES_;
  float* ninv   = ws + o; o += N_NODES_;
  int* hcnt     = (int*)(ws + o); o += N_HEDGES_;
  int* ndeg     = (int*)(ws + o); o += N_NODES_;
  int* gcnt     = (int*)(ws + o); o += G_;
  int* goff     = (int*)(ws + o); o += G_ + 1;
  int* node_off = (int*)(ws + o); o += N_NODES_;
  int* hedge_off= (int*)(ws + o); o += N_HEDGES_;
  int* gcurN    = (int*)(ws + o); o += NBN5_;
  int* gcurH    = (int*)(ws + o); o += NBH5_;
  int* totN     = (int*)(ws + o); o += NBN5_;
  int* totH     = (int*)(ws + o); o += NBH5_;
  int* bbaseN   = (int*)(ws + o); o += NBN5_;
  int* bbaseH   = (int*)(ws + o); o += NBH5_;
  int* edge_n   = (int*)(ws + o); o += E_;
  int* edge_h   = (int*)(ws + o); o += E_;

  hipMemsetAsync(totN, 0, sizeof(int)*(NBN5_ + NBH5_), stream);  // totN,totH contiguous
  hipMemsetAsync(gcnt, 0, sizeof(int)*G_, stream);

  k_gcnt<<<(N_NODES_+255)/256, 256, 0, stream>>>(batch, gcnt);
  k_gscan<<<1, 512, 0, stream>>>(gcnt, goff);
  k_hattr_pack<<<(N_HEDGES_*18+255)/256, 256, 0, stream>>>(hattr, hattr16);

  // bucketed CSR build (no per-row atomics anywhere)
  k_bhist<<<512, 256, 0, stream>>>(ni, hi, totN, totH);
  k_bscan<<<1, 512, 0, stream>>>(totN, totH, bbaseN, bbaseH, gcurN, gcurH);
  k_binfill<<<(E_+CHUNK_-1)/CHUNK_, 256, 0, stream>>>(ni, hi, gcurN, gcurH, pairN, pairH);
  k_csrfill2<<<NBN5_, 512, 0, stream>>>(bbaseN, gcurN, pairN, N_NODES_, edge_n,
                                        node_off, ndeg, ninv);
  k_csrfill2<<<NBH5_, 512, 0, stream>>>(bbaseH, gcurH, pairH, N_HEDGES_, edge_h,
                                        hedge_off, hcnt, hinv);

  k_embed<<<768, 256, 0, stream>>>(x, We, be, h16a);

  u32* hc16 = h16a;
  u32* hn16 = h16b;
  for (int l = 0; l < L_; ++l){
    const float* Wf1l = Wf1 + (size_t)l*D_*HE_;
    const float* Wc1l = Wc1 + (size_t)l*D_*HE_;
    const float* Wf2l = Wf2 + (size_t)l*D_*H_;
    const float* Wc2l = Wc2 + (size_t)l*D_*H_;

    hipMemsetAsync(hstats, 0, sizeof(float)*160, stream);
    hipMemsetAsync(nstats, 0, sizeof(float)*128, stream);

    k_gather_hedge<<<(N_HEDGES_*8+255)/256, 256, 0, stream>>>(hc16, hedge_off, hcnt, edge_h,
                                                              hinv, hmean16);
    k_hedge_mlp1<<<1280, 256, 0, stream>>>(hmean16, hattr16, Wf1l, bf1 + l*HE_,
                                           Wc1l, bc1 + l*HE_, tfc16T, hstats);
    k_bn_fin_hedge<<<1, 128, 0, stream>>>(hstats, bn_f_g + l*HE_, bn_f_b + l*HE_,
                                          bn_c_g + l*HE_, bn_c_b + l*HE_, habs,
                                          1.f/(float)N_HEDGES_);
    k_hedge_feats<<<1536, 256, 0, stream>>>(tfc16T, habs, Wf2l, bf2 + l*H_,
                                            Wc2l, bc2 + l*H_, heFC2);
    k_node_lin<<<1024, 256, 0, stream>>>(hc16, Wf2l, Wc2l, nFC2);
    k_edge<<<2048, 256, 0, stream>>>(nFC2, heFC2, node_off, ndeg, edge_n, ninv,
                                     nmean16, nstats);
    k_bn_fin_node<<<1, 64, 0, stream>>>(nstats, bn_o_g + l*H_, bn_o_b + l*H_, nabs,
                                        1.f/(float)N_NODES_);
    k_node_update<<<(N_NODES_*32+255)/256, 256, 0, stream>>>((const u32*)nmean16, nabs,
                                                             hc16, hn16);
    u32* t3 = hc16; hc16 = hn16; hn16 = t3;
  }

  k_graph_agg2<<<G_, 256, 0, stream>>>(hc16, goff, gmean);
  k_head<<<G_, 128, 0, stream>>>(gmean, Wl2, bl2, Wo, bo, (float*)d_out);
}